// Round 7
// baseline (561.593 us; speedup 1.0000x reference)
//
#include <hip/hip_runtime.h>
#include <cstddef>

// N=100000, E=800000, H=128, C=10, G=512
#define HD 128
#define SCAN_BS 256
#define SCAN_CHUNK 2048  // 8 elements per thread
#define QSEG 8           // partial-pool blocks per graph
#define TROWS 64         // destination rows per fused-layer block
#define QSTRIDE 132      // padded LDS row stride (floats), 16B-aligned

typedef float f32x4 __attribute__((ext_vector_type(4)));
typedef short s16x8 __attribute__((ext_vector_type(8)));

static __device__ __forceinline__ int atomAddI(int* p, int v) {
    return __hip_atomic_fetch_add(p, v, __ATOMIC_RELAXED, __HIP_MEMORY_SCOPE_AGENT);
}

// round-to-nearest-even f32 -> bf16 bits
static __device__ __forceinline__ unsigned short rne_bf16(float f) {
    unsigned u = __float_as_uint(f);
    unsigned r = u + 0x7FFFu + ((u >> 16) & 1u);
    return (unsigned short)(r >> 16);
}
static __device__ __forceinline__ float bf16_to_f32(unsigned short h) {
    return __uint_as_float((unsigned)h << 16);
}

__global__ void k_zero_int(int* p, int n) {
    int i = blockIdx.x * blockDim.x + threadIdx.x;
    if (i < n) p[i] = 0;
}

__global__ void k_deg_int(const int* __restrict__ col, int* cnt, int E) {
    int e = blockIdx.x * blockDim.x + threadIdx.x;
    if (e < E) atomAddI(&cnt[col[e]], 1);
}

__global__ __launch_bounds__(SCAN_BS) void k_scan1(const int* __restrict__ cnt,
                                                   int* __restrict__ rowptr,
                                                   int* __restrict__ bsum, int n) {
    __shared__ int sd[SCAN_BS];
    const int t = threadIdx.x;
    const int base = blockIdx.x * SCAN_CHUNK + t * 8;
    int loc[8];
    int tsum = 0;
#pragma unroll
    for (int i = 0; i < 8; ++i) {
        loc[i] = (base + i < n) ? cnt[base + i] : 0;
        tsum += loc[i];
    }
    sd[t] = tsum;
    __syncthreads();
    for (int off = 1; off < SCAN_BS; off <<= 1) {
        int u = (t >= off) ? sd[t - off] : 0;
        __syncthreads();
        sd[t] += u;
        __syncthreads();
    }
    const int texc = sd[t] - tsum;
    if (t == SCAN_BS - 1) bsum[blockIdx.x] = sd[t];
    int pos = texc;
#pragma unroll
    for (int i = 0; i < 8; ++i) {
        if (base + i < n) rowptr[base + i] = pos;
        pos += loc[i];
    }
}

__global__ void k_scan2(int* bsum, int nblk, int* rowptr, int n) {
    if (threadIdx.x == 0 && blockIdx.x == 0) {
        int run = 0;
        for (int i = 0; i < nblk; ++i) { int v = bsum[i]; bsum[i] = run; run += v; }
        rowptr[n] = run;
    }
}

// rowptr += block offset; wofs = rowptr; dinv = rsqrt(1+cnt)
__global__ void k_scan3(int* rowptr, int* wofs, const int* __restrict__ bsum,
                        const int* __restrict__ cnt, float* __restrict__ dinv, int n) {
    int i = blockIdx.x * blockDim.x + threadIdx.x;
    if (i < n) {
        int v = rowptr[i] + bsum[i >> 11];  // SCAN_CHUNK = 2048
        rowptr[i] = v;
        wofs[i] = v;
        dinv[i] = rsqrtf(1.0f + (float)cnt[i]);
    }
}

__global__ void k_fill_csr(const int* __restrict__ rowi, const int* __restrict__ coli,
                           int* wofs, int* __restrict__ csr_src, int E) {
    int e = blockIdx.x * blockDim.x + threadIdx.x;
    if (e >= E) return;
    int p = atomAddI(&wofs[coli[e]], 1);
    csr_src[p] = rowi[e];
}

// Precompute W (128x128 f32) into MFMA B-fragment order, split hi/lo bf16.
// B-frag for 16x16x32: lane l holds B[k = kt*32+(l>>4)*8+e][col = nt*16+(l&15)].
__global__ __launch_bounds__(256) void k_wfrag(const float* __restrict__ W1,
                                               const float* __restrict__ W2,
                                               const float* __restrict__ W3,
                                               short* __restrict__ wf) {
    const int w = blockIdx.x >> 3;
    const int slot = (blockIdx.x & 7) * 256 + threadIdx.x;  // 0..2047
    const int nt = slot >> 8;
    const int kt = (slot >> 6) & 3;
    const int lane = slot & 63;
    const float* W = (w == 0) ? W1 : (w == 1) ? W2 : W3;
    short* whi = wf + (size_t)w * 32768;
    short* wlo = whi + 16384;
    const int obase = ((nt * 4 + kt) * 64 + lane) * 8;
    s16x8 hi8, lo8;
#pragma unroll
    for (int e = 0; e < 8; ++e) {
        const int k = kt * 32 + (lane >> 4) * 8 + e;
        const int c = nt * 16 + (lane & 15);
        const float v = W[(size_t)k * HD + c];
        const unsigned short h = rne_bf16(v);
        hi8[e] = (short)h;
        lo8[e] = (short)rne_bf16(v - bf16_to_f32(h));
    }
    *(s16x8*)&whi[obase] = hi8;
    *(s16x8*)&wlo[obase] = lo8;
}

static __device__ __forceinline__ void split8(const float* xs, s16x8& hi, s16x8& lo) {
#pragma unroll
    for (int e = 0; e < 8; ++e) {
        const unsigned short h = rne_bf16(xs[e]);
        hi[e] = (short)h;
        lo[e] = (short)rne_bf16(xs[e] - bf16_to_f32(h));
    }
}

// Fused GCN layer, aggregate-first:  Pout = epilogue( (D̃·(Ã·Pin*)) @ W )
//   Pin* = D̃·Pin applied per-edge iff scale_src (layer 1, raw x input);
//          layers 2/3 consume Pout of the previous layer which is pre-scaled.
//   epilogue: !last -> relu(dinv·z + dinv·b)   (stores D̃·H for next layer)
//              last -> z + b                    (stores H3 for pooling)
// Phase A: 4 waves gather 16 dst rows each into LDS Q (half-wave float4 rows,
// edges split by parity across halves, shfl_xor(32) combine).
// Phase B: each wave MFMAs its 16 rows x 128 cols from LDS (split-bf16,
// hh+lh+hl) against L2-hot W fragments.
__global__ __launch_bounds__(256) void k_layer(const float* __restrict__ Pin,
                                               const int* __restrict__ rowptr,
                                               const int* __restrict__ csr_src,
                                               const short* __restrict__ whi,
                                               const short* __restrict__ wlo,
                                               const float* __restrict__ dinv,
                                               const float* __restrict__ b,
                                               float* __restrict__ Pout,
                                               int n, int scale_src, int last) {
    __shared__ float Q[TROWS][QSTRIDE];
    const int lane = threadIdx.x & 63;
    const int wid  = threadIdx.x >> 6;
    const int tile = blockIdx.x * TROWS;

    // ---------------- Phase A: gather into LDS ----------------
    {
        const int half = lane >> 5;
        const int j = (lane & 31) * 4;
        for (int t = 0; t < 16; ++t) {
            const int lrow = wid * 16 + t;
            const int node = tile + lrow;   // wave-uniform
            if (node >= n) break;
            const float4 sv = *(const float4*)&Pin[(size_t)node * HD + j];
            float ax, ay, az, aw;
            if (half == 0) {
                const float ss = scale_src ? dinv[node] : 1.0f;
                ax = sv.x * ss; ay = sv.y * ss; az = sv.z * ss; aw = sv.w * ss;
            } else {
                ax = ay = az = aw = 0.f;
            }
            int k = rowptr[node];
            const int e = rowptr[node + 1];
            if (scale_src) {
                for (; k + 2 <= e; k += 2) {
                    const int src = csr_src[k + half];
                    const float f = dinv[src];
                    const float4 v = *(const float4*)&Pin[(size_t)src * HD + j];
                    ax = fmaf(v.x, f, ax); ay = fmaf(v.y, f, ay);
                    az = fmaf(v.z, f, az); aw = fmaf(v.w, f, aw);
                }
                if (k < e && half == 0) {
                    const int src = csr_src[k];
                    const float f = dinv[src];
                    const float4 v = *(const float4*)&Pin[(size_t)src * HD + j];
                    ax = fmaf(v.x, f, ax); ay = fmaf(v.y, f, ay);
                    az = fmaf(v.z, f, az); aw = fmaf(v.w, f, aw);
                }
            } else {
                for (; k + 2 <= e; k += 2) {
                    const int src = csr_src[k + half];
                    const float4 v = *(const float4*)&Pin[(size_t)src * HD + j];
                    ax += v.x; ay += v.y; az += v.z; aw += v.w;
                }
                if (k < e && half == 0) {
                    const int src = csr_src[k];
                    const float4 v = *(const float4*)&Pin[(size_t)src * HD + j];
                    ax += v.x; ay += v.y; az += v.z; aw += v.w;
                }
            }
            ax += __shfl_xor(ax, 32);
            ay += __shfl_xor(ay, 32);
            az += __shfl_xor(az, 32);
            aw += __shfl_xor(aw, 32);
            if (half == 0)
                *(float4*)&Q[lrow][j] = make_float4(ax, ay, az, aw);
        }
    }
    __syncthreads();

    // ---------------- Phase B: MFMA from LDS ----------------
    const int arow_l = wid * 16 + (lane & 15);
    const int arow_g = tile + arow_l;
    const float da = (arow_g < n) ? dinv[arow_g] : 0.f;
    const int kb = (lane >> 4) * 8;

    f32x4 acc[8];
#pragma unroll
    for (int nt = 0; nt < 8; ++nt) acc[nt] = (f32x4){0.f, 0.f, 0.f, 0.f};

#pragma unroll
    for (int kt = 0; kt < 4; ++kt) {
        const float* qp = &Q[arow_l][kt * 32 + kb];
        const float4 q0 = *(const float4*)qp;
        const float4 q1 = *(const float4*)(qp + 4);
        const float xs[8] = {q0.x * da, q0.y * da, q0.z * da, q0.w * da,
                             q1.x * da, q1.y * da, q1.z * da, q1.w * da};
        s16x8 ahi, alo;
        split8(xs, ahi, alo);
#pragma unroll
        for (int nt = 0; nt < 8; ++nt) {
            const int fo = ((nt * 4 + kt) * 64 + lane) * 8;
            const s16x8 bhi = *(const s16x8*)&whi[fo];
            const s16x8 blo = *(const s16x8*)&wlo[fo];
            acc[nt] = __builtin_amdgcn_mfma_f32_16x16x32_bf16(ahi, bhi, acc[nt], 0, 0, 0);
            acc[nt] = __builtin_amdgcn_mfma_f32_16x16x32_bf16(alo, bhi, acc[nt], 0, 0, 0);
            acc[nt] = __builtin_amdgcn_mfma_f32_16x16x32_bf16(ahi, blo, acc[nt], 0, 0, 0);
        }
    }

    // C/D layout: col = lane&15, row = (lane>>4)*4 + reg
    const int colb = lane & 15;
    const int rq = (lane >> 4) * 4;
#pragma unroll
    for (int r = 0; r < 4; ++r) {
        const int row = tile + wid * 16 + rq + r;
        if (row < n) {
            const float d = dinv[row];
#pragma unroll
            for (int nt = 0; nt < 8; ++nt) {
                const float z = acc[nt][r];
                const float bb = b[nt * 16 + colb];
                float v;
                if (!last) v = fmaxf(fmaf(z, d, bb * d), 0.f);  // = dinv*relu(z+b)
                else       v = z + bb;
                Pout[(size_t)row * HD + nt * 16 + colb] = v;
            }
        }
    }
}

// Stage 1 pooling: QSEG blocks per graph.
__global__ __launch_bounds__(128) void k_pool_part(const float* __restrict__ X,
                                                   const int* __restrict__ batch,
                                                   float* __restrict__ psum, int n) {
    const int g = blockIdx.x / QSEG;
    const int q = blockIdx.x % QSEG;
    const int t = threadIdx.x;
    int lo = 0, hi = n;
    while (lo < hi) { int m = (lo + hi) >> 1; if (batch[m] < g) lo = m + 1; else hi = m; }
    const int start = lo;
    hi = n;
    while (lo < hi) { int m = (lo + hi) >> 1; if (batch[m] < g + 1) lo = m + 1; else hi = m; }
    const int end = lo;
    float acc = 0.f;
    for (int i = start + q; i < end; i += QSEG) acc += X[(size_t)i * HD + t];
    psum[(size_t)blockIdx.x * HD + t] = acc;
}

// Stage 2 + final linear fused.
__global__ __launch_bounds__(128) void k_pool_final(const float* __restrict__ psum,
                                                    const int* __restrict__ batch,
                                                    const float* __restrict__ Wl,
                                                    const float* __restrict__ bl,
                                                    float* __restrict__ out, int n, int C) {
    __shared__ float pl[HD];
    const int g = blockIdx.x;
    const int t = threadIdx.x;
    int lo = 0, hi = n;
    while (lo < hi) { int m = (lo + hi) >> 1; if (batch[m] < g) lo = m + 1; else hi = m; }
    const int start = lo;
    hi = n;
    while (lo < hi) { int m = (lo + hi) >> 1; if (batch[m] < g + 1) lo = m + 1; else hi = m; }
    const int cnt = lo - start;
    float acc = 0.f;
#pragma unroll
    for (int q = 0; q < QSEG; ++q)
        acc += psum[((size_t)g * QSEG + q) * HD + t];
    pl[t] = acc / (float)max(cnt, 1);
    __syncthreads();
    if (t < C) {
        float s = 0.f;
        for (int k = 0; k < HD; ++k)
            s = fmaf(pl[k], Wl[(size_t)k * C + t], s);
        out[(size_t)g * C + t] = s + bl[t];
    }
}

extern "C" void kernel_launch(void* const* d_in, const int* in_sizes, int n_in,
                              void* d_out, int out_size, void* d_ws, size_t ws_size,
                              hipStream_t stream) {
    const float* x   = (const float*)d_in[0];
    const int* ei    = (const int*)d_in[1];
    const int* batch = (const int*)d_in[2];
    const float* W1 = (const float*)d_in[3];
    const float* b1 = (const float*)d_in[4];
    const float* W2 = (const float*)d_in[5];
    const float* b2 = (const float*)d_in[6];
    const float* W3 = (const float*)d_in[7];
    const float* b3 = (const float*)d_in[8];
    const float* Wl = (const float*)d_in[9];
    const float* bl = (const float*)d_in[10];
    float* out = (float*)d_out;

    const int N = in_sizes[0] / HD;
    const int E = in_sizes[1] / 2;
    const int C = 10;
    const int G = out_size / C;

    const int* rowi = ei;      // sources
    const int* coli = ei + E;  // targets

    // workspace layout
    float* B0     = (float*)d_ws;                    // N*HD
    float* B1     = B0 + (size_t)N * HD;             // N*HD
    float* dinv   = B1 + (size_t)N * HD;             // N
    short* wf     = (short*)(dinv + N);              // 3*2*16384 shorts
    int* rowptr   = (int*)(wf + 3 * 32768);          // N+1
    int* wofs     = rowptr + (N + 1);                // N
    int* cnt      = wofs + N;                        // N
    int* bsum     = cnt + N;                         // 64
    int* csr_src  = bsum + 64;                       // E
    float* psum   = B1;  // G*QSEG*HD floats — B1 is dead after layer 3

    const int T = 256;
    const int nblk = (N + SCAN_CHUNK - 1) / SCAN_CHUNK;

    // ---- preprocessing: CSR, dinv, W fragments ----
    k_zero_int<<<(N + T - 1) / T, T, 0, stream>>>(cnt, N);
    k_deg_int<<<(E + T - 1) / T, T, 0, stream>>>(coli, cnt, E);
    k_scan1<<<nblk, SCAN_BS, 0, stream>>>(cnt, rowptr, bsum, N);
    k_scan2<<<1, 64, 0, stream>>>(bsum, nblk, rowptr, N);
    k_scan3<<<(N + T - 1) / T, T, 0, stream>>>(rowptr, wofs, bsum, cnt, dinv, N);
    k_fill_csr<<<(E + T - 1) / T, T, 0, stream>>>(rowi, coli, wofs, csr_src, E);
    k_wfrag<<<24, 256, 0, stream>>>(W1, W2, W3, wf);

    const short* whi1 = wf;                const short* wlo1 = wf + 16384;
    const short* whi2 = wf + 32768;        const short* wlo2 = wf + 49152;
    const short* whi3 = wf + 65536;        const short* wlo3 = wf + 81920;

    const int gLayer = (N + TROWS - 1) / TROWS;

    // Layer 1: x -> B0   (per-edge dinv scaling, relu, store D̃·H1)
    k_layer<<<gLayer, T, 0, stream>>>(x, rowptr, csr_src, whi1, wlo1, dinv, b1, B0, N, 1, 0);
    // Layer 2: B0 -> B1  (plain gather, relu, store D̃·H2)
    k_layer<<<gLayer, T, 0, stream>>>(B0, rowptr, csr_src, whi2, wlo2, dinv, b2, B1, N, 0, 0);
    // Layer 3: B1 -> B0  (plain gather, no relu, store H3)
    k_layer<<<gLayer, T, 0, stream>>>(B1, rowptr, csr_src, whi3, wlo3, dinv, b3, B0, N, 0, 1);

    // Two-stage pool + fused final linear (psum aliases B1, now dead)
    k_pool_part<<<G * QSEG, 128, 0, stream>>>(B0, batch, psum, N);
    k_pool_final<<<G, 128, 0, stream>>>(psum, batch, Wl, bl, out, N, C);
}

// Round 8
// 365.808 us; speedup vs baseline: 1.5352x; 1.5352x over previous
//
#include <hip/hip_runtime.h>
#include <cstddef>

// N=100000, E=800000, H=128, C=10, G=512
#define HD 128
#define SCAN_BS 256
#define SCAN_CHUNK 2048  // 8 elements per thread
#define QSEG 8           // partial-pool blocks per graph

typedef float f32x4 __attribute__((ext_vector_type(4)));
typedef short s16x8 __attribute__((ext_vector_type(8)));
typedef unsigned short u16x4 __attribute__((ext_vector_type(4)));

static __device__ __forceinline__ int atomAddI(int* p, int v) {
    return __hip_atomic_fetch_add(p, v, __ATOMIC_RELAXED, __HIP_MEMORY_SCOPE_AGENT);
}

// round-to-nearest-even f32 -> bf16 bits
static __device__ __forceinline__ unsigned short rne_bf16(float f) {
    unsigned u = __float_as_uint(f);
    unsigned r = u + 0x7FFFu + ((u >> 16) & 1u);
    return (unsigned short)(r >> 16);
}
static __device__ __forceinline__ float bf16_to_f32(unsigned short h) {
    return __uint_as_float((unsigned)h << 16);
}

__global__ void k_zero_int(int* p, int n) {
    int i = blockIdx.x * blockDim.x + threadIdx.x;
    if (i < n) p[i] = 0;
}

__global__ void k_deg_int(const int* __restrict__ col, int* cnt, int E) {
    int e = blockIdx.x * blockDim.x + threadIdx.x;
    if (e < E) atomAddI(&cnt[col[e]], 1);
}

__global__ __launch_bounds__(SCAN_BS) void k_scan1(const int* __restrict__ cnt,
                                                   int* __restrict__ rowptr,
                                                   int* __restrict__ bsum, int n) {
    __shared__ int sd[SCAN_BS];
    const int t = threadIdx.x;
    const int base = blockIdx.x * SCAN_CHUNK + t * 8;
    int loc[8];
    int tsum = 0;
#pragma unroll
    for (int i = 0; i < 8; ++i) {
        loc[i] = (base + i < n) ? cnt[base + i] : 0;
        tsum += loc[i];
    }
    sd[t] = tsum;
    __syncthreads();
    for (int off = 1; off < SCAN_BS; off <<= 1) {
        int u = (t >= off) ? sd[t - off] : 0;
        __syncthreads();
        sd[t] += u;
        __syncthreads();
    }
    const int texc = sd[t] - tsum;
    if (t == SCAN_BS - 1) bsum[blockIdx.x] = sd[t];
    int pos = texc;
#pragma unroll
    for (int i = 0; i < 8; ++i) {
        if (base + i < n) rowptr[base + i] = pos;
        pos += loc[i];
    }
}

__global__ void k_scan2(int* bsum, int nblk, int* rowptr, int n) {
    if (threadIdx.x == 0 && blockIdx.x == 0) {
        int run = 0;
        for (int i = 0; i < nblk; ++i) { int v = bsum[i]; bsum[i] = run; run += v; }
        rowptr[n] = run;
    }
}

// rowptr += block offset; wofs = rowptr; dinv = rsqrt(1+cnt)
__global__ void k_scan3(int* rowptr, int* wofs, const int* __restrict__ bsum,
                        const int* __restrict__ cnt, float* __restrict__ dinv, int n) {
    int i = blockIdx.x * blockDim.x + threadIdx.x;
    if (i < n) {
        int v = rowptr[i] + bsum[i >> 11];  // SCAN_CHUNK = 2048
        rowptr[i] = v;
        wofs[i] = v;
        dinv[i] = rsqrtf(1.0f + (float)cnt[i]);
    }
}

__global__ void k_fill_csr(const int* __restrict__ rowi, const int* __restrict__ coli,
                           int* wofs, int* __restrict__ csr_src, int E) {
    int e = blockIdx.x * blockDim.x + threadIdx.x;
    if (e >= E) return;
    int p = atomAddI(&wofs[coli[e]], 1);
    csr_src[p] = rowi[e];
}

// Precompute W (128x128 f32) into MFMA B-fragment order, split hi/lo bf16.
// B-frag for 16x16x32: lane l holds B[k = kt*32+(l>>4)*8+e][col = nt*16+(l&15)].
__global__ __launch_bounds__(256) void k_wfrag(const float* __restrict__ W1,
                                               const float* __restrict__ W2,
                                               const float* __restrict__ W3,
                                               short* __restrict__ wf) {
    const int w = blockIdx.x >> 3;
    const int slot = (blockIdx.x & 7) * 256 + threadIdx.x;  // 0..2047
    const int nt = slot >> 8;
    const int kt = (slot >> 6) & 3;
    const int lane = slot & 63;
    const float* W = (w == 0) ? W1 : (w == 1) ? W2 : W3;
    short* whi = wf + (size_t)w * 32768;
    short* wlo = whi + 16384;
    const int obase = ((nt * 4 + kt) * 64 + lane) * 8;
    s16x8 hi8, lo8;
#pragma unroll
    for (int e = 0; e < 8; ++e) {
        const int k = kt * 32 + (lane >> 4) * 8 + e;
        const int c = nt * 16 + (lane & 15);
        const float v = W[(size_t)k * HD + c];
        const unsigned short h = rne_bf16(v);
        hi8[e] = (short)h;
        lo8[e] = (short)rne_bf16(v - bf16_to_f32(h));
    }
    *(s16x8*)&whi[obase] = hi8;
    *(s16x8*)&wlo[obase] = lo8;
}

static __device__ __forceinline__ void split8(const float* xs, s16x8& hi, s16x8& lo) {
#pragma unroll
    for (int e = 0; e < 8; ++e) {
        const unsigned short h = rne_bf16(xs[e]);
        hi[e] = (short)h;
        lo[e] = (short)rne_bf16(xs[e] - bf16_to_f32(h));
    }
}

// M = bf16( dinv ⊙ (X @ W) )  via split-bf16 MFMA (hh + lh + hl).
// Block = 4 waves; wave computes 16 rows x 128 cols; X is f32, output bf16
// messages (halves gather traffic downstream).
__global__ __launch_bounds__(256) void k_gemm(const float* __restrict__ X,
                                              const short* __restrict__ whi,
                                              const short* __restrict__ wlo,
                                              const float* __restrict__ dinv,
                                              unsigned short* __restrict__ M, int n) {
    const int lane = threadIdx.x & 63;
    const int wid = threadIdx.x >> 6;
    const int rbase = blockIdx.x * 64 + wid * 16;
    const int arow = min(rbase + (lane & 15), n - 1);
    const int kbase = (lane >> 4) * 8;

    f32x4 acc[8];
#pragma unroll
    for (int nt = 0; nt < 8; ++nt) acc[nt] = (f32x4){0.f, 0.f, 0.f, 0.f};

#pragma unroll
    for (int kt = 0; kt < 4; ++kt) {
        const float4 x0 = *(const float4*)&X[(size_t)arow * HD + kt * 32 + kbase];
        const float4 x1 = *(const float4*)&X[(size_t)arow * HD + kt * 32 + kbase + 4];
        const float xs[8] = {x0.x, x0.y, x0.z, x0.w, x1.x, x1.y, x1.z, x1.w};
        s16x8 ahi, alo;
        split8(xs, ahi, alo);
#pragma unroll
        for (int nt = 0; nt < 8; ++nt) {
            const int fo = ((nt * 4 + kt) * 64 + lane) * 8;
            const s16x8 bhi = *(const s16x8*)&whi[fo];
            const s16x8 blo = *(const s16x8*)&wlo[fo];
            acc[nt] = __builtin_amdgcn_mfma_f32_16x16x32_bf16(ahi, bhi, acc[nt], 0, 0, 0);
            acc[nt] = __builtin_amdgcn_mfma_f32_16x16x32_bf16(alo, bhi, acc[nt], 0, 0, 0);
            acc[nt] = __builtin_amdgcn_mfma_f32_16x16x32_bf16(ahi, blo, acc[nt], 0, 0, 0);
        }
    }

    // C/D layout: col = lane&15, row = (lane>>4)*4 + reg
    const int colb = lane & 15;
    const int rq = (lane >> 4) * 4;
#pragma unroll
    for (int r = 0; r < 4; ++r) {
        const int row = rbase + rq + r;
        if (row < n) {
            const float d = dinv[row];
#pragma unroll
            for (int nt = 0; nt < 8; ++nt)
                M[(size_t)row * HD + nt * 16 + colb] = rne_bf16(acc[nt][r] * d);
        }
    }
}

// OUT[i] = [relu]( dinv[i]*(M[i] + sum_{e in CSR[i]} M[src_e]) + b ),  M bf16.
// One wave per node; each 32-lane half-wave covers the full 128-col row
// (bf16x4 = 8B/lane); edges split by parity across halves; 8-edge unroll;
// cross-half combine via __shfl_xor(.,32); f32 accumulate and f32 output.
__global__ __launch_bounds__(256) void k_gather(const int* __restrict__ rowptr,
                                                const int* __restrict__ csr_src,
                                                const unsigned short* __restrict__ M,
                                                const float* __restrict__ dinv,
                                                const float* __restrict__ b,
                                                float* __restrict__ OUT,
                                                int n, int relu) {
    const int node = __builtin_amdgcn_readfirstlane(blockIdx.x * 4 + (threadIdx.x >> 6));
    if (node >= n) return;
    const int lane = threadIdx.x & 63;
    const int half = lane >> 5;
    const int j = (lane & 31) * 4;

    f32x4 acc = (f32x4){0.f, 0.f, 0.f, 0.f};
    if (half == 0) {  // self loop counted once
        const u16x4 sv = *(const u16x4*)&M[(size_t)node * HD + j];
        acc.x = bf16_to_f32(sv.x); acc.y = bf16_to_f32(sv.y);
        acc.z = bf16_to_f32(sv.z); acc.w = bf16_to_f32(sv.w);
    }

    const int s = rowptr[node];
    const int e = rowptr[node + 1];
    int k = s;
    for (; k + 8 <= e; k += 8) {
        int idx[8];
#pragma unroll
        for (int u = 0; u < 8; ++u) idx[u] = csr_src[k + u];
#pragma unroll
        for (int p = 0; p < 4; ++p) {
            const int src = idx[p * 2 + half];
            const u16x4 v = *(const u16x4*)&M[(size_t)src * HD + j];
            acc.x += bf16_to_f32(v.x); acc.y += bf16_to_f32(v.y);
            acc.z += bf16_to_f32(v.z); acc.w += bf16_to_f32(v.w);
        }
    }
    for (; k + 2 <= e; k += 2) {
        const int src = csr_src[k + half];
        const u16x4 v = *(const u16x4*)&M[(size_t)src * HD + j];
        acc.x += bf16_to_f32(v.x); acc.y += bf16_to_f32(v.y);
        acc.z += bf16_to_f32(v.z); acc.w += bf16_to_f32(v.w);
    }
    if (k < e && half == 0) {  // single leftover edge
        const int src = csr_src[k];
        const u16x4 v = *(const u16x4*)&M[(size_t)src * HD + j];
        acc.x += bf16_to_f32(v.x); acc.y += bf16_to_f32(v.y);
        acc.z += bf16_to_f32(v.z); acc.w += bf16_to_f32(v.w);
    }

    // combine halves
    acc.x += __shfl_xor(acc.x, 32);
    acc.y += __shfl_xor(acc.y, 32);
    acc.z += __shfl_xor(acc.z, 32);
    acc.w += __shfl_xor(acc.w, 32);

    if (half == 0) {
        const float d = dinv[node];
        const float4 bv = *(const float4*)&b[j];
        float ox = fmaf(acc.x, d, bv.x);
        float oy = fmaf(acc.y, d, bv.y);
        float oz = fmaf(acc.z, d, bv.z);
        float ow = fmaf(acc.w, d, bv.w);
        if (relu) {
            ox = fmaxf(ox, 0.f); oy = fmaxf(oy, 0.f);
            oz = fmaxf(oz, 0.f); ow = fmaxf(ow, 0.f);
        }
        *(float4*)&OUT[(size_t)node * HD + j] = make_float4(ox, oy, oz, ow);
    }
}

// Stage 1 pooling: QSEG blocks per graph.
__global__ __launch_bounds__(128) void k_pool_part(const float* __restrict__ X,
                                                   const int* __restrict__ batch,
                                                   float* __restrict__ psum, int n) {
    const int g = blockIdx.x / QSEG;
    const int q = blockIdx.x % QSEG;
    const int t = threadIdx.x;
    int lo = 0, hi = n;
    while (lo < hi) { int m = (lo + hi) >> 1; if (batch[m] < g) lo = m + 1; else hi = m; }
    const int start = lo;
    hi = n;
    while (lo < hi) { int m = (lo + hi) >> 1; if (batch[m] < g + 1) lo = m + 1; else hi = m; }
    const int end = lo;
    float acc = 0.f;
    for (int i = start + q; i < end; i += QSEG) acc += X[(size_t)i * HD + t];
    psum[(size_t)blockIdx.x * HD + t] = acc;
}

// Stage 2 + final linear fused.
__global__ __launch_bounds__(128) void k_pool_final(const float* __restrict__ psum,
                                                    const int* __restrict__ batch,
                                                    const float* __restrict__ Wl,
                                                    const float* __restrict__ bl,
                                                    float* __restrict__ out, int n, int C) {
    __shared__ float pl[HD];
    const int g = blockIdx.x;
    const int t = threadIdx.x;
    int lo = 0, hi = n;
    while (lo < hi) { int m = (lo + hi) >> 1; if (batch[m] < g) lo = m + 1; else hi = m; }
    const int start = lo;
    hi = n;
    while (lo < hi) { int m = (lo + hi) >> 1; if (batch[m] < g + 1) lo = m + 1; else hi = m; }
    const int cnt = lo - start;
    float acc = 0.f;
#pragma unroll
    for (int q = 0; q < QSEG; ++q)
        acc += psum[((size_t)g * QSEG + q) * HD + t];
    pl[t] = acc / (float)max(cnt, 1);
    __syncthreads();
    if (t < C) {
        float s = 0.f;
        for (int k = 0; k < HD; ++k)
            s = fmaf(pl[k], Wl[(size_t)k * C + t], s);
        out[(size_t)g * C + t] = s + bl[t];
    }
}

extern "C" void kernel_launch(void* const* d_in, const int* in_sizes, int n_in,
                              void* d_out, int out_size, void* d_ws, size_t ws_size,
                              hipStream_t stream) {
    const float* x   = (const float*)d_in[0];
    const int* ei    = (const int*)d_in[1];
    const int* batch = (const int*)d_in[2];
    const float* W1 = (const float*)d_in[3];
    const float* b1 = (const float*)d_in[4];
    const float* W2 = (const float*)d_in[5];
    const float* b2 = (const float*)d_in[6];
    const float* W3 = (const float*)d_in[7];
    const float* b3 = (const float*)d_in[8];
    const float* Wl = (const float*)d_in[9];
    const float* bl = (const float*)d_in[10];
    float* out = (float*)d_out;

    const int N = in_sizes[0] / HD;
    const int E = in_sizes[1] / 2;
    const int C = 10;
    const int G = out_size / C;

    const int* rowi = ei;      // sources
    const int* coli = ei + E;  // targets

    // workspace layout
    float* Y        = (float*)d_ws;                  // N*HD f32 (gather out / gemm in)
    unsigned short* M = (unsigned short*)(Y + (size_t)N * HD);  // N*HD bf16 messages
    float* dinv     = (float*)(M + (size_t)N * HD);  // N
    short* wf       = (short*)(dinv + N);            // 3*2*16384 shorts
    int* rowptr     = (int*)(wf + 3 * 32768);        // N+1
    int* wofs       = rowptr + (N + 1);              // N
    int* cnt        = wofs + N;                      // N
    int* bsum       = cnt + N;                       // 64
    int* csr_src    = bsum + 64;                     // E
    float* psum     = (float*)M;  // G*QSEG*HD floats — M dead after layer-3 gather

    const int T = 256;
    const int nblk = (N + SCAN_CHUNK - 1) / SCAN_CHUNK;

    // ---- preprocessing: CSR, dinv, W fragments ----
    k_zero_int<<<(N + T - 1) / T, T, 0, stream>>>(cnt, N);
    k_deg_int<<<(E + T - 1) / T, T, 0, stream>>>(coli, cnt, E);
    k_scan1<<<nblk, SCAN_BS, 0, stream>>>(cnt, rowptr, bsum, N);
    k_scan2<<<1, 64, 0, stream>>>(bsum, nblk, rowptr, N);
    k_scan3<<<(N + T - 1) / T, T, 0, stream>>>(rowptr, wofs, bsum, cnt, dinv, N);
    k_fill_csr<<<(E + T - 1) / T, T, 0, stream>>>(rowi, coli, wofs, csr_src, E);
    k_wfrag<<<24, 256, 0, stream>>>(W1, W2, W3, wf);

    const short* whi1 = wf;                const short* wlo1 = wf + 16384;
    const short* whi2 = wf + 32768;        const short* wlo2 = wf + 49152;
    const short* whi3 = wf + 65536;        const short* wlo3 = wf + 81920;

    const int gGemm   = (N + 63) / 64;
    const int gGather = (N + 3) / 4;

    // Layer 1: x --gemm--> M --gather--> Y (relu)
    k_gemm<<<gGemm, T, 0, stream>>>(x, whi1, wlo1, dinv, M, N);
    k_gather<<<gGather, T, 0, stream>>>(rowptr, csr_src, M, dinv, b1, Y, N, 1);

    // Layer 2: Y --gemm--> M --gather--> Y (relu)
    k_gemm<<<gGemm, T, 0, stream>>>(Y, whi2, wlo2, dinv, M, N);
    k_gather<<<gGather, T, 0, stream>>>(rowptr, csr_src, M, dinv, b2, Y, N, 1);

    // Layer 3: Y --gemm--> M --gather--> Y (no relu)
    k_gemm<<<gGemm, T, 0, stream>>>(Y, whi3, wlo3, dinv, M, N);
    k_gather<<<gGather, T, 0, stream>>>(rowptr, csr_src, M, dinv, b3, Y, N, 0);

    // Two-stage pool + fused final linear (psum aliases M, now dead)
    k_pool_part<<<G * QSEG, 128, 0, stream>>>(Y, batch, psum, N);
    k_pool_final<<<G, 128, 0, stream>>>(psum, batch, Wl, bl, out, N, C);
}

// Round 9
// 355.002 us; speedup vs baseline: 1.5819x; 1.0304x over previous
//
#include <hip/hip_runtime.h>
#include <cstddef>

// N=100000, E=800000, H=128, C=10, G=512
#define HD 128
#define SCAN_BS 256
#define SCAN_CHUNK 2048  // 8 elements per thread
#define QSEG 8           // partial-pool blocks per graph

typedef float f32x4 __attribute__((ext_vector_type(4)));
typedef short s16x8 __attribute__((ext_vector_type(8)));
typedef unsigned short u16x4 __attribute__((ext_vector_type(4)));

static __device__ __forceinline__ int atomAddI(int* p, int v) {
    return __hip_atomic_fetch_add(p, v, __ATOMIC_RELAXED, __HIP_MEMORY_SCOPE_AGENT);
}

// round-to-nearest-even f32 -> bf16 bits
static __device__ __forceinline__ unsigned short rne_bf16(float f) {
    unsigned u = __float_as_uint(f);
    unsigned r = u + 0x7FFFu + ((u >> 16) & 1u);
    return (unsigned short)(r >> 16);
}
static __device__ __forceinline__ float bf16_to_f32(unsigned short h) {
    return __uint_as_float((unsigned)h << 16);
}

__global__ void k_zero_int(int* p, int n) {
    int i = blockIdx.x * blockDim.x + threadIdx.x;
    if (i < n) p[i] = 0;
}

__global__ void k_deg_int(const int* __restrict__ col, int* cnt, int E) {
    int e = blockIdx.x * blockDim.x + threadIdx.x;
    if (e < E) atomAddI(&cnt[col[e]], 1);
}

__global__ __launch_bounds__(SCAN_BS) void k_scan1(const int* __restrict__ cnt,
                                                   int* __restrict__ rowptr,
                                                   int* __restrict__ bsum, int n) {
    __shared__ int sd[SCAN_BS];
    const int t = threadIdx.x;
    const int base = blockIdx.x * SCAN_CHUNK + t * 8;
    int loc[8];
    int tsum = 0;
#pragma unroll
    for (int i = 0; i < 8; ++i) {
        loc[i] = (base + i < n) ? cnt[base + i] : 0;
        tsum += loc[i];
    }
    sd[t] = tsum;
    __syncthreads();
    for (int off = 1; off < SCAN_BS; off <<= 1) {
        int u = (t >= off) ? sd[t - off] : 0;
        __syncthreads();
        sd[t] += u;
        __syncthreads();
    }
    const int texc = sd[t] - tsum;
    if (t == SCAN_BS - 1) bsum[blockIdx.x] = sd[t];
    int pos = texc;
#pragma unroll
    for (int i = 0; i < 8; ++i) {
        if (base + i < n) rowptr[base + i] = pos;
        pos += loc[i];
    }
}

__global__ void k_scan2(int* bsum, int nblk, int* rowptr, int n) {
    if (threadIdx.x == 0 && blockIdx.x == 0) {
        int run = 0;
        for (int i = 0; i < nblk; ++i) { int v = bsum[i]; bsum[i] = run; run += v; }
        rowptr[n] = run;
    }
}

// rowptr += block offset; wofs = rowptr; dinv = rsqrt(1+cnt)
__global__ void k_scan3(int* rowptr, int* wofs, const int* __restrict__ bsum,
                        const int* __restrict__ cnt, float* __restrict__ dinv, int n) {
    int i = blockIdx.x * blockDim.x + threadIdx.x;
    if (i < n) {
        int v = rowptr[i] + bsum[i >> 11];  // SCAN_CHUNK = 2048
        rowptr[i] = v;
        wofs[i] = v;
        dinv[i] = rsqrtf(1.0f + (float)cnt[i]);
    }
}

__global__ void k_fill_csr(const int* __restrict__ rowi, const int* __restrict__ coli,
                           int* wofs, int* __restrict__ csr_src, int E) {
    int e = blockIdx.x * blockDim.x + threadIdx.x;
    if (e >= E) return;
    int p = atomAddI(&wofs[coli[e]], 1);
    csr_src[p] = rowi[e];
}

// Precompute W (128x128 f32) into MFMA B-fragment order, split hi/lo bf16.
// B-frag for 16x16x32: lane l holds B[k = kt*32+(l>>4)*8+e][col = nt*16+(l&15)].
__global__ __launch_bounds__(256) void k_wfrag(const float* __restrict__ W1,
                                               const float* __restrict__ W2,
                                               const float* __restrict__ W3,
                                               short* __restrict__ wf) {
    const int w = blockIdx.x >> 3;
    const int slot = (blockIdx.x & 7) * 256 + threadIdx.x;  // 0..2047
    const int nt = slot >> 8;
    const int kt = (slot >> 6) & 3;
    const int lane = slot & 63;
    const float* W = (w == 0) ? W1 : (w == 1) ? W2 : W3;
    short* whi = wf + (size_t)w * 32768;
    short* wlo = whi + 16384;
    const int obase = ((nt * 4 + kt) * 64 + lane) * 8;
    s16x8 hi8, lo8;
#pragma unroll
    for (int e = 0; e < 8; ++e) {
        const int k = kt * 32 + (lane >> 4) * 8 + e;
        const int c = nt * 16 + (lane & 15);
        const float v = W[(size_t)k * HD + c];
        const unsigned short h = rne_bf16(v);
        hi8[e] = (short)h;
        lo8[e] = (short)rne_bf16(v - bf16_to_f32(h));
    }
    *(s16x8*)&whi[obase] = hi8;
    *(s16x8*)&wlo[obase] = lo8;
}

static __device__ __forceinline__ void split8(const float* xs, s16x8& hi, s16x8& lo) {
#pragma unroll
    for (int e = 0; e < 8; ++e) {
        const unsigned short h = rne_bf16(xs[e]);
        hi[e] = (short)h;
        lo[e] = (short)rne_bf16(xs[e] - bf16_to_f32(h));
    }
}

// M = bf16( dinv ⊙ (A @ W) )  via bf16 MFMA.
// AF32=1: A is f32 -> on-the-fly hi/lo split, 3 MFMAs (hh+lh+hl).
// AF32=0: A is bf16 -> direct fragment load, 2 MFMAs (a·Whi + a·Wlo).
// Block = 4 waves; wave computes 16 rows x 128 cols.
template <int AF32>
__global__ __launch_bounds__(256) void k_gemm(const void* __restrict__ Av,
                                              const short* __restrict__ whi,
                                              const short* __restrict__ wlo,
                                              const float* __restrict__ dinv,
                                              unsigned short* __restrict__ M, int n) {
    const int lane = threadIdx.x & 63;
    const int wid = threadIdx.x >> 6;
    const int rbase = blockIdx.x * 64 + wid * 16;
    const int arow = min(rbase + (lane & 15), n - 1);
    const int kbase = (lane >> 4) * 8;

    f32x4 acc[8];
#pragma unroll
    for (int nt = 0; nt < 8; ++nt) acc[nt] = (f32x4){0.f, 0.f, 0.f, 0.f};

#pragma unroll
    for (int kt = 0; kt < 4; ++kt) {
        s16x8 ahi, alo;
        if (AF32) {
            const float* X = (const float*)Av;
            const float4 x0 = *(const float4*)&X[(size_t)arow * HD + kt * 32 + kbase];
            const float4 x1 = *(const float4*)&X[(size_t)arow * HD + kt * 32 + kbase + 4];
            const float xs[8] = {x0.x, x0.y, x0.z, x0.w, x1.x, x1.y, x1.z, x1.w};
            split8(xs, ahi, alo);
        } else {
            const short* X = (const short*)Av;
            ahi = *(const s16x8*)&X[(size_t)arow * HD + kt * 32 + kbase];
        }
#pragma unroll
        for (int nt = 0; nt < 8; ++nt) {
            const int fo = ((nt * 4 + kt) * 64 + lane) * 8;
            const s16x8 bhi = *(const s16x8*)&whi[fo];
            const s16x8 blo = *(const s16x8*)&wlo[fo];
            acc[nt] = __builtin_amdgcn_mfma_f32_16x16x32_bf16(ahi, bhi, acc[nt], 0, 0, 0);
            acc[nt] = __builtin_amdgcn_mfma_f32_16x16x32_bf16(ahi, blo, acc[nt], 0, 0, 0);
            if (AF32)
                acc[nt] = __builtin_amdgcn_mfma_f32_16x16x32_bf16(alo, bhi, acc[nt], 0, 0, 0);
        }
    }

    // C/D layout: col = lane&15, row = (lane>>4)*4 + reg
    const int colb = lane & 15;
    const int rq = (lane >> 4) * 4;
#pragma unroll
    for (int r = 0; r < 4; ++r) {
        const int row = rbase + rq + r;
        if (row < n) {
            const float d = dinv[row];
#pragma unroll
            for (int nt = 0; nt < 8; ++nt)
                M[(size_t)row * HD + nt * 16 + colb] = rne_bf16(acc[nt][r] * d);
        }
    }
}

// OUT[i] = epi( dinv[i]*(M[i] + sum_{e in CSR[i]} M[src_e]) + b ),  M bf16.
// LAST=0: relu, bf16 output (activations for next layer's gemm).
// LAST=1: no relu, f32 output (feeds pooling).
// One wave per node; each 32-lane half-wave covers the full 128-col row
// (bf16x4 = 8B/lane); edges split by parity; f32 accumulate.
template <int LAST>
__global__ __launch_bounds__(256) void k_gather(const int* __restrict__ rowptr,
                                                const int* __restrict__ csr_src,
                                                const unsigned short* __restrict__ M,
                                                const float* __restrict__ dinv,
                                                const float* __restrict__ b,
                                                void* __restrict__ OUTv, int n) {
    const int node = __builtin_amdgcn_readfirstlane(blockIdx.x * 4 + (threadIdx.x >> 6));
    if (node >= n) return;
    const int lane = threadIdx.x & 63;
    const int half = lane >> 5;
    const int j = (lane & 31) * 4;

    f32x4 acc = (f32x4){0.f, 0.f, 0.f, 0.f};
    if (half == 0) {  // self loop counted once
        const u16x4 sv = *(const u16x4*)&M[(size_t)node * HD + j];
        acc.x = bf16_to_f32(sv.x); acc.y = bf16_to_f32(sv.y);
        acc.z = bf16_to_f32(sv.z); acc.w = bf16_to_f32(sv.w);
    }

    const int s = rowptr[node];
    const int e = rowptr[node + 1];
    int k = s;
    for (; k + 8 <= e; k += 8) {
        int idx[8];
#pragma unroll
        for (int u = 0; u < 8; ++u) idx[u] = csr_src[k + u];
#pragma unroll
        for (int p = 0; p < 4; ++p) {
            const int src = idx[p * 2 + half];
            const u16x4 v = *(const u16x4*)&M[(size_t)src * HD + j];
            acc.x += bf16_to_f32(v.x); acc.y += bf16_to_f32(v.y);
            acc.z += bf16_to_f32(v.z); acc.w += bf16_to_f32(v.w);
        }
    }
    for (; k + 2 <= e; k += 2) {
        const int src = csr_src[k + half];
        const u16x4 v = *(const u16x4*)&M[(size_t)src * HD + j];
        acc.x += bf16_to_f32(v.x); acc.y += bf16_to_f32(v.y);
        acc.z += bf16_to_f32(v.z); acc.w += bf16_to_f32(v.w);
    }
    if (k < e && half == 0) {  // single leftover edge
        const int src = csr_src[k];
        const u16x4 v = *(const u16x4*)&M[(size_t)src * HD + j];
        acc.x += bf16_to_f32(v.x); acc.y += bf16_to_f32(v.y);
        acc.z += bf16_to_f32(v.z); acc.w += bf16_to_f32(v.w);
    }

    // combine halves
    acc.x += __shfl_xor(acc.x, 32);
    acc.y += __shfl_xor(acc.y, 32);
    acc.z += __shfl_xor(acc.z, 32);
    acc.w += __shfl_xor(acc.w, 32);

    if (half == 0) {
        const float d = dinv[node];
        const float4 bv = *(const float4*)&b[j];
        float ox = fmaf(acc.x, d, bv.x);
        float oy = fmaf(acc.y, d, bv.y);
        float oz = fmaf(acc.z, d, bv.z);
        float ow = fmaf(acc.w, d, bv.w);
        if (!LAST) {
            ox = fmaxf(ox, 0.f); oy = fmaxf(oy, 0.f);
            oz = fmaxf(oz, 0.f); ow = fmaxf(ow, 0.f);
            unsigned short* OUT = (unsigned short*)OUTv;
            u16x4 o = {rne_bf16(ox), rne_bf16(oy), rne_bf16(oz), rne_bf16(ow)};
            *(u16x4*)&OUT[(size_t)node * HD + j] = o;
        } else {
            float* OUT = (float*)OUTv;
            *(float4*)&OUT[(size_t)node * HD + j] = make_float4(ox, oy, oz, ow);
        }
    }
}

// Stage 1 pooling: QSEG blocks per graph.
__global__ __launch_bounds__(128) void k_pool_part(const float* __restrict__ X,
                                                   const int* __restrict__ batch,
                                                   float* __restrict__ psum, int n) {
    const int g = blockIdx.x / QSEG;
    const int q = blockIdx.x % QSEG;
    const int t = threadIdx.x;
    int lo = 0, hi = n;
    while (lo < hi) { int m = (lo + hi) >> 1; if (batch[m] < g) lo = m + 1; else hi = m; }
    const int start = lo;
    hi = n;
    while (lo < hi) { int m = (lo + hi) >> 1; if (batch[m] < g + 1) lo = m + 1; else hi = m; }
    const int end = lo;
    float acc = 0.f;
    for (int i = start + q; i < end; i += QSEG) acc += X[(size_t)i * HD + t];
    psum[(size_t)blockIdx.x * HD + t] = acc;
}

// Stage 2 + final linear fused.
__global__ __launch_bounds__(128) void k_pool_final(const float* __restrict__ psum,
                                                    const int* __restrict__ batch,
                                                    const float* __restrict__ Wl,
                                                    const float* __restrict__ bl,
                                                    float* __restrict__ out, int n, int C) {
    __shared__ float pl[HD];
    const int g = blockIdx.x;
    const int t = threadIdx.x;
    int lo = 0, hi = n;
    while (lo < hi) { int m = (lo + hi) >> 1; if (batch[m] < g) lo = m + 1; else hi = m; }
    const int start = lo;
    hi = n;
    while (lo < hi) { int m = (lo + hi) >> 1; if (batch[m] < g + 1) lo = m + 1; else hi = m; }
    const int cnt = lo - start;
    float acc = 0.f;
#pragma unroll
    for (int q = 0; q < QSEG; ++q)
        acc += psum[((size_t)g * QSEG + q) * HD + t];
    pl[t] = acc / (float)max(cnt, 1);
    __syncthreads();
    if (t < C) {
        float s = 0.f;
        for (int k = 0; k < HD; ++k)
            s = fmaf(pl[k], Wl[(size_t)k * C + t], s);
        out[(size_t)g * C + t] = s + bl[t];
    }
}

extern "C" void kernel_launch(void* const* d_in, const int* in_sizes, int n_in,
                              void* d_out, int out_size, void* d_ws, size_t ws_size,
                              hipStream_t stream) {
    const float* x   = (const float*)d_in[0];
    const int* ei    = (const int*)d_in[1];
    const int* batch = (const int*)d_in[2];
    const float* W1 = (const float*)d_in[3];
    const float* b1 = (const float*)d_in[4];
    const float* W2 = (const float*)d_in[5];
    const float* b2 = (const float*)d_in[6];
    const float* W3 = (const float*)d_in[7];
    const float* b3 = (const float*)d_in[8];
    const float* Wl = (const float*)d_in[9];
    const float* bl = (const float*)d_in[10];
    float* out = (float*)d_out;

    const int N = in_sizes[0] / HD;
    const int E = in_sizes[1] / 2;
    const int C = 10;
    const int G = out_size / C;

    const int* rowi = ei;      // sources
    const int* coli = ei + E;  // targets

    // workspace layout
    float* Yf         = (float*)d_ws;                            // N*HD f32 (layer-3 out)
    unsigned short* M = (unsigned short*)(Yf + (size_t)N * HD);  // N*HD bf16 messages
    unsigned short* Yb = M + (size_t)N * HD;                     // N*HD bf16 activations
    float* dinv     = (float*)(Yb + (size_t)N * HD);             // N
    short* wf       = (short*)(dinv + N);            // 3*2*16384 shorts
    int* rowptr     = (int*)(wf + 3 * 32768);        // N+1
    int* wofs       = rowptr + (N + 1);              // N
    int* cnt        = wofs + N;                      // N
    int* bsum       = cnt + N;                       // 64
    int* csr_src    = bsum + 64;                     // E
    float* psum     = (float*)M;  // G*QSEG*HD floats — M dead after layer-3 gather

    const int T = 256;
    const int nblk = (N + SCAN_CHUNK - 1) / SCAN_CHUNK;

    // ---- preprocessing: CSR, dinv, W fragments ----
    k_zero_int<<<(N + T - 1) / T, T, 0, stream>>>(cnt, N);
    k_deg_int<<<(E + T - 1) / T, T, 0, stream>>>(coli, cnt, E);
    k_scan1<<<nblk, SCAN_BS, 0, stream>>>(cnt, rowptr, bsum, N);
    k_scan2<<<1, 64, 0, stream>>>(bsum, nblk, rowptr, N);
    k_scan3<<<(N + T - 1) / T, T, 0, stream>>>(rowptr, wofs, bsum, cnt, dinv, N);
    k_fill_csr<<<(E + T - 1) / T, T, 0, stream>>>(rowi, coli, wofs, csr_src, E);
    k_wfrag<<<24, 256, 0, stream>>>(W1, W2, W3, wf);

    const short* whi1 = wf;                const short* wlo1 = wf + 16384;
    const short* whi2 = wf + 32768;        const short* wlo2 = wf + 49152;
    const short* whi3 = wf + 65536;        const short* wlo3 = wf + 81920;

    const int gGemm   = (N + 63) / 64;
    const int gGather = (N + 3) / 4;

    // Layer 1: x(f32) --gemm--> M --gather--> Yb (bf16, relu)
    k_gemm<1><<<gGemm, T, 0, stream>>>(x, whi1, wlo1, dinv, M, N);
    k_gather<0><<<gGather, T, 0, stream>>>(rowptr, csr_src, M, dinv, b1, Yb, N);

    // Layer 2: Yb(bf16) --gemm--> M --gather--> Yb (bf16, relu)
    k_gemm<0><<<gGemm, T, 0, stream>>>(Yb, whi2, wlo2, dinv, M, N);
    k_gather<0><<<gGather, T, 0, stream>>>(rowptr, csr_src, M, dinv, b2, Yb, N);

    // Layer 3: Yb(bf16) --gemm--> M --gather--> Yf (f32, no relu)
    k_gemm<0><<<gGemm, T, 0, stream>>>(Yb, whi3, wlo3, dinv, M, N);
    k_gather<1><<<gGather, T, 0, stream>>>(rowptr, csr_src, M, dinv, b3, Yf, N);

    // Two-stage pool + fused final linear (psum aliases M, now dead)
    k_pool_part<<<G * QSEG, 128, 0, stream>>>(Yf, batch, psum, N);
    k_pool_final<<<G, 128, 0, stream>>>(psum, batch, Wl, bl, out, N, C);
}

// Round 10
// 342.740 us; speedup vs baseline: 1.6385x; 1.0358x over previous
//
#include <hip/hip_runtime.h>
#include <cstddef>

// N=100000, E=800000, H=128, C=10, G=512
#define HD 128
#define QSEG 8      // partial-pool blocks per graph
#define BSH 7       // bucket shift: 128 dsts per bucket
#define NBP 1024    // padded bucket-array size (>= NB)
#define EB 4096     // edges per k_bin block

typedef float f32x4 __attribute__((ext_vector_type(4)));
typedef short s16x8 __attribute__((ext_vector_type(8)));
typedef unsigned short u16x4 __attribute__((ext_vector_type(4)));

static __device__ __forceinline__ int atomAddI(int* p, int v) {
    return __hip_atomic_fetch_add(p, v, __ATOMIC_RELAXED, __HIP_MEMORY_SCOPE_AGENT);
}

// round-to-nearest-even f32 -> bf16 bits
static __device__ __forceinline__ unsigned short rne_bf16(float f) {
    unsigned u = __float_as_uint(f);
    unsigned r = u + 0x7FFFu + ((u >> 16) & 1u);
    return (unsigned short)(r >> 16);
}
static __device__ __forceinline__ float bf16_to_f32(unsigned short h) {
    return __uint_as_float((unsigned)h << 16);
}

__global__ void k_zero_int(int* p, int n) {
    int i = blockIdx.x * blockDim.x + threadIdx.x;
    if (i < n) p[i] = 0;
}

// Coarse histogram of dst buckets (dst>>BSH) via per-block LDS staging.
__global__ __launch_bounds__(256) void k_bhist(const int* __restrict__ coli,
                                               int* __restrict__ bcnt, int E, int NB) {
    __shared__ int lc[NBP];
    for (int b = threadIdx.x; b < NBP; b += 256) lc[b] = 0;
    __syncthreads();
    const int base = blockIdx.x * (EB * 2);
    const int end = min(base + EB * 2, E);
    for (int i = base + threadIdx.x; i < end; i += 256)
        atomicAdd(&lc[coli[i] >> BSH], 1);
    __syncthreads();
    for (int b = threadIdx.x; b < NB; b += 256)
        if (lc[b]) atomAddI(&bcnt[b], lc[b]);
}

// Serial scan of bucket counts -> bbase (segment starts) + cursor copy;
// bbase[NB] = E; rowptr[N] = E.
__global__ void k_bscan(const int* __restrict__ bcnt, int* __restrict__ bbase,
                        int* __restrict__ cursor, int* __restrict__ rowptr,
                        int NB, int E, int N) {
    if (threadIdx.x == 0 && blockIdx.x == 0) {
        int run = 0;
        for (int j = 0; j < NB; ++j) {
            bbase[j] = run;
            cursor[j] = run;
            run += bcnt[j];
        }
        bbase[NB] = run;
        rowptr[N] = run;  // == E
    }
}

// Bin edges into bucket-grouped (src,dst) pairs. Per-block LDS histogram,
// one reservation atomic per (block,bucket), then 8B pair writes into the
// reserved contiguous runs (~2x writeback inflation vs 16x for 4B scatter).
__global__ __launch_bounds__(256) void k_bin(const int* __restrict__ rowi,
                                             const int* __restrict__ coli,
                                             int* __restrict__ cursor,
                                             uint2* __restrict__ pairs, int E, int NB) {
    __shared__ int lcnt[NBP];
    __shared__ int gbs[NBP];
    const int t = threadIdx.x;
    const int base = blockIdx.x * EB;
    for (int b = t; b < NBP; b += 256) lcnt[b] = 0;
    __syncthreads();

    uint2 ed[16];
    int eb[16];
#pragma unroll
    for (int u = 0; u < 16; ++u) {
        const int idx = base + u * 256 + t;
        if (idx < E) {
            ed[u].x = (unsigned)rowi[idx];
            ed[u].y = (unsigned)coli[idx];
            eb[u] = (int)(ed[u].y >> BSH);
            atomicAdd(&lcnt[eb[u]], 1);
        } else {
            eb[u] = -1;
        }
    }
    __syncthreads();
    for (int b = t; b < NB; b += 256) {
        const int c = lcnt[b];
        gbs[b] = c > 0 ? atomAddI(&cursor[b], c) : 0;
    }
    __syncthreads();
    for (int b = t; b < NBP; b += 256) lcnt[b] = 0;
    __syncthreads();
#pragma unroll
    for (int u = 0; u < 16; ++u) {
        if (eb[u] >= 0) {
            const int p = gbs[eb[u]] + atomicAdd(&lcnt[eb[u]], 1);
            pairs[p] = ed[u];
        }
    }
}

// One block per bucket: exact CSR for its 128 dsts.
// Pass 1: LDS histogram of bucket pairs -> write rowptr/dinv coalesced.
// Pass 2: scatter src into the bucket's contiguous CSR segment (~8KB,
// single-block/XCD-local -> clean writeback).
__global__ __launch_bounds__(256) void k_sortbuild(const uint2* __restrict__ pairs,
                                                   const int* __restrict__ bbase,
                                                   int* __restrict__ rowptr,
                                                   float* __restrict__ dinv,
                                                   int* __restrict__ csr_src, int N) {
    __shared__ int cnt[128];
    __shared__ int pref[128];
    const int j = blockIdx.x;
    const int t = threadIdx.x;
    const int s = bbase[j];
    const int e2 = bbase[j + 1];
    const int d0 = j << BSH;
    const int dc = min(128, N - d0);

    if (t < 128) cnt[t] = 0;
    __syncthreads();
    for (int i = s + t; i < e2; i += 256)
        atomicAdd(&cnt[pairs[i].y - (unsigned)d0], 1);
    __syncthreads();
    if (t == 0) {
        int run = 0;
        for (int k = 0; k < 128; ++k) { pref[k] = run; run += cnt[k]; }
    }
    __syncthreads();
    if (t < dc) {
        rowptr[d0 + t] = s + pref[t];
        dinv[d0 + t] = rsqrtf(1.0f + (float)cnt[t]);
    }
    __syncthreads();
    if (t < 128) cnt[t] = 0;
    __syncthreads();
    for (int i = s + t; i < e2; i += 256) {
        const uint2 p = pairs[i];
        const int dl = (int)(p.y - (unsigned)d0);
        const int pos = atomicAdd(&cnt[dl], 1);
        csr_src[s + pref[dl] + pos] = (int)p.x;
    }
}

// Precompute W (128x128 f32) into MFMA B-fragment order, split hi/lo bf16.
// B-frag for 16x16x32: lane l holds B[k = kt*32+(l>>4)*8+e][col = nt*16+(l&15)].
__global__ __launch_bounds__(256) void k_wfrag(const float* __restrict__ W1,
                                               const float* __restrict__ W2,
                                               const float* __restrict__ W3,
                                               short* __restrict__ wf) {
    const int w = blockIdx.x >> 3;
    const int slot = (blockIdx.x & 7) * 256 + threadIdx.x;  // 0..2047
    const int nt = slot >> 8;
    const int kt = (slot >> 6) & 3;
    const int lane = slot & 63;
    const float* W = (w == 0) ? W1 : (w == 1) ? W2 : W3;
    short* whi = wf + (size_t)w * 32768;
    short* wlo = whi + 16384;
    const int obase = ((nt * 4 + kt) * 64 + lane) * 8;
    s16x8 hi8, lo8;
#pragma unroll
    for (int e = 0; e < 8; ++e) {
        const int k = kt * 32 + (lane >> 4) * 8 + e;
        const int c = nt * 16 + (lane & 15);
        const float v = W[(size_t)k * HD + c];
        const unsigned short h = rne_bf16(v);
        hi8[e] = (short)h;
        lo8[e] = (short)rne_bf16(v - bf16_to_f32(h));
    }
    *(s16x8*)&whi[obase] = hi8;
    *(s16x8*)&wlo[obase] = lo8;
}

static __device__ __forceinline__ void split8(const float* xs, s16x8& hi, s16x8& lo) {
#pragma unroll
    for (int e = 0; e < 8; ++e) {
        const unsigned short h = rne_bf16(xs[e]);
        hi[e] = (short)h;
        lo[e] = (short)rne_bf16(xs[e] - bf16_to_f32(h));
    }
}

// M = bf16( dinv ⊙ (A @ W) )  via bf16 MFMA.
// AF32=1: A is f32 -> on-the-fly hi/lo split, 3 MFMAs (hh+lh+hl).
// AF32=0: A is bf16 -> direct fragment load, 2 MFMAs (a·Whi + a·Wlo).
// Block = 4 waves; wave computes 16 rows x 128 cols.
template <int AF32>
__global__ __launch_bounds__(256) void k_gemm(const void* __restrict__ Av,
                                              const short* __restrict__ whi,
                                              const short* __restrict__ wlo,
                                              const float* __restrict__ dinv,
                                              unsigned short* __restrict__ M, int n) {
    const int lane = threadIdx.x & 63;
    const int wid = threadIdx.x >> 6;
    const int rbase = blockIdx.x * 64 + wid * 16;
    const int arow = min(rbase + (lane & 15), n - 1);
    const int kbase = (lane >> 4) * 8;

    f32x4 acc[8];
#pragma unroll
    for (int nt = 0; nt < 8; ++nt) acc[nt] = (f32x4){0.f, 0.f, 0.f, 0.f};

#pragma unroll
    for (int kt = 0; kt < 4; ++kt) {
        s16x8 ahi, alo;
        if (AF32) {
            const float* X = (const float*)Av;
            const float4 x0 = *(const float4*)&X[(size_t)arow * HD + kt * 32 + kbase];
            const float4 x1 = *(const float4*)&X[(size_t)arow * HD + kt * 32 + kbase + 4];
            const float xs[8] = {x0.x, x0.y, x0.z, x0.w, x1.x, x1.y, x1.z, x1.w};
            split8(xs, ahi, alo);
        } else {
            const short* X = (const short*)Av;
            ahi = *(const s16x8*)&X[(size_t)arow * HD + kt * 32 + kbase];
        }
#pragma unroll
        for (int nt = 0; nt < 8; ++nt) {
            const int fo = ((nt * 4 + kt) * 64 + lane) * 8;
            const s16x8 bhi = *(const s16x8*)&whi[fo];
            const s16x8 blo = *(const s16x8*)&wlo[fo];
            acc[nt] = __builtin_amdgcn_mfma_f32_16x16x32_bf16(ahi, bhi, acc[nt], 0, 0, 0);
            acc[nt] = __builtin_amdgcn_mfma_f32_16x16x32_bf16(ahi, blo, acc[nt], 0, 0, 0);
            if (AF32)
                acc[nt] = __builtin_amdgcn_mfma_f32_16x16x32_bf16(alo, bhi, acc[nt], 0, 0, 0);
        }
    }

    // C/D layout: col = lane&15, row = (lane>>4)*4 + reg
    const int colb = lane & 15;
    const int rq = (lane >> 4) * 4;
#pragma unroll
    for (int r = 0; r < 4; ++r) {
        const int row = rbase + rq + r;
        if (row < n) {
            const float d = dinv[row];
#pragma unroll
            for (int nt = 0; nt < 8; ++nt)
                M[(size_t)row * HD + nt * 16 + colb] = rne_bf16(acc[nt][r] * d);
        }
    }
}

// OUT[i] = epi( dinv[i]*(M[i] + sum_{e in CSR[i]} M[src_e]) + b ),  M bf16.
// LAST=0: relu, bf16 output.  LAST=1: no relu, f32 output (feeds pooling).
template <int LAST>
__global__ __launch_bounds__(256) void k_gather(const int* __restrict__ rowptr,
                                                const int* __restrict__ csr_src,
                                                const unsigned short* __restrict__ M,
                                                const float* __restrict__ dinv,
                                                const float* __restrict__ b,
                                                void* __restrict__ OUTv, int n) {
    const int node = __builtin_amdgcn_readfirstlane(blockIdx.x * 4 + (threadIdx.x >> 6));
    if (node >= n) return;
    const int lane = threadIdx.x & 63;
    const int half = lane >> 5;
    const int j = (lane & 31) * 4;

    f32x4 acc = (f32x4){0.f, 0.f, 0.f, 0.f};
    if (half == 0) {  // self loop counted once
        const u16x4 sv = *(const u16x4*)&M[(size_t)node * HD + j];
        acc.x = bf16_to_f32(sv.x); acc.y = bf16_to_f32(sv.y);
        acc.z = bf16_to_f32(sv.z); acc.w = bf16_to_f32(sv.w);
    }

    const int s = rowptr[node];
    const int e = rowptr[node + 1];
    int k = s;
    for (; k + 8 <= e; k += 8) {
        int idx[8];
#pragma unroll
        for (int u = 0; u < 8; ++u) idx[u] = csr_src[k + u];
#pragma unroll
        for (int p = 0; p < 4; ++p) {
            const int src = idx[p * 2 + half];
            const u16x4 v = *(const u16x4*)&M[(size_t)src * HD + j];
            acc.x += bf16_to_f32(v.x); acc.y += bf16_to_f32(v.y);
            acc.z += bf16_to_f32(v.z); acc.w += bf16_to_f32(v.w);
        }
    }
    for (; k + 2 <= e; k += 2) {
        const int src = csr_src[k + half];
        const u16x4 v = *(const u16x4*)&M[(size_t)src * HD + j];
        acc.x += bf16_to_f32(v.x); acc.y += bf16_to_f32(v.y);
        acc.z += bf16_to_f32(v.z); acc.w += bf16_to_f32(v.w);
    }
    if (k < e && half == 0) {  // single leftover edge
        const int src = csr_src[k];
        const u16x4 v = *(const u16x4*)&M[(size_t)src * HD + j];
        acc.x += bf16_to_f32(v.x); acc.y += bf16_to_f32(v.y);
        acc.z += bf16_to_f32(v.z); acc.w += bf16_to_f32(v.w);
    }

    acc.x += __shfl_xor(acc.x, 32);
    acc.y += __shfl_xor(acc.y, 32);
    acc.z += __shfl_xor(acc.z, 32);
    acc.w += __shfl_xor(acc.w, 32);

    if (half == 0) {
        const float d = dinv[node];
        const float4 bv = *(const float4*)&b[j];
        float ox = fmaf(acc.x, d, bv.x);
        float oy = fmaf(acc.y, d, bv.y);
        float oz = fmaf(acc.z, d, bv.z);
        float ow = fmaf(acc.w, d, bv.w);
        if (!LAST) {
            ox = fmaxf(ox, 0.f); oy = fmaxf(oy, 0.f);
            oz = fmaxf(oz, 0.f); ow = fmaxf(ow, 0.f);
            unsigned short* OUT = (unsigned short*)OUTv;
            u16x4 o = {rne_bf16(ox), rne_bf16(oy), rne_bf16(oz), rne_bf16(ow)};
            *(u16x4*)&OUT[(size_t)node * HD + j] = o;
        } else {
            float* OUT = (float*)OUTv;
            *(float4*)&OUT[(size_t)node * HD + j] = make_float4(ox, oy, oz, ow);
        }
    }
}

// Stage 1 pooling: QSEG blocks per graph.
__global__ __launch_bounds__(128) void k_pool_part(const float* __restrict__ X,
                                                   const int* __restrict__ batch,
                                                   float* __restrict__ psum, int n) {
    const int g = blockIdx.x / QSEG;
    const int q = blockIdx.x % QSEG;
    const int t = threadIdx.x;
    int lo = 0, hi = n;
    while (lo < hi) { int m = (lo + hi) >> 1; if (batch[m] < g) lo = m + 1; else hi = m; }
    const int start = lo;
    hi = n;
    while (lo < hi) { int m = (lo + hi) >> 1; if (batch[m] < g + 1) lo = m + 1; else hi = m; }
    const int end = lo;
    float acc = 0.f;
    for (int i = start + q; i < end; i += QSEG) acc += X[(size_t)i * HD + t];
    psum[(size_t)blockIdx.x * HD + t] = acc;
}

// Stage 2 + final linear fused.
__global__ __launch_bounds__(128) void k_pool_final(const float* __restrict__ psum,
                                                    const int* __restrict__ batch,
                                                    const float* __restrict__ Wl,
                                                    const float* __restrict__ bl,
                                                    float* __restrict__ out, int n, int C) {
    __shared__ float pl[HD];
    const int g = blockIdx.x;
    const int t = threadIdx.x;
    int lo = 0, hi = n;
    while (lo < hi) { int m = (lo + hi) >> 1; if (batch[m] < g) lo = m + 1; else hi = m; }
    const int start = lo;
    hi = n;
    while (lo < hi) { int m = (lo + hi) >> 1; if (batch[m] < g + 1) lo = m + 1; else hi = m; }
    const int cnt = lo - start;
    float acc = 0.f;
#pragma unroll
    for (int q = 0; q < QSEG; ++q)
        acc += psum[((size_t)g * QSEG + q) * HD + t];
    pl[t] = acc / (float)max(cnt, 1);
    __syncthreads();
    if (t < C) {
        float s = 0.f;
        for (int k = 0; k < HD; ++k)
            s = fmaf(pl[k], Wl[(size_t)k * C + t], s);
        out[(size_t)g * C + t] = s + bl[t];
    }
}

extern "C" void kernel_launch(void* const* d_in, const int* in_sizes, int n_in,
                              void* d_out, int out_size, void* d_ws, size_t ws_size,
                              hipStream_t stream) {
    const float* x   = (const float*)d_in[0];
    const int* ei    = (const int*)d_in[1];
    const int* batch = (const int*)d_in[2];
    const float* W1 = (const float*)d_in[3];
    const float* b1 = (const float*)d_in[4];
    const float* W2 = (const float*)d_in[5];
    const float* b2 = (const float*)d_in[6];
    const float* W3 = (const float*)d_in[7];
    const float* b3 = (const float*)d_in[8];
    const float* Wl = (const float*)d_in[9];
    const float* bl = (const float*)d_in[10];
    float* out = (float*)d_out;

    const int N = in_sizes[0] / HD;
    const int E = in_sizes[1] / 2;
    const int C = 10;
    const int G = out_size / C;
    const int NB = (N + 127) >> BSH;  // 128-dst buckets

    const int* rowi = ei;      // sources
    const int* coli = ei + E;  // targets

    // workspace layout
    float* Yf         = (float*)d_ws;                            // N*HD f32 (layer-3 out)
    unsigned short* M = (unsigned short*)(Yf + (size_t)N * HD);  // N*HD bf16 messages
    unsigned short* Yb = M + (size_t)N * HD;                     // N*HD bf16 activations
    float* dinv     = (float*)(Yb + (size_t)N * HD);             // N
    short* wf       = (short*)(dinv + N);            // 3*2*16384 shorts
    int* rowptr     = (int*)(wf + 3 * 32768);        // N+1
    int* bcnt       = rowptr + (N + 1);              // NB
    int* bbase      = bcnt + NB;                     // NB+1
    int* cursor     = bbase + (NB + 1);              // NB
    int* csr_src    = cursor + NB;                   // E
    uint2* pairs    = (uint2*)M;   // E uint2 (6.4MB) — M unused until layer 1
    float* psum     = (float*)M;   // pooling scratch — M dead after layer-3 gather

    const int T = 256;

    // ---- preprocessing: bucketed CSR build + dinv + W fragments ----
    k_zero_int<<<(NB + T - 1) / T, T, 0, stream>>>(bcnt, NB);
    k_bhist<<<(E + EB * 2 - 1) / (EB * 2), T, 0, stream>>>(coli, bcnt, E, NB);
    k_bscan<<<1, 64, 0, stream>>>(bcnt, bbase, cursor, rowptr, NB, E, N);
    k_bin<<<(E + EB - 1) / EB, T, 0, stream>>>(rowi, coli, cursor, pairs, E, NB);
    k_sortbuild<<<NB, T, 0, stream>>>(pairs, bbase, rowptr, dinv, csr_src, N);
    k_wfrag<<<24, 256, 0, stream>>>(W1, W2, W3, wf);

    const short* whi1 = wf;                const short* wlo1 = wf + 16384;
    const short* whi2 = wf + 32768;        const short* wlo2 = wf + 49152;
    const short* whi3 = wf + 65536;        const short* wlo3 = wf + 81920;

    const int gGemm   = (N + 63) / 64;
    const int gGather = (N + 3) / 4;

    // Layer 1: x(f32) --gemm--> M --gather--> Yb (bf16, relu)
    k_gemm<1><<<gGemm, T, 0, stream>>>(x, whi1, wlo1, dinv, M, N);
    k_gather<0><<<gGather, T, 0, stream>>>(rowptr, csr_src, M, dinv, b1, Yb, N);

    // Layer 2: Yb(bf16) --gemm--> M --gather--> Yb (bf16, relu)
    k_gemm<0><<<gGemm, T, 0, stream>>>(Yb, whi2, wlo2, dinv, M, N);
    k_gather<0><<<gGather, T, 0, stream>>>(rowptr, csr_src, M, dinv, b2, Yb, N);

    // Layer 3: Yb(bf16) --gemm--> M --gather--> Yf (f32, no relu)
    k_gemm<0><<<gGemm, T, 0, stream>>>(Yb, whi3, wlo3, dinv, M, N);
    k_gather<1><<<gGather, T, 0, stream>>>(rowptr, csr_src, M, dinv, b3, Yf, N);

    // Two-stage pool + fused final linear (psum aliases M, now dead)
    k_pool_part<<<G * QSEG, 128, 0, stream>>>(Yf, batch, psum, N);
    k_pool_final<<<G, 128, 0, stream>>>(psum, batch, Wl, bl, out, N, C);
}

// Round 11
// 335.074 us; speedup vs baseline: 1.6760x; 1.0229x over previous
//
#include <hip/hip_runtime.h>
#include <cstddef>

// N=100000, E=800000, H=128, C=10, G=512
#define HD 128
#define QSEG 8      // partial-pool blocks per graph
#define BSH 7       // bucket shift: 128 dsts per bucket
#define NBP 1024    // padded bucket-array size (>= NB)
#define EB 4096     // edges per k_bin block

// Permuted storage layout for all hidden N x 128 arrays (M, Yb, Yf):
//   storage index s holds logical column c(s) = (s%8)*16 + s/8
//   inverse: s(c) = (c%16)*8 + c/16
// Chosen so the MFMA C/D fragment (col = nt*16 + lane&15) maps to 8
// contiguous shorts per (lane, r): s = (lane&15)*8 + nt  -> coalesced
// 16B stores. Layer>=2 A-fragments read contiguous storage and the K
// relabeling k_log = e*16 + kt*4 + (lane>>4) is baked into the W fragments
// (K-permutation is free as long as A and B fragments agree positionally).

typedef float f32x4 __attribute__((ext_vector_type(4)));
typedef short s16x8 __attribute__((ext_vector_type(8)));
typedef unsigned short u16x4 __attribute__((ext_vector_type(4)));
typedef unsigned short u16x8 __attribute__((ext_vector_type(8)));

static __device__ __forceinline__ int atomAddI(int* p, int v) {
    return __hip_atomic_fetch_add(p, v, __ATOMIC_RELAXED, __HIP_MEMORY_SCOPE_AGENT);
}

// round-to-nearest-even f32 -> bf16 bits
static __device__ __forceinline__ unsigned short rne_bf16(float f) {
    unsigned u = __float_as_uint(f);
    unsigned r = u + 0x7FFFu + ((u >> 16) & 1u);
    return (unsigned short)(r >> 16);
}
static __device__ __forceinline__ float bf16_to_f32(unsigned short h) {
    return __uint_as_float((unsigned)h << 16);
}

__global__ void k_zero_int(int* p, int n) {
    int i = blockIdx.x * blockDim.x + threadIdx.x;
    if (i < n) p[i] = 0;
}

// Coarse histogram of dst buckets (dst>>BSH) via per-block LDS staging.
__global__ __launch_bounds__(256) void k_bhist(const int* __restrict__ coli,
                                               int* __restrict__ bcnt, int E, int NB) {
    __shared__ int lc[NBP];
    for (int b = threadIdx.x; b < NBP; b += 256) lc[b] = 0;
    __syncthreads();
    const int base = blockIdx.x * (EB * 2);
    const int end = min(base + EB * 2, E);
    for (int i = base + threadIdx.x; i < end; i += 256)
        atomicAdd(&lc[coli[i] >> BSH], 1);
    __syncthreads();
    for (int b = threadIdx.x; b < NB; b += 256)
        if (lc[b]) atomAddI(&bcnt[b], lc[b]);
}

// Serial scan of bucket counts -> bbase (segment starts) + cursor copy.
__global__ void k_bscan(const int* __restrict__ bcnt, int* __restrict__ bbase,
                        int* __restrict__ cursor, int* __restrict__ rowptr,
                        int NB, int E, int N) {
    if (threadIdx.x == 0 && blockIdx.x == 0) {
        int run = 0;
        for (int j = 0; j < NB; ++j) {
            bbase[j] = run;
            cursor[j] = run;
            run += bcnt[j];
        }
        bbase[NB] = run;
        rowptr[N] = run;  // == E
    }
}

// Bin edges into bucket-grouped (src,dst) pairs.
__global__ __launch_bounds__(256) void k_bin(const int* __restrict__ rowi,
                                             const int* __restrict__ coli,
                                             int* __restrict__ cursor,
                                             uint2* __restrict__ pairs, int E, int NB) {
    __shared__ int lcnt[NBP];
    __shared__ int gbs[NBP];
    const int t = threadIdx.x;
    const int base = blockIdx.x * EB;
    for (int b = t; b < NBP; b += 256) lcnt[b] = 0;
    __syncthreads();

    uint2 ed[16];
    int eb[16];
#pragma unroll
    for (int u = 0; u < 16; ++u) {
        const int idx = base + u * 256 + t;
        if (idx < E) {
            ed[u].x = (unsigned)rowi[idx];
            ed[u].y = (unsigned)coli[idx];
            eb[u] = (int)(ed[u].y >> BSH);
            atomicAdd(&lcnt[eb[u]], 1);
        } else {
            eb[u] = -1;
        }
    }
    __syncthreads();
    for (int b = t; b < NB; b += 256) {
        const int c = lcnt[b];
        gbs[b] = c > 0 ? atomAddI(&cursor[b], c) : 0;
    }
    __syncthreads();
    for (int b = t; b < NBP; b += 256) lcnt[b] = 0;
    __syncthreads();
#pragma unroll
    for (int u = 0; u < 16; ++u) {
        if (eb[u] >= 0) {
            const int p = gbs[eb[u]] + atomicAdd(&lcnt[eb[u]], 1);
            pairs[p] = ed[u];
        }
    }
}

// One block per bucket: exact CSR for its 128 dsts.
__global__ __launch_bounds__(256) void k_sortbuild(const uint2* __restrict__ pairs,
                                                   const int* __restrict__ bbase,
                                                   int* __restrict__ rowptr,
                                                   float* __restrict__ dinv,
                                                   int* __restrict__ csr_src, int N) {
    __shared__ int cnt[128];
    __shared__ int pref[128];
    const int j = blockIdx.x;
    const int t = threadIdx.x;
    const int s = bbase[j];
    const int e2 = bbase[j + 1];
    const int d0 = j << BSH;
    const int dc = min(128, N - d0);

    if (t < 128) cnt[t] = 0;
    __syncthreads();
    for (int i = s + t; i < e2; i += 256)
        atomicAdd(&cnt[pairs[i].y - (unsigned)d0], 1);
    __syncthreads();
    if (t == 0) {
        int run = 0;
        for (int k = 0; k < 128; ++k) { pref[k] = run; run += cnt[k]; }
    }
    __syncthreads();
    if (t < dc) {
        rowptr[d0 + t] = s + pref[t];
        dinv[d0 + t] = rsqrtf(1.0f + (float)cnt[t]);
    }
    __syncthreads();
    if (t < 128) cnt[t] = 0;
    __syncthreads();
    for (int i = s + t; i < e2; i += 256) {
        const uint2 p = pairs[i];
        const int dl = (int)(p.y - (unsigned)d0);
        const int pos = atomicAdd(&cnt[dl], 1);
        csr_src[s + pref[dl] + pos] = (int)p.x;
    }
}

// Precompute W into MFMA B-fragment order, split hi/lo bf16.
// w==0 (layer 1, natural-layout A=x): k = kt*32 + (lane>>4)*8 + e.
// w>=1 (permuted-storage A):          k = e*16 + kt*4 + (lane>>4).
__global__ __launch_bounds__(256) void k_wfrag(const float* __restrict__ W1,
                                               const float* __restrict__ W2,
                                               const float* __restrict__ W3,
                                               short* __restrict__ wf) {
    const int w = blockIdx.x >> 3;
    const int slot = (blockIdx.x & 7) * 256 + threadIdx.x;  // 0..2047
    const int nt = slot >> 8;
    const int kt = (slot >> 6) & 3;
    const int lane = slot & 63;
    const float* W = (w == 0) ? W1 : (w == 1) ? W2 : W3;
    short* whi = wf + (size_t)w * 32768;
    short* wlo = whi + 16384;
    const int obase = ((nt * 4 + kt) * 64 + lane) * 8;
    const int c = nt * 16 + (lane & 15);
    s16x8 hi8, lo8;
#pragma unroll
    for (int e = 0; e < 8; ++e) {
        const int k = (w == 0) ? (kt * 32 + (lane >> 4) * 8 + e)
                               : (e * 16 + kt * 4 + (lane >> 4));
        const float v = W[(size_t)k * HD + c];
        const unsigned short h = rne_bf16(v);
        hi8[e] = (short)h;
        lo8[e] = (short)rne_bf16(v - bf16_to_f32(h));
    }
    *(s16x8*)&whi[obase] = hi8;
    *(s16x8*)&wlo[obase] = lo8;
}

// Permute the three bias vectors into storage order: bp[s] = b[(s%8)*16 + s/8].
__global__ void k_bprep(const float* __restrict__ b1, const float* __restrict__ b2,
                        const float* __restrict__ b3, float* __restrict__ bp) {
    const int t = threadIdx.x;  // 128
    const float* b = (blockIdx.x == 0) ? b1 : (blockIdx.x == 1) ? b2 : b3;
    bp[blockIdx.x * HD + t] = b[(t & 7) * 16 + (t >> 3)];
}

static __device__ __forceinline__ void split8(const float* xs, s16x8& hi, s16x8& lo) {
#pragma unroll
    for (int e = 0; e < 8; ++e) {
        const unsigned short h = rne_bf16(xs[e]);
        hi[e] = (short)h;
        lo[e] = (short)rne_bf16(xs[e] - bf16_to_f32(h));
    }
}

// M = bf16( dinv ⊙ (A @ W) ) in PERMUTED storage, via bf16 MFMA.
// AF32=1: A f32 natural layout -> split, 3 MFMAs.  AF32=0: A bf16 permuted
// storage -> direct contiguous fragment load, 2 MFMAs.
// Epilogue: per (lane,r) the 8 nt-values are contiguous in storage ->
// one u16x8 (16B) store; a wave's store instr covers 4 full 256B rows.
template <int AF32>
__global__ __launch_bounds__(256) void k_gemm(const void* __restrict__ Av,
                                              const short* __restrict__ whi,
                                              const short* __restrict__ wlo,
                                              const float* __restrict__ dinv,
                                              unsigned short* __restrict__ M, int n) {
    const int lane = threadIdx.x & 63;
    const int wid = threadIdx.x >> 6;
    const int rbase = blockIdx.x * 64 + wid * 16;
    const int arow = min(rbase + (lane & 15), n - 1);
    const int kbase = (lane >> 4) * 8;

    f32x4 acc[8];
#pragma unroll
    for (int nt = 0; nt < 8; ++nt) acc[nt] = (f32x4){0.f, 0.f, 0.f, 0.f};

#pragma unroll
    for (int kt = 0; kt < 4; ++kt) {
        s16x8 ahi, alo;
        if (AF32) {
            const float* X = (const float*)Av;
            const float4 x0 = *(const float4*)&X[(size_t)arow * HD + kt * 32 + kbase];
            const float4 x1 = *(const float4*)&X[(size_t)arow * HD + kt * 32 + kbase + 4];
            const float xs[8] = {x0.x, x0.y, x0.z, x0.w, x1.x, x1.y, x1.z, x1.w};
            split8(xs, ahi, alo);
        } else {
            const short* X = (const short*)Av;
            ahi = *(const s16x8*)&X[(size_t)arow * HD + kt * 32 + kbase];
        }
#pragma unroll
        for (int nt = 0; nt < 8; ++nt) {
            const int fo = ((nt * 4 + kt) * 64 + lane) * 8;
            const s16x8 bhi = *(const s16x8*)&whi[fo];
            const s16x8 blo = *(const s16x8*)&wlo[fo];
            acc[nt] = __builtin_amdgcn_mfma_f32_16x16x32_bf16(ahi, bhi, acc[nt], 0, 0, 0);
            acc[nt] = __builtin_amdgcn_mfma_f32_16x16x32_bf16(ahi, blo, acc[nt], 0, 0, 0);
            if (AF32)
                acc[nt] = __builtin_amdgcn_mfma_f32_16x16x32_bf16(alo, bhi, acc[nt], 0, 0, 0);
        }
    }

    // C/D: row = (lane>>4)*4 + r, logical col = nt*16+(lane&15)
    //  -> storage s = (lane&15)*8 + nt  (contiguous over nt)
    const int colb = lane & 15;
    const int rq = (lane >> 4) * 4;
#pragma unroll
    for (int r = 0; r < 4; ++r) {
        const int row = rbase + rq + r;
        if (row < n) {
            const float d = dinv[row];
            u16x8 o;
#pragma unroll
            for (int nt = 0; nt < 8; ++nt) o[nt] = rne_bf16(acc[nt][r] * d);
            *(u16x8*)&M[(size_t)row * HD + colb * 8] = o;
        }
    }
}

// OUT[i] = epi( dinv[i]*(M[i] + sum_{e in CSR[i]} M[src_e]) + b ).
// Purely positional over the permuted storage; b must be pre-permuted.
// LAST=0: relu, bf16 output.  LAST=1: no relu, f32 output (feeds pooling).
template <int LAST>
__global__ __launch_bounds__(256) void k_gather(const int* __restrict__ rowptr,
                                                const int* __restrict__ csr_src,
                                                const unsigned short* __restrict__ M,
                                                const float* __restrict__ dinv,
                                                const float* __restrict__ b,
                                                void* __restrict__ OUTv, int n) {
    const int node = __builtin_amdgcn_readfirstlane(blockIdx.x * 4 + (threadIdx.x >> 6));
    if (node >= n) return;
    const int lane = threadIdx.x & 63;
    const int half = lane >> 5;
    const int j = (lane & 31) * 4;

    f32x4 acc = (f32x4){0.f, 0.f, 0.f, 0.f};
    if (half == 0) {  // self loop counted once
        const u16x4 sv = *(const u16x4*)&M[(size_t)node * HD + j];
        acc.x = bf16_to_f32(sv.x); acc.y = bf16_to_f32(sv.y);
        acc.z = bf16_to_f32(sv.z); acc.w = bf16_to_f32(sv.w);
    }

    const int s = rowptr[node];
    const int e = rowptr[node + 1];
    int k = s;
    for (; k + 8 <= e; k += 8) {
        int idx[8];
#pragma unroll
        for (int u = 0; u < 8; ++u) idx[u] = csr_src[k + u];
#pragma unroll
        for (int p = 0; p < 4; ++p) {
            const int src = idx[p * 2 + half];
            const u16x4 v = *(const u16x4*)&M[(size_t)src * HD + j];
            acc.x += bf16_to_f32(v.x); acc.y += bf16_to_f32(v.y);
            acc.z += bf16_to_f32(v.z); acc.w += bf16_to_f32(v.w);
        }
    }
    for (; k + 2 <= e; k += 2) {
        const int src = csr_src[k + half];
        const u16x4 v = *(const u16x4*)&M[(size_t)src * HD + j];
        acc.x += bf16_to_f32(v.x); acc.y += bf16_to_f32(v.y);
        acc.z += bf16_to_f32(v.z); acc.w += bf16_to_f32(v.w);
    }
    if (k < e && half == 0) {  // single leftover edge
        const int src = csr_src[k];
        const u16x4 v = *(const u16x4*)&M[(size_t)src * HD + j];
        acc.x += bf16_to_f32(v.x); acc.y += bf16_to_f32(v.y);
        acc.z += bf16_to_f32(v.z); acc.w += bf16_to_f32(v.w);
    }

    acc.x += __shfl_xor(acc.x, 32);
    acc.y += __shfl_xor(acc.y, 32);
    acc.z += __shfl_xor(acc.z, 32);
    acc.w += __shfl_xor(acc.w, 32);

    if (half == 0) {
        const float d = dinv[node];
        const float4 bv = *(const float4*)&b[j];
        float ox = fmaf(acc.x, d, bv.x);
        float oy = fmaf(acc.y, d, bv.y);
        float oz = fmaf(acc.z, d, bv.z);
        float ow = fmaf(acc.w, d, bv.w);
        if (!LAST) {
            ox = fmaxf(ox, 0.f); oy = fmaxf(oy, 0.f);
            oz = fmaxf(oz, 0.f); ow = fmaxf(ow, 0.f);
            unsigned short* OUT = (unsigned short*)OUTv;
            u16x4 o = {rne_bf16(ox), rne_bf16(oy), rne_bf16(oz), rne_bf16(ow)};
            *(u16x4*)&OUT[(size_t)node * HD + j] = o;
        } else {
            float* OUT = (float*)OUTv;
            *(float4*)&OUT[(size_t)node * HD + j] = make_float4(ox, oy, oz, ow);
        }
    }
}

// Stage 1 pooling: QSEG blocks per graph (positional over permuted storage).
__global__ __launch_bounds__(128) void k_pool_part(const float* __restrict__ X,
                                                   const int* __restrict__ batch,
                                                   float* __restrict__ psum, int n) {
    const int g = blockIdx.x / QSEG;
    const int q = blockIdx.x % QSEG;
    const int t = threadIdx.x;
    int lo = 0, hi = n;
    while (lo < hi) { int m = (lo + hi) >> 1; if (batch[m] < g) lo = m + 1; else hi = m; }
    const int start = lo;
    hi = n;
    while (lo < hi) { int m = (lo + hi) >> 1; if (batch[m] < g + 1) lo = m + 1; else hi = m; }
    const int end = lo;
    float acc = 0.f;
    for (int i = start + q; i < end; i += QSEG) acc += X[(size_t)i * HD + t];
    psum[(size_t)blockIdx.x * HD + t] = acc;
}

// Stage 2 + final linear fused. pl is in permuted storage; map to logical
// column c(k) = (k%8)*16 + k/8 when indexing Wl.
__global__ __launch_bounds__(128) void k_pool_final(const float* __restrict__ psum,
                                                    const int* __restrict__ batch,
                                                    const float* __restrict__ Wl,
                                                    const float* __restrict__ bl,
                                                    float* __restrict__ out, int n, int C) {
    __shared__ float pl[HD];
    const int g = blockIdx.x;
    const int t = threadIdx.x;
    int lo = 0, hi = n;
    while (lo < hi) { int m = (lo + hi) >> 1; if (batch[m] < g) lo = m + 1; else hi = m; }
    const int start = lo;
    hi = n;
    while (lo < hi) { int m = (lo + hi) >> 1; if (batch[m] < g + 1) lo = m + 1; else hi = m; }
    const int cnt = lo - start;
    float acc = 0.f;
#pragma unroll
    for (int q = 0; q < QSEG; ++q)
        acc += psum[((size_t)g * QSEG + q) * HD + t];
    pl[t] = acc / (float)max(cnt, 1);
    __syncthreads();
    if (t < C) {
        float s = 0.f;
        for (int k = 0; k < HD; ++k) {
            const int c = (k & 7) * 16 + (k >> 3);
            s = fmaf(pl[k], Wl[(size_t)c * C + t], s);
        }
        out[(size_t)g * C + t] = s + bl[t];
    }
}

extern "C" void kernel_launch(void* const* d_in, const int* in_sizes, int n_in,
                              void* d_out, int out_size, void* d_ws, size_t ws_size,
                              hipStream_t stream) {
    const float* x   = (const float*)d_in[0];
    const int* ei    = (const int*)d_in[1];
    const int* batch = (const int*)d_in[2];
    const float* W1 = (const float*)d_in[3];
    const float* b1 = (const float*)d_in[4];
    const float* W2 = (const float*)d_in[5];
    const float* b2 = (const float*)d_in[6];
    const float* W3 = (const float*)d_in[7];
    const float* b3 = (const float*)d_in[8];
    const float* Wl = (const float*)d_in[9];
    const float* bl = (const float*)d_in[10];
    float* out = (float*)d_out;

    const int N = in_sizes[0] / HD;
    const int E = in_sizes[1] / 2;
    const int C = 10;
    const int G = out_size / C;
    const int NB = (N + 127) >> BSH;  // 128-dst buckets

    const int* rowi = ei;      // sources
    const int* coli = ei + E;  // targets

    // workspace layout
    float* Yf         = (float*)d_ws;                            // N*HD f32 (layer-3 out)
    unsigned short* M = (unsigned short*)(Yf + (size_t)N * HD);  // N*HD bf16 messages
    unsigned short* Yb = M + (size_t)N * HD;                     // N*HD bf16 activations
    float* dinv     = (float*)(Yb + (size_t)N * HD);             // N
    short* wf       = (short*)(dinv + N);            // 3*2*16384 shorts
    float* bp       = (float*)(wf + 3 * 32768);      // 3*128 permuted biases
    int* rowptr     = (int*)(bp + 3 * HD);           // N+1
    int* bcnt       = rowptr + (N + 1);              // NB
    int* bbase      = bcnt + NB;                     // NB+1
    int* cursor     = bbase + (NB + 1);              // NB
    int* csr_src    = cursor + NB;                   // E
    uint2* pairs    = (uint2*)M;   // E uint2 (6.4MB) — M unused until layer 1
    float* psum     = (float*)M;   // pooling scratch — M dead after layer-3 gather

    const int T = 256;

    // ---- preprocessing: bucketed CSR build + dinv + W fragments + biases ----
    k_zero_int<<<(NB + T - 1) / T, T, 0, stream>>>(bcnt, NB);
    k_bhist<<<(E + EB * 2 - 1) / (EB * 2), T, 0, stream>>>(coli, bcnt, E, NB);
    k_bscan<<<1, 64, 0, stream>>>(bcnt, bbase, cursor, rowptr, NB, E, N);
    k_bin<<<(E + EB - 1) / EB, T, 0, stream>>>(rowi, coli, cursor, pairs, E, NB);
    k_sortbuild<<<NB, T, 0, stream>>>(pairs, bbase, rowptr, dinv, csr_src, N);
    k_wfrag<<<24, 256, 0, stream>>>(W1, W2, W3, wf);
    k_bprep<<<3, 128, 0, stream>>>(b1, b2, b3, bp);

    const short* whi1 = wf;                const short* wlo1 = wf + 16384;
    const short* whi2 = wf + 32768;        const short* wlo2 = wf + 49152;
    const short* whi3 = wf + 65536;        const short* wlo3 = wf + 81920;

    const int gGemm   = (N + 63) / 64;
    const int gGather = (N + 3) / 4;

    // Layer 1: x(f32,natural) --gemm--> M(perm) --gather--> Yb (bf16, relu)
    k_gemm<1><<<gGemm, T, 0, stream>>>(x, whi1, wlo1, dinv, M, N);
    k_gather<0><<<gGather, T, 0, stream>>>(rowptr, csr_src, M, dinv, bp, Yb, N);

    // Layer 2: Yb(perm) --gemm--> M(perm) --gather--> Yb (bf16, relu)
    k_gemm<0><<<gGemm, T, 0, stream>>>(Yb, whi2, wlo2, dinv, M, N);
    k_gather<0><<<gGather, T, 0, stream>>>(rowptr, csr_src, M, dinv, bp + HD, Yb, N);

    // Layer 3: Yb(perm) --gemm--> M(perm) --gather--> Yf (f32, no relu)
    k_gemm<0><<<gGemm, T, 0, stream>>>(Yb, whi3, wlo3, dinv, M, N);
    k_gather<1><<<gGather, T, 0, stream>>>(rowptr, csr_src, M, dinv, bp + 2 * HD, Yf, N);

    // Two-stage pool + fused final linear (psum aliases M, now dead)
    k_pool_part<<<G * QSEG, 128, 0, stream>>>(Yf, batch, psum, N);
    k_pool_final<<<G, 128, 0, stream>>>(psum, batch, Wl, bl, out, N, C);
}

// Round 12
// 327.025 us; speedup vs baseline: 1.7173x; 1.0246x over previous
//
#include <hip/hip_runtime.h>
#include <cstddef>

// N=100000, E=800000, H=128, C=10, G=512
#define HD 128
#define QSEG 8      // partial-pool blocks per graph
#define BSH 7       // bucket shift: 128 dsts per bucket
#define NBP 1024    // padded bucket-array size (>= NB)
#define EB 4096     // edges per k_bin block

// Permuted storage layout for all hidden N x 128 arrays (M, Yb, Yf):
//   storage index s holds logical column c(s) = (s%8)*16 + s/8
//   inverse: s(c) = (c%16)*8 + c/16
// MFMA C/D fragment -> 8 contiguous shorts per (lane, r): coalesced 16B
// stores. Layer>=2 K relabeling is baked into the W fragments.

typedef float f32x4 __attribute__((ext_vector_type(4)));
typedef short s16x8 __attribute__((ext_vector_type(8)));
typedef unsigned short u16x4 __attribute__((ext_vector_type(4)));
typedef unsigned short u16x8 __attribute__((ext_vector_type(8)));

static __device__ __forceinline__ int atomAddI(int* p, int v) {
    return __hip_atomic_fetch_add(p, v, __ATOMIC_RELAXED, __HIP_MEMORY_SCOPE_AGENT);
}

// round-to-nearest-even f32 -> bf16 bits
static __device__ __forceinline__ unsigned short rne_bf16(float f) {
    unsigned u = __float_as_uint(f);
    unsigned r = u + 0x7FFFu + ((u >> 16) & 1u);
    return (unsigned short)(r >> 16);
}
static __device__ __forceinline__ float bf16_to_f32(unsigned short h) {
    return __uint_as_float((unsigned)h << 16);
}

__global__ void k_zero_int(int* p, int n) {
    int i = blockIdx.x * blockDim.x + threadIdx.x;
    if (i < n) p[i] = 0;
}

// Coarse histogram of dst buckets (dst>>BSH) via per-block LDS staging.
__global__ __launch_bounds__(256) void k_bhist(const int* __restrict__ coli,
                                               int* __restrict__ bcnt, int E, int NB) {
    __shared__ int lc[NBP];
    for (int b = threadIdx.x; b < NBP; b += 256) lc[b] = 0;
    __syncthreads();
    const int base = blockIdx.x * (EB * 2);
    const int end = min(base + EB * 2, E);
    for (int i = base + threadIdx.x; i < end; i += 256)
        atomicAdd(&lc[coli[i] >> BSH], 1);
    __syncthreads();
    for (int b = threadIdx.x; b < NB; b += 256)
        if (lc[b]) atomAddI(&bcnt[b], lc[b]);
}

// Serial scan of bucket counts -> bbase (segment starts) + cursor copy.
__global__ void k_bscan(const int* __restrict__ bcnt, int* __restrict__ bbase,
                        int* __restrict__ cursor, int* __restrict__ rowptr,
                        int NB, int E, int N) {
    if (threadIdx.x == 0 && blockIdx.x == 0) {
        int run = 0;
        for (int j = 0; j < NB; ++j) {
            bbase[j] = run;
            cursor[j] = run;
            run += bcnt[j];
        }
        bbase[NB] = run;
        rowptr[N] = run;  // == E
    }
}

// Bin edges into bucket-grouped (src,dst) pairs.
__global__ __launch_bounds__(256) void k_bin(const int* __restrict__ rowi,
                                             const int* __restrict__ coli,
                                             int* __restrict__ cursor,
                                             uint2* __restrict__ pairs, int E, int NB) {
    __shared__ int lcnt[NBP];
    __shared__ int gbs[NBP];
    const int t = threadIdx.x;
    const int base = blockIdx.x * EB;
    for (int b = t; b < NBP; b += 256) lcnt[b] = 0;
    __syncthreads();

    uint2 ed[16];
    int eb[16];
#pragma unroll
    for (int u = 0; u < 16; ++u) {
        const int idx = base + u * 256 + t;
        if (idx < E) {
            ed[u].x = (unsigned)rowi[idx];
            ed[u].y = (unsigned)coli[idx];
            eb[u] = (int)(ed[u].y >> BSH);
            atomicAdd(&lcnt[eb[u]], 1);
        } else {
            eb[u] = -1;
        }
    }
    __syncthreads();
    for (int b = t; b < NB; b += 256) {
        const int c = lcnt[b];
        gbs[b] = c > 0 ? atomAddI(&cursor[b], c) : 0;
    }
    __syncthreads();
    for (int b = t; b < NBP; b += 256) lcnt[b] = 0;
    __syncthreads();
#pragma unroll
    for (int u = 0; u < 16; ++u) {
        if (eb[u] >= 0) {
            const int p = gbs[eb[u]] + atomicAdd(&lcnt[eb[u]], 1);
            pairs[p] = ed[u];
        }
    }
}

// One block per bucket: exact CSR for its 128 dsts.
__global__ __launch_bounds__(256) void k_sortbuild(const uint2* __restrict__ pairs,
                                                   const int* __restrict__ bbase,
                                                   int* __restrict__ rowptr,
                                                   float* __restrict__ dinv,
                                                   int* __restrict__ csr_src, int N) {
    __shared__ int cnt[128];
    __shared__ int pref[128];
    const int j = blockIdx.x;
    const int t = threadIdx.x;
    const int s = bbase[j];
    const int e2 = bbase[j + 1];
    const int d0 = j << BSH;
    const int dc = min(128, N - d0);

    if (t < 128) cnt[t] = 0;
    __syncthreads();
    for (int i = s + t; i < e2; i += 256)
        atomicAdd(&cnt[pairs[i].y - (unsigned)d0], 1);
    __syncthreads();
    if (t == 0) {
        int run = 0;
        for (int k = 0; k < 128; ++k) { pref[k] = run; run += cnt[k]; }
    }
    __syncthreads();
    if (t < dc) {
        rowptr[d0 + t] = s + pref[t];
        dinv[d0 + t] = rsqrtf(1.0f + (float)cnt[t]);
    }
    __syncthreads();
    if (t < 128) cnt[t] = 0;
    __syncthreads();
    for (int i = s + t; i < e2; i += 256) {
        const uint2 p = pairs[i];
        const int dl = (int)(p.y - (unsigned)d0);
        const int pos = atomicAdd(&cnt[dl], 1);
        csr_src[s + pref[dl] + pos] = (int)p.x;
    }
}

// Precompute W into MFMA B-fragment order, split hi/lo bf16.
// w==0 (layer 1, natural-layout A=x): k = kt*32 + (lane>>4)*8 + e.
// w>=1 (permuted-storage A):          k = e*16 + kt*4 + (lane>>4).
__global__ __launch_bounds__(256) void k_wfrag(const float* __restrict__ W1,
                                               const float* __restrict__ W2,
                                               const float* __restrict__ W3,
                                               short* __restrict__ wf) {
    const int w = blockIdx.x >> 3;
    const int slot = (blockIdx.x & 7) * 256 + threadIdx.x;  // 0..2047
    const int nt = slot >> 8;
    const int kt = (slot >> 6) & 3;
    const int lane = slot & 63;
    const float* W = (w == 0) ? W1 : (w == 1) ? W2 : W3;
    short* whi = wf + (size_t)w * 32768;
    short* wlo = whi + 16384;
    const int obase = ((nt * 4 + kt) * 64 + lane) * 8;
    const int c = nt * 16 + (lane & 15);
    s16x8 hi8, lo8;
#pragma unroll
    for (int e = 0; e < 8; ++e) {
        const int k = (w == 0) ? (kt * 32 + (lane >> 4) * 8 + e)
                               : (e * 16 + kt * 4 + (lane >> 4));
        const float v = W[(size_t)k * HD + c];
        const unsigned short h = rne_bf16(v);
        hi8[e] = (short)h;
        lo8[e] = (short)rne_bf16(v - bf16_to_f32(h));
    }
    *(s16x8*)&whi[obase] = hi8;
    *(s16x8*)&wlo[obase] = lo8;
}

// Permute the three bias vectors into storage order: bp[s] = b[(s%8)*16 + s/8].
__global__ void k_bprep(const float* __restrict__ b1, const float* __restrict__ b2,
                        const float* __restrict__ b3, float* __restrict__ bp) {
    const int t = threadIdx.x;  // 128
    const float* b = (blockIdx.x == 0) ? b1 : (blockIdx.x == 1) ? b2 : b3;
    bp[blockIdx.x * HD + t] = b[(t & 7) * 16 + (t >> 3)];
}

static __device__ __forceinline__ void split8(const float* xs, s16x8& hi, s16x8& lo) {
#pragma unroll
    for (int e = 0; e < 8; ++e) {
        const unsigned short h = rne_bf16(xs[e]);
        hi[e] = (short)h;
        lo[e] = (short)rne_bf16(xs[e] - bf16_to_f32(h));
    }
}

// M = bf16( dinv ⊙ (A @ W) ) in PERMUTED storage, via bf16 MFMA.
// W fragments (whi 32KB + wlo 32KB) are staged ONCE per block into LDS and
// read by all 4 waves via conflict-free ds_read_b128 — removes the per-wave
// 64KB L2 re-fetch of the hot fragment table (4x fragment traffic cut).
// AF32=1: A f32 natural layout -> split, 3 MFMAs.  AF32=0: A bf16 permuted
// storage -> direct contiguous fragment load, 2 MFMAs.
template <int AF32>
__global__ __launch_bounds__(256) void k_gemm(const void* __restrict__ Av,
                                              const short* __restrict__ whi,
                                              const short* __restrict__ wlo,
                                              const float* __restrict__ dinv,
                                              unsigned short* __restrict__ M, int n) {
    __shared__ short lds[32768];  // 64 KB: [0,16384) = whi, [16384,32768) = wlo
    {
        const float4* s0 = (const float4*)whi;   // 2048 float4
        const float4* s1 = (const float4*)wlo;   // 2048 float4
        float4* d0 = (float4*)lds;
        float4* d1 = (float4*)(lds + 16384);
#pragma unroll
        for (int i = 0; i < 8; ++i) {
            d0[i * 256 + threadIdx.x] = s0[i * 256 + threadIdx.x];
            d1[i * 256 + threadIdx.x] = s1[i * 256 + threadIdx.x];
        }
    }
    __syncthreads();
    const short* lwhi = lds;
    const short* lwlo = lds + 16384;

    const int lane = threadIdx.x & 63;
    const int wid = threadIdx.x >> 6;
    const int rbase = blockIdx.x * 64 + wid * 16;
    const int arow = min(rbase + (lane & 15), n - 1);
    const int kbase = (lane >> 4) * 8;

    f32x4 acc[8];
#pragma unroll
    for (int nt = 0; nt < 8; ++nt) acc[nt] = (f32x4){0.f, 0.f, 0.f, 0.f};

#pragma unroll
    for (int kt = 0; kt < 4; ++kt) {
        s16x8 ahi, alo;
        if (AF32) {
            const float* X = (const float*)Av;
            const float4 x0 = *(const float4*)&X[(size_t)arow * HD + kt * 32 + kbase];
            const float4 x1 = *(const float4*)&X[(size_t)arow * HD + kt * 32 + kbase + 4];
            const float xs[8] = {x0.x, x0.y, x0.z, x0.w, x1.x, x1.y, x1.z, x1.w};
            split8(xs, ahi, alo);
        } else {
            const short* X = (const short*)Av;
            ahi = *(const s16x8*)&X[(size_t)arow * HD + kt * 32 + kbase];
        }
#pragma unroll
        for (int nt = 0; nt < 8; ++nt) {
            const int fo = ((nt * 4 + kt) * 64 + lane) * 8;
            const s16x8 bhi = *(const s16x8*)&lwhi[fo];
            const s16x8 blo = *(const s16x8*)&lwlo[fo];
            acc[nt] = __builtin_amdgcn_mfma_f32_16x16x32_bf16(ahi, bhi, acc[nt], 0, 0, 0);
            acc[nt] = __builtin_amdgcn_mfma_f32_16x16x32_bf16(ahi, blo, acc[nt], 0, 0, 0);
            if (AF32)
                acc[nt] = __builtin_amdgcn_mfma_f32_16x16x32_bf16(alo, bhi, acc[nt], 0, 0, 0);
        }
    }

    // C/D: row = (lane>>4)*4 + r, logical col = nt*16+(lane&15)
    //  -> storage s = (lane&15)*8 + nt  (contiguous over nt)
    const int colb = lane & 15;
    const int rq = (lane >> 4) * 4;
#pragma unroll
    for (int r = 0; r < 4; ++r) {
        const int row = rbase + rq + r;
        if (row < n) {
            const float d = dinv[row];
            u16x8 o;
#pragma unroll
            for (int nt = 0; nt < 8; ++nt) o[nt] = rne_bf16(acc[nt][r] * d);
            *(u16x8*)&M[(size_t)row * HD + colb * 8] = o;
        }
    }
}

// OUT[i] = epi( dinv[i]*(M[i] + sum_{e in CSR[i]} M[src_e]) + b ).
// Purely positional over the permuted storage; b must be pre-permuted.
// LAST=0: relu, bf16 output.  LAST=1: no relu, f32 output (feeds pooling).
template <int LAST>
__global__ __launch_bounds__(256) void k_gather(const int* __restrict__ rowptr,
                                                const int* __restrict__ csr_src,
                                                const unsigned short* __restrict__ M,
                                                const float* __restrict__ dinv,
                                                const float* __restrict__ b,
                                                void* __restrict__ OUTv, int n) {
    const int node = __builtin_amdgcn_readfirstlane(blockIdx.x * 4 + (threadIdx.x >> 6));
    if (node >= n) return;
    const int lane = threadIdx.x & 63;
    const int half = lane >> 5;
    const int j = (lane & 31) * 4;

    f32x4 acc = (f32x4){0.f, 0.f, 0.f, 0.f};
    if (half == 0) {  // self loop counted once
        const u16x4 sv = *(const u16x4*)&M[(size_t)node * HD + j];
        acc.x = bf16_to_f32(sv.x); acc.y = bf16_to_f32(sv.y);
        acc.z = bf16_to_f32(sv.z); acc.w = bf16_to_f32(sv.w);
    }

    const int s = rowptr[node];
    const int e = rowptr[node + 1];
    int k = s;
    for (; k + 8 <= e; k += 8) {
        int idx[8];
#pragma unroll
        for (int u = 0; u < 8; ++u) idx[u] = csr_src[k + u];
#pragma unroll
        for (int p = 0; p < 4; ++p) {
            const int src = idx[p * 2 + half];
            const u16x4 v = *(const u16x4*)&M[(size_t)src * HD + j];
            acc.x += bf16_to_f32(v.x); acc.y += bf16_to_f32(v.y);
            acc.z += bf16_to_f32(v.z); acc.w += bf16_to_f32(v.w);
        }
    }
    for (; k + 2 <= e; k += 2) {
        const int src = csr_src[k + half];
        const u16x4 v = *(const u16x4*)&M[(size_t)src * HD + j];
        acc.x += bf16_to_f32(v.x); acc.y += bf16_to_f32(v.y);
        acc.z += bf16_to_f32(v.z); acc.w += bf16_to_f32(v.w);
    }
    if (k < e && half == 0) {  // single leftover edge
        const int src = csr_src[k];
        const u16x4 v = *(const u16x4*)&M[(size_t)src * HD + j];
        acc.x += bf16_to_f32(v.x); acc.y += bf16_to_f32(v.y);
        acc.z += bf16_to_f32(v.z); acc.w += bf16_to_f32(v.w);
    }

    acc.x += __shfl_xor(acc.x, 32);
    acc.y += __shfl_xor(acc.y, 32);
    acc.z += __shfl_xor(acc.z, 32);
    acc.w += __shfl_xor(acc.w, 32);

    if (half == 0) {
        const float d = dinv[node];
        const float4 bv = *(const float4*)&b[j];
        float ox = fmaf(acc.x, d, bv.x);
        float oy = fmaf(acc.y, d, bv.y);
        float oz = fmaf(acc.z, d, bv.z);
        float ow = fmaf(acc.w, d, bv.w);
        if (!LAST) {
            ox = fmaxf(ox, 0.f); oy = fmaxf(oy, 0.f);
            oz = fmaxf(oz, 0.f); ow = fmaxf(ow, 0.f);
            unsigned short* OUT = (unsigned short*)OUTv;
            u16x4 o = {rne_bf16(ox), rne_bf16(oy), rne_bf16(oz), rne_bf16(ow)};
            *(u16x4*)&OUT[(size_t)node * HD + j] = o;
        } else {
            float* OUT = (float*)OUTv;
            *(float4*)&OUT[(size_t)node * HD + j] = make_float4(ox, oy, oz, ow);
        }
    }
}

// Stage 1 pooling: QSEG blocks per graph (positional over permuted storage).
__global__ __launch_bounds__(128) void k_pool_part(const float* __restrict__ X,
                                                   const int* __restrict__ batch,
                                                   float* __restrict__ psum, int n) {
    const int g = blockIdx.x / QSEG;
    const int q = blockIdx.x % QSEG;
    const int t = threadIdx.x;
    int lo = 0, hi = n;
    while (lo < hi) { int m = (lo + hi) >> 1; if (batch[m] < g) lo = m + 1; else hi = m; }
    const int start = lo;
    hi = n;
    while (lo < hi) { int m = (lo + hi) >> 1; if (batch[m] < g + 1) lo = m + 1; else hi = m; }
    const int end = lo;
    float acc = 0.f;
    for (int i = start + q; i < end; i += QSEG) acc += X[(size_t)i * HD + t];
    psum[(size_t)blockIdx.x * HD + t] = acc;
}

// Stage 2 + final linear fused. pl is in permuted storage; map to logical
// column c(k) = (k%8)*16 + k/8 when indexing Wl.
__global__ __launch_bounds__(128) void k_pool_final(const float* __restrict__ psum,
                                                    const int* __restrict__ batch,
                                                    const float* __restrict__ Wl,
                                                    const float* __restrict__ bl,
                                                    float* __restrict__ out, int n, int C) {
    __shared__ float pl[HD];
    const int g = blockIdx.x;
    const int t = threadIdx.x;
    int lo = 0, hi = n;
    while (lo < hi) { int m = (lo + hi) >> 1; if (batch[m] < g) lo = m + 1; else hi = m; }
    const int start = lo;
    hi = n;
    while (lo < hi) { int m = (lo + hi) >> 1; if (batch[m] < g + 1) lo = m + 1; else hi = m; }
    const int cnt = lo - start;
    float acc = 0.f;
#pragma unroll
    for (int q = 0; q < QSEG; ++q)
        acc += psum[((size_t)g * QSEG + q) * HD + t];
    pl[t] = acc / (float)max(cnt, 1);
    __syncthreads();
    if (t < C) {
        float s = 0.f;
        for (int k = 0; k < HD; ++k) {
            const int c = (k & 7) * 16 + (k >> 3);
            s = fmaf(pl[k], Wl[(size_t)c * C + t], s);
        }
        out[(size_t)g * C + t] = s + bl[t];
    }
}

extern "C" void kernel_launch(void* const* d_in, const int* in_sizes, int n_in,
                              void* d_out, int out_size, void* d_ws, size_t ws_size,
                              hipStream_t stream) {
    const float* x   = (const float*)d_in[0];
    const int* ei    = (const int*)d_in[1];
    const int* batch = (const int*)d_in[2];
    const float* W1 = (const float*)d_in[3];
    const float* b1 = (const float*)d_in[4];
    const float* W2 = (const float*)d_in[5];
    const float* b2 = (const float*)d_in[6];
    const float* W3 = (const float*)d_in[7];
    const float* b3 = (const float*)d_in[8];
    const float* Wl = (const float*)d_in[9];
    const float* bl = (const float*)d_in[10];
    float* out = (float*)d_out;

    const int N = in_sizes[0] / HD;
    const int E = in_sizes[1] / 2;
    const int C = 10;
    const int G = out_size / C;
    const int NB = (N + 127) >> BSH;  // 128-dst buckets

    const int* rowi = ei;      // sources
    const int* coli = ei + E;  // targets

    // workspace layout
    float* Yf         = (float*)d_ws;                            // N*HD f32 (layer-3 out)
    unsigned short* M = (unsigned short*)(Yf + (size_t)N * HD);  // N*HD bf16 messages
    unsigned short* Yb = M + (size_t)N * HD;                     // N*HD bf16 activations
    float* dinv     = (float*)(Yb + (size_t)N * HD);             // N
    short* wf       = (short*)(dinv + N);            // 3*2*16384 shorts
    float* bp       = (float*)(wf + 3 * 32768);      // 3*128 permuted biases
    int* rowptr     = (int*)(bp + 3 * HD);           // N+1
    int* bcnt       = rowptr + (N + 1);              // NB
    int* bbase      = bcnt + NB;                     // NB+1
    int* cursor     = bbase + (NB + 1);              // NB
    int* csr_src    = cursor + NB;                   // E
    uint2* pairs    = (uint2*)M;   // E uint2 (6.4MB) — M unused until layer 1
    float* psum     = (float*)M;   // pooling scratch — M dead after layer-3 gather

    const int T = 256;

    // ---- preprocessing: bucketed CSR build + dinv + W fragments + biases ----
    k_zero_int<<<(NB + T - 1) / T, T, 0, stream>>>(bcnt, NB);
    k_bhist<<<(E + EB * 2 - 1) / (EB * 2), T, 0, stream>>>(coli, bcnt, E, NB);
    k_bscan<<<1, 64, 0, stream>>>(bcnt, bbase, cursor, rowptr, NB, E, N);
    k_bin<<<(E + EB - 1) / EB, T, 0, stream>>>(rowi, coli, cursor, pairs, E, NB);
    k_sortbuild<<<NB, T, 0, stream>>>(pairs, bbase, rowptr, dinv, csr_src, N);
    k_wfrag<<<24, 256, 0, stream>>>(W1, W2, W3, wf);
    k_bprep<<<3, 128, 0, stream>>>(b1, b2, b3, bp);

    const short* whi1 = wf;                const short* wlo1 = wf + 16384;
    const short* whi2 = wf + 32768;        const short* wlo2 = wf + 49152;
    const short* whi3 = wf + 65536;        const short* wlo3 = wf + 81920;

    const int gGemm   = (N + 63) / 64;
    const int gGather = (N + 3) / 4;

    // Layer 1: x(f32,natural) --gemm--> M(perm) --gather--> Yb (bf16, relu)
    k_gemm<1><<<gGemm, T, 0, stream>>>(x, whi1, wlo1, dinv, M, N);
    k_gather<0><<<gGather, T, 0, stream>>>(rowptr, csr_src, M, dinv, bp, Yb, N);

    // Layer 2: Yb(perm) --gemm--> M(perm) --gather--> Yb (bf16, relu)
    k_gemm<0><<<gGemm, T, 0, stream>>>(Yb, whi2, wlo2, dinv, M, N);
    k_gather<0><<<gGather, T, 0, stream>>>(rowptr, csr_src, M, dinv, bp + HD, Yb, N);

    // Layer 3: Yb(perm) --gemm--> M(perm) --gather--> Yf (f32, no relu)
    k_gemm<0><<<gGemm, T, 0, stream>>>(Yb, whi3, wlo3, dinv, M, N);
    k_gather<1><<<gGather, T, 0, stream>>>(rowptr, csr_src, M, dinv, bp + 2 * HD, Yf, N);

    // Two-stage pool + fused final linear (psum aliases M, now dead)
    k_pool_part<<<G * QSEG, 128, 0, stream>>>(Yf, batch, psum, N);
    k_pool_final<<<G, 128, 0, stream>>>(psum, batch, Wl, bl, out, N, C);
}

// Round 13
// 320.555 us; speedup vs baseline: 1.7519x; 1.0202x over previous
//
#include <hip/hip_runtime.h>
#include <cstddef>

// N=100000, E=800000, H=128, C=10, G=512
#define HD 128
#define QSEG 8      // partial-pool blocks per graph
#define BSH 7       // bucket shift: 128 dsts per bucket
#define NBP 1024    // padded bucket-array size (>= NB)
#define EB 4096     // edges per k_bin block

// Permuted storage layout for all hidden N x 128 arrays (M, Yb, Yf):
//   storage index s holds logical column c(s) = (s%8)*16 + s/8
// MFMA C/D fragment -> 8 contiguous shorts per (lane, r): coalesced 16B
// stores. Layer>=2 K relabeling is baked into the W fragments.
// Packed edge encoding (k_bin/k_sortbuild): u32 = (dst&127)<<20 | src,
// valid for N < 2^20.

typedef float f32x4 __attribute__((ext_vector_type(4)));
typedef short s16x8 __attribute__((ext_vector_type(8)));
typedef unsigned short u16x4 __attribute__((ext_vector_type(4)));
typedef unsigned short u16x8 __attribute__((ext_vector_type(8)));

static __device__ __forceinline__ int atomAddI(int* p, int v) {
    return __hip_atomic_fetch_add(p, v, __ATOMIC_RELAXED, __HIP_MEMORY_SCOPE_AGENT);
}

// round-to-nearest-even f32 -> bf16 bits
static __device__ __forceinline__ unsigned short rne_bf16(float f) {
    unsigned u = __float_as_uint(f);
    unsigned r = u + 0x7FFFu + ((u >> 16) & 1u);
    return (unsigned short)(r >> 16);
}
static __device__ __forceinline__ float bf16_to_f32(unsigned short h) {
    return __uint_as_float((unsigned)h << 16);
}

__global__ void k_zero_int(int* p, int n) {
    int i = blockIdx.x * blockDim.x + threadIdx.x;
    if (i < n) p[i] = 0;
}

// Coarse histogram of dst buckets (dst>>BSH) via per-block LDS staging.
__global__ __launch_bounds__(256) void k_bhist(const int* __restrict__ coli,
                                               int* __restrict__ bcnt, int E, int NB) {
    __shared__ int lc[NBP];
    for (int b = threadIdx.x; b < NBP; b += 256) lc[b] = 0;
    __syncthreads();
    const int base = blockIdx.x * (EB * 2);
    const int end = min(base + EB * 2, E);
    for (int i = base + threadIdx.x; i < end; i += 256)
        atomicAdd(&lc[coli[i] >> BSH], 1);
    __syncthreads();
    for (int b = threadIdx.x; b < NB; b += 256)
        if (lc[b]) atomAddI(&bcnt[b], lc[b]);
}

// Serial scan of bucket counts -> bbase (segment starts) + cursor copy.
__global__ void k_bscan(const int* __restrict__ bcnt, int* __restrict__ bbase,
                        int* __restrict__ cursor, int* __restrict__ rowptr,
                        int NB, int E, int N) {
    if (threadIdx.x == 0 && blockIdx.x == 0) {
        int run = 0;
        for (int j = 0; j < NB; ++j) {
            bbase[j] = run;
            cursor[j] = run;
            run += bcnt[j];
        }
        bbase[NB] = run;
        rowptr[N] = run;  // == E
    }
}

// Bin edges into bucket-grouped packed u32 ((dst&127)<<20 | src).
__global__ __launch_bounds__(256) void k_bin(const int* __restrict__ rowi,
                                             const int* __restrict__ coli,
                                             int* __restrict__ cursor,
                                             unsigned* __restrict__ pairs, int E, int NB) {
    __shared__ int lcnt[NBP];
    __shared__ int gbs[NBP];
    const int t = threadIdx.x;
    const int base = blockIdx.x * EB;
    for (int b = t; b < NBP; b += 256) lcnt[b] = 0;
    __syncthreads();

    unsigned ed[16];
    int eb[16];
#pragma unroll
    for (int u = 0; u < 16; ++u) {
        const int idx = base + u * 256 + t;
        if (idx < E) {
            const unsigned src = (unsigned)rowi[idx];
            const unsigned dst = (unsigned)coli[idx];
            ed[u] = ((dst & 127u) << 20) | src;
            eb[u] = (int)(dst >> BSH);
            atomicAdd(&lcnt[eb[u]], 1);
        } else {
            eb[u] = -1;
        }
    }
    __syncthreads();
    for (int b = t; b < NB; b += 256) {
        const int c = lcnt[b];
        gbs[b] = c > 0 ? atomAddI(&cursor[b], c) : 0;
    }
    __syncthreads();
    for (int b = t; b < NBP; b += 256) lcnt[b] = 0;
    __syncthreads();
#pragma unroll
    for (int u = 0; u < 16; ++u) {
        if (eb[u] >= 0) {
            const int p = gbs[eb[u]] + atomicAdd(&lcnt[eb[u]], 1);
            pairs[p] = ed[u];
        }
    }
}

// One block per bucket: exact CSR for its 128 dsts.
__global__ __launch_bounds__(256) void k_sortbuild(const unsigned* __restrict__ pairs,
                                                   const int* __restrict__ bbase,
                                                   int* __restrict__ rowptr,
                                                   float* __restrict__ dinv,
                                                   int* __restrict__ csr_src, int N) {
    __shared__ int cnt[128];
    __shared__ int pref[128];
    const int j = blockIdx.x;
    const int t = threadIdx.x;
    const int s = bbase[j];
    const int e2 = bbase[j + 1];
    const int d0 = j << BSH;
    const int dc = min(128, N - d0);

    if (t < 128) cnt[t] = 0;
    __syncthreads();
    for (int i = s + t; i < e2; i += 256)
        atomicAdd(&cnt[pairs[i] >> 20], 1);
    __syncthreads();
    if (t == 0) {
        int run = 0;
        for (int k = 0; k < 128; ++k) { pref[k] = run; run += cnt[k]; }
    }
    __syncthreads();
    if (t < dc) {
        rowptr[d0 + t] = s + pref[t];
        dinv[d0 + t] = rsqrtf(1.0f + (float)cnt[t]);
    }
    __syncthreads();
    if (t < 128) cnt[t] = 0;
    __syncthreads();
    for (int i = s + t; i < e2; i += 256) {
        const unsigned p = pairs[i];
        const int dl = (int)(p >> 20);
        const int pos = atomicAdd(&cnt[dl], 1);
        csr_src[s + pref[dl] + pos] = (int)(p & 0xFFFFFu);
    }
}

// Precompute W into MFMA B-fragment order, split hi/lo bf16.
// w==0 (layer 1, natural-layout A=x): k = kt*32 + (lane>>4)*8 + e.
// w>=1 (permuted-storage A):          k = e*16 + kt*4 + (lane>>4).
__global__ __launch_bounds__(256) void k_wfrag(const float* __restrict__ W1,
                                               const float* __restrict__ W2,
                                               const float* __restrict__ W3,
                                               short* __restrict__ wf) {
    const int w = blockIdx.x >> 3;
    const int slot = (blockIdx.x & 7) * 256 + threadIdx.x;  // 0..2047
    const int nt = slot >> 8;
    const int kt = (slot >> 6) & 3;
    const int lane = slot & 63;
    const float* W = (w == 0) ? W1 : (w == 1) ? W2 : W3;
    short* whi = wf + (size_t)w * 32768;
    short* wlo = whi + 16384;
    const int obase = ((nt * 4 + kt) * 64 + lane) * 8;
    const int c = nt * 16 + (lane & 15);
    s16x8 hi8, lo8;
#pragma unroll
    for (int e = 0; e < 8; ++e) {
        const int k = (w == 0) ? (kt * 32 + (lane >> 4) * 8 + e)
                               : (e * 16 + kt * 4 + (lane >> 4));
        const float v = W[(size_t)k * HD + c];
        const unsigned short h = rne_bf16(v);
        hi8[e] = (short)h;
        lo8[e] = (short)rne_bf16(v - bf16_to_f32(h));
    }
    *(s16x8*)&whi[obase] = hi8;
    *(s16x8*)&wlo[obase] = lo8;
}

// Permute the three bias vectors into storage order: bp[s] = b[(s%8)*16 + s/8].
__global__ void k_bprep(const float* __restrict__ b1, const float* __restrict__ b2,
                        const float* __restrict__ b3, float* __restrict__ bp) {
    const int t = threadIdx.x;  // 128
    const float* b = (blockIdx.x == 0) ? b1 : (blockIdx.x == 1) ? b2 : b3;
    bp[blockIdx.x * HD + t] = b[(t & 7) * 16 + (t >> 3)];
}

static __device__ __forceinline__ void split8(const float* xs, s16x8& hi, s16x8& lo) {
#pragma unroll
    for (int e = 0; e < 8; ++e) {
        const unsigned short h = rne_bf16(xs[e]);
        hi[e] = (short)h;
        lo[e] = (short)rne_bf16(xs[e] - bf16_to_f32(h));
    }
}

// M = bf16( dinv ⊙ (A @ W) ) in PERMUTED storage, via bf16 MFMA.
// W fragments (whi|wlo, 64KB contiguous) staged once per block into LDS.
// Block = 4 waves covers 128 rows; each wave owns 32 rows as TWO independent
// 16-row accumulator chains -> each LDS fragment read feeds 4 (AF32: 6)
// MFMAs and the two chains give ILP to cover latency at 2 blocks/CU.
// AF32=1: A f32 natural layout -> split, 3 products.  AF32=0: A bf16
// permuted storage -> direct load, 2 products.
template <int AF32>
__global__ __launch_bounds__(256) void k_gemm(const void* __restrict__ Av,
                                              const short* __restrict__ whi,
                                              const short* __restrict__ wlo,
                                              const float* __restrict__ dinv,
                                              unsigned short* __restrict__ M, int n) {
    __shared__ short lds[32768];  // 64 KB: [0,16384) = whi, [16384,32768) = wlo
    {
        const float4* s0 = (const float4*)whi;  // whi+wlo contiguous: 4096 float4
        float4* d0 = (float4*)lds;
#pragma unroll
        for (int i = 0; i < 16; ++i)
            d0[i * 256 + threadIdx.x] = s0[i * 256 + threadIdx.x];
    }
    __syncthreads();
    const short* lwhi = lds;
    const short* lwlo = lds + 16384;

    const int lane = threadIdx.x & 63;
    const int wid = threadIdx.x >> 6;
    const int rbase = blockIdx.x * 128 + wid * 32;
    const int arow0 = min(rbase + (lane & 15), n - 1);
    const int arow1 = min(rbase + 16 + (lane & 15), n - 1);
    const int kbase = (lane >> 4) * 8;

    f32x4 acc[2][8];
#pragma unroll
    for (int g = 0; g < 2; ++g)
#pragma unroll
        for (int nt = 0; nt < 8; ++nt) acc[g][nt] = (f32x4){0.f, 0.f, 0.f, 0.f};

#pragma unroll
    for (int kt = 0; kt < 4; ++kt) {
        s16x8 a0hi, a0lo, a1hi, a1lo;
        if (AF32) {
            const float* X = (const float*)Av;
            const float4 p0 = *(const float4*)&X[(size_t)arow0 * HD + kt * 32 + kbase];
            const float4 p1 = *(const float4*)&X[(size_t)arow0 * HD + kt * 32 + kbase + 4];
            const float4 q0 = *(const float4*)&X[(size_t)arow1 * HD + kt * 32 + kbase];
            const float4 q1 = *(const float4*)&X[(size_t)arow1 * HD + kt * 32 + kbase + 4];
            const float xs0[8] = {p0.x, p0.y, p0.z, p0.w, p1.x, p1.y, p1.z, p1.w};
            const float xs1[8] = {q0.x, q0.y, q0.z, q0.w, q1.x, q1.y, q1.z, q1.w};
            split8(xs0, a0hi, a0lo);
            split8(xs1, a1hi, a1lo);
        } else {
            const short* X = (const short*)Av;
            a0hi = *(const s16x8*)&X[(size_t)arow0 * HD + kt * 32 + kbase];
            a1hi = *(const s16x8*)&X[(size_t)arow1 * HD + kt * 32 + kbase];
        }
#pragma unroll
        for (int nt = 0; nt < 8; ++nt) {
            const int fo = ((nt * 4 + kt) * 64 + lane) * 8;
            const s16x8 bhi = *(const s16x8*)&lwhi[fo];
            const s16x8 blo = *(const s16x8*)&lwlo[fo];
            acc[0][nt] = __builtin_amdgcn_mfma_f32_16x16x32_bf16(a0hi, bhi, acc[0][nt], 0, 0, 0);
            acc[1][nt] = __builtin_amdgcn_mfma_f32_16x16x32_bf16(a1hi, bhi, acc[1][nt], 0, 0, 0);
            acc[0][nt] = __builtin_amdgcn_mfma_f32_16x16x32_bf16(a0hi, blo, acc[0][nt], 0, 0, 0);
            acc[1][nt] = __builtin_amdgcn_mfma_f32_16x16x32_bf16(a1hi, blo, acc[1][nt], 0, 0, 0);
            if (AF32) {
                acc[0][nt] = __builtin_amdgcn_mfma_f32_16x16x32_bf16(a0lo, bhi, acc[0][nt], 0, 0, 0);
                acc[1][nt] = __builtin_amdgcn_mfma_f32_16x16x32_bf16(a1lo, bhi, acc[1][nt], 0, 0, 0);
            }
        }
    }

    // C/D: row = (lane>>4)*4 + r, logical col = nt*16+(lane&15)
    //  -> storage s = (lane&15)*8 + nt  (contiguous over nt)
    const int colb = lane & 15;
    const int rq = (lane >> 4) * 4;
#pragma unroll
    for (int g = 0; g < 2; ++g) {
#pragma unroll
        for (int r = 0; r < 4; ++r) {
            const int row = rbase + g * 16 + rq + r;
            if (row < n) {
                const float d = dinv[row];
                u16x8 o;
#pragma unroll
                for (int nt = 0; nt < 8; ++nt) o[nt] = rne_bf16(acc[g][nt][r] * d);
                *(u16x8*)&M[(size_t)row * HD + colb * 8] = o;
            }
        }
    }
}

// OUT[i] = epi( dinv[i]*(M[i] + sum_{e in CSR[i]} M[src_e]) + b ).
// Purely positional over the permuted storage; b must be pre-permuted.
// LAST=0: relu, bf16 output.  LAST=1: no relu, f32 output (feeds pooling).
template <int LAST>
__global__ __launch_bounds__(256) void k_gather(const int* __restrict__ rowptr,
                                                const int* __restrict__ csr_src,
                                                const unsigned short* __restrict__ M,
                                                const float* __restrict__ dinv,
                                                const float* __restrict__ b,
                                                void* __restrict__ OUTv, int n) {
    const int node = __builtin_amdgcn_readfirstlane(blockIdx.x * 4 + (threadIdx.x >> 6));
    if (node >= n) return;
    const int lane = threadIdx.x & 63;
    const int half = lane >> 5;
    const int j = (lane & 31) * 4;

    f32x4 acc = (f32x4){0.f, 0.f, 0.f, 0.f};
    if (half == 0) {  // self loop counted once
        const u16x4 sv = *(const u16x4*)&M[(size_t)node * HD + j];
        acc.x = bf16_to_f32(sv.x); acc.y = bf16_to_f32(sv.y);
        acc.z = bf16_to_f32(sv.z); acc.w = bf16_to_f32(sv.w);
    }

    const int s = rowptr[node];
    const int e = rowptr[node + 1];
    int k = s;
    for (; k + 8 <= e; k += 8) {
        int idx[8];
#pragma unroll
        for (int u = 0; u < 8; ++u) idx[u] = csr_src[k + u];
#pragma unroll
        for (int p = 0; p < 4; ++p) {
            const int src = idx[p * 2 + half];
            const u16x4 v = *(const u16x4*)&M[(size_t)src * HD + j];
            acc.x += bf16_to_f32(v.x); acc.y += bf16_to_f32(v.y);
            acc.z += bf16_to_f32(v.z); acc.w += bf16_to_f32(v.w);
        }
    }
    for (; k + 2 <= e; k += 2) {
        const int src = csr_src[k + half];
        const u16x4 v = *(const u16x4*)&M[(size_t)src * HD + j];
        acc.x += bf16_to_f32(v.x); acc.y += bf16_to_f32(v.y);
        acc.z += bf16_to_f32(v.z); acc.w += bf16_to_f32(v.w);
    }
    if (k < e && half == 0) {  // single leftover edge
        const int src = csr_src[k];
        const u16x4 v = *(const u16x4*)&M[(size_t)src * HD + j];
        acc.x += bf16_to_f32(v.x); acc.y += bf16_to_f32(v.y);
        acc.z += bf16_to_f32(v.z); acc.w += bf16_to_f32(v.w);
    }

    acc.x += __shfl_xor(acc.x, 32);
    acc.y += __shfl_xor(acc.y, 32);
    acc.z += __shfl_xor(acc.z, 32);
    acc.w += __shfl_xor(acc.w, 32);

    if (half == 0) {
        const float d = dinv[node];
        const float4 bv = *(const float4*)&b[j];
        float ox = fmaf(acc.x, d, bv.x);
        float oy = fmaf(acc.y, d, bv.y);
        float oz = fmaf(acc.z, d, bv.z);
        float ow = fmaf(acc.w, d, bv.w);
        if (!LAST) {
            ox = fmaxf(ox, 0.f); oy = fmaxf(oy, 0.f);
            oz = fmaxf(oz, 0.f); ow = fmaxf(ow, 0.f);
            unsigned short* OUT = (unsigned short*)OUTv;
            u16x4 o = {rne_bf16(ox), rne_bf16(oy), rne_bf16(oz), rne_bf16(ow)};
            *(u16x4*)&OUT[(size_t)node * HD + j] = o;
        } else {
            float* OUT = (float*)OUTv;
            *(float4*)&OUT[(size_t)node * HD + j] = make_float4(ox, oy, oz, ow);
        }
    }
}

// Stage 1 pooling: QSEG blocks per graph (positional over permuted storage).
__global__ __launch_bounds__(128) void k_pool_part(const float* __restrict__ X,
                                                   const int* __restrict__ batch,
                                                   float* __restrict__ psum, int n) {
    const int g = blockIdx.x / QSEG;
    const int q = blockIdx.x % QSEG;
    const int t = threadIdx.x;
    int lo = 0, hi = n;
    while (lo < hi) { int m = (lo + hi) >> 1; if (batch[m] < g) lo = m + 1; else hi = m; }
    const int start = lo;
    hi = n;
    while (lo < hi) { int m = (lo + hi) >> 1; if (batch[m] < g + 1) lo = m + 1; else hi = m; }
    const int end = lo;
    float acc = 0.f;
    for (int i = start + q; i < end; i += QSEG) acc += X[(size_t)i * HD + t];
    psum[(size_t)blockIdx.x * HD + t] = acc;
}

// Stage 2 + final linear fused. pl is in permuted storage; map to logical
// column c(k) = (k%8)*16 + k/8 when indexing Wl.
__global__ __launch_bounds__(128) void k_pool_final(const float* __restrict__ psum,
                                                    const int* __restrict__ batch,
                                                    const float* __restrict__ Wl,
                                                    const float* __restrict__ bl,
                                                    float* __restrict__ out, int n, int C) {
    __shared__ float pl[HD];
    const int g = blockIdx.x;
    const int t = threadIdx.x;
    int lo = 0, hi = n;
    while (lo < hi) { int m = (lo + hi) >> 1; if (batch[m] < g) lo = m + 1; else hi = m; }
    const int start = lo;
    hi = n;
    while (lo < hi) { int m = (lo + hi) >> 1; if (batch[m] < g + 1) lo = m + 1; else hi = m; }
    const int cnt = lo - start;
    float acc = 0.f;
#pragma unroll
    for (int q = 0; q < QSEG; ++q)
        acc += psum[((size_t)g * QSEG + q) * HD + t];
    pl[t] = acc / (float)max(cnt, 1);
    __syncthreads();
    if (t < C) {
        float s = 0.f;
        for (int k = 0; k < HD; ++k) {
            const int c = (k & 7) * 16 + (k >> 3);
            s = fmaf(pl[k], Wl[(size_t)c * C + t], s);
        }
        out[(size_t)g * C + t] = s + bl[t];
    }
}

extern "C" void kernel_launch(void* const* d_in, const int* in_sizes, int n_in,
                              void* d_out, int out_size, void* d_ws, size_t ws_size,
                              hipStream_t stream) {
    const float* x   = (const float*)d_in[0];
    const int* ei    = (const int*)d_in[1];
    const int* batch = (const int*)d_in[2];
    const float* W1 = (const float*)d_in[3];
    const float* b1 = (const float*)d_in[4];
    const float* W2 = (const float*)d_in[5];
    const float* b2 = (const float*)d_in[6];
    const float* W3 = (const float*)d_in[7];
    const float* b3 = (const float*)d_in[8];
    const float* Wl = (const float*)d_in[9];
    const float* bl = (const float*)d_in[10];
    float* out = (float*)d_out;

    const int N = in_sizes[0] / HD;
    const int E = in_sizes[1] / 2;
    const int C = 10;
    const int G = out_size / C;
    const int NB = (N + 127) >> BSH;  // 128-dst buckets

    const int* rowi = ei;      // sources
    const int* coli = ei + E;  // targets

    // workspace layout
    float* Yf         = (float*)d_ws;                            // N*HD f32 (layer-3 out)
    unsigned short* M = (unsigned short*)(Yf + (size_t)N * HD);  // N*HD bf16 messages
    unsigned short* Yb = M + (size_t)N * HD;                     // N*HD bf16 activations
    float* dinv     = (float*)(Yb + (size_t)N * HD);             // N
    short* wf       = (short*)(dinv + N);            // 3*2*16384 shorts
    float* bp       = (float*)(wf + 3 * 32768);      // 3*128 permuted biases
    int* rowptr     = (int*)(bp + 3 * HD);           // N+1
    int* bcnt       = rowptr + (N + 1);              // NB
    int* bbase      = bcnt + NB;                     // NB+1
    int* cursor     = bbase + (NB + 1);              // NB
    int* csr_src    = cursor + NB;                   // E
    unsigned* pairs = (unsigned*)M;  // E u32 (3.2MB) — M unused until layer 1
    float* psum     = (float*)M;     // pooling scratch — M dead after layer-3 gather

    const int T = 256;

    // ---- preprocessing: bucketed CSR build + dinv + W fragments + biases ----
    k_zero_int<<<(NB + T - 1) / T, T, 0, stream>>>(bcnt, NB);
    k_bhist<<<(E + EB * 2 - 1) / (EB * 2), T, 0, stream>>>(coli, bcnt, E, NB);
    k_bscan<<<1, 64, 0, stream>>>(bcnt, bbase, cursor, rowptr, NB, E, N);
    k_bin<<<(E + EB - 1) / EB, T, 0, stream>>>(rowi, coli, cursor, pairs, E, NB);
    k_sortbuild<<<NB, T, 0, stream>>>(pairs, bbase, rowptr, dinv, csr_src, N);
    k_wfrag<<<24, 256, 0, stream>>>(W1, W2, W3, wf);
    k_bprep<<<3, 128, 0, stream>>>(b1, b2, b3, bp);

    const short* whi1 = wf;                const short* wlo1 = wf + 16384;
    const short* whi2 = wf + 32768;        const short* wlo2 = wf + 49152;
    const short* whi3 = wf + 65536;        const short* wlo3 = wf + 81920;

    const int gGemm   = (N + 127) / 128;
    const int gGather = (N + 3) / 4;

    // Layer 1: x(f32,natural) --gemm--> M(perm) --gather--> Yb (bf16, relu)
    k_gemm<1><<<gGemm, T, 0, stream>>>(x, whi1, wlo1, dinv, M, N);
    k_gather<0><<<gGather, T, 0, stream>>>(rowptr, csr_src, M, dinv, bp, Yb, N);

    // Layer 2: Yb(perm) --gemm--> M(perm) --gather--> Yb (bf16, relu)
    k_gemm<0><<<gGemm, T, 0, stream>>>(Yb, whi2, wlo2, dinv, M, N);
    k_gather<0><<<gGather, T, 0, stream>>>(rowptr, csr_src, M, dinv, bp + HD, Yb, N);

    // Layer 3: Yb(perm) --gemm--> M(perm) --gather--> Yf (f32, no relu)
    k_gemm<0><<<gGemm, T, 0, stream>>>(Yb, whi3, wlo3, dinv, M, N);
    k_gather<1><<<gGather, T, 0, stream>>>(rowptr, csr_src, M, dinv, bp + 2 * HD, Yf, N);

    // Two-stage pool + fused final linear (psum aliases M, now dead)
    k_pool_part<<<G * QSEG, 128, 0, stream>>>(Yf, batch, psum, N);
    k_pool_final<<<G, 128, 0, stream>>>(psum, batch, Wl, bl, out, N, C);
}

// Round 14
// 304.052 us; speedup vs baseline: 1.8470x; 1.0543x over previous
//
#include <hip/hip_runtime.h>
#include <cstddef>

// N=100000, E=800000, H=128, C=10, G=512
#define HD 128
#define QSEG 8      // partial-pool blocks per graph
#define BSH 7       // bucket shift: 128 dsts per bucket
#define NBP 1024    // padded bucket-array size (>= NB)
#define EB 4096     // edges per k_bin block

// Permuted storage layout for all hidden N x 128 arrays (M, Yb, Yf):
//   storage index s holds logical column c(s) = (s%8)*16 + s/8
// MFMA C/D fragment -> 8 contiguous shorts per (lane, r): coalesced 16B
// stores. Layer>=2 K relabeling is baked into the W fragments.
// Packed edge encoding (k_bin/k_sortbuild): u32 = (dst&127)<<20 | src,
// valid for N < 2^20.

typedef float f32x4 __attribute__((ext_vector_type(4)));
typedef float f32x8 __attribute__((ext_vector_type(8)));
typedef short s16x8 __attribute__((ext_vector_type(8)));
typedef unsigned short u16x4 __attribute__((ext_vector_type(4)));
typedef unsigned short u16x8 __attribute__((ext_vector_type(8)));

static __device__ __forceinline__ int atomAddI(int* p, int v) {
    return __hip_atomic_fetch_add(p, v, __ATOMIC_RELAXED, __HIP_MEMORY_SCOPE_AGENT);
}

// round-to-nearest-even f32 -> bf16 bits
static __device__ __forceinline__ unsigned short rne_bf16(float f) {
    unsigned u = __float_as_uint(f);
    unsigned r = u + 0x7FFFu + ((u >> 16) & 1u);
    return (unsigned short)(r >> 16);
}
static __device__ __forceinline__ float bf16_to_f32(unsigned short h) {
    return __uint_as_float((unsigned)h << 16);
}

__global__ void k_zero_int(int* p, int n) {
    int i = blockIdx.x * blockDim.x + threadIdx.x;
    if (i < n) p[i] = 0;
}

// Coarse histogram of dst buckets (dst>>BSH) via per-block LDS staging.
__global__ __launch_bounds__(256) void k_bhist(const int* __restrict__ coli,
                                               int* __restrict__ bcnt, int E, int NB) {
    __shared__ int lc[NBP];
    for (int b = threadIdx.x; b < NBP; b += 256) lc[b] = 0;
    __syncthreads();
    const int base = blockIdx.x * (EB * 2);
    const int end = min(base + EB * 2, E);
    for (int i = base + threadIdx.x; i < end; i += 256)
        atomicAdd(&lc[coli[i] >> BSH], 1);
    __syncthreads();
    for (int b = threadIdx.x; b < NB; b += 256)
        if (lc[b]) atomAddI(&bcnt[b], lc[b]);
}

// Serial scan of bucket counts -> bbase (segment starts) + cursor copy.
__global__ void k_bscan(const int* __restrict__ bcnt, int* __restrict__ bbase,
                        int* __restrict__ cursor, int* __restrict__ rowptr,
                        int NB, int E, int N) {
    if (threadIdx.x == 0 && blockIdx.x == 0) {
        int run = 0;
        for (int j = 0; j < NB; ++j) {
            bbase[j] = run;
            cursor[j] = run;
            run += bcnt[j];
        }
        bbase[NB] = run;
        rowptr[N] = run;  // == E
    }
}

// Bin edges into bucket-grouped packed u32 ((dst&127)<<20 | src).
__global__ __launch_bounds__(256) void k_bin(const int* __restrict__ rowi,
                                             const int* __restrict__ coli,
                                             int* __restrict__ cursor,
                                             unsigned* __restrict__ pairs, int E, int NB) {
    __shared__ int lcnt[NBP];
    __shared__ int gbs[NBP];
    const int t = threadIdx.x;
    const int base = blockIdx.x * EB;
    for (int b = t; b < NBP; b += 256) lcnt[b] = 0;
    __syncthreads();

    unsigned ed[16];
    int eb[16];
#pragma unroll
    for (int u = 0; u < 16; ++u) {
        const int idx = base + u * 256 + t;
        if (idx < E) {
            const unsigned src = (unsigned)rowi[idx];
            const unsigned dst = (unsigned)coli[idx];
            ed[u] = ((dst & 127u) << 20) | src;
            eb[u] = (int)(dst >> BSH);
            atomicAdd(&lcnt[eb[u]], 1);
        } else {
            eb[u] = -1;
        }
    }
    __syncthreads();
    for (int b = t; b < NB; b += 256) {
        const int c = lcnt[b];
        gbs[b] = c > 0 ? atomAddI(&cursor[b], c) : 0;
    }
    __syncthreads();
    for (int b = t; b < NBP; b += 256) lcnt[b] = 0;
    __syncthreads();
#pragma unroll
    for (int u = 0; u < 16; ++u) {
        if (eb[u] >= 0) {
            const int p = gbs[eb[u]] + atomicAdd(&lcnt[eb[u]], 1);
            pairs[p] = ed[u];
        }
    }
}

// One block per bucket: exact CSR for its 128 dsts.
__global__ __launch_bounds__(256) void k_sortbuild(const unsigned* __restrict__ pairs,
                                                   const int* __restrict__ bbase,
                                                   int* __restrict__ rowptr,
                                                   float* __restrict__ dinv,
                                                   int* __restrict__ csr_src, int N) {
    __shared__ int cnt[128];
    __shared__ int pref[128];
    const int j = blockIdx.x;
    const int t = threadIdx.x;
    const int s = bbase[j];
    const int e2 = bbase[j + 1];
    const int d0 = j << BSH;
    const int dc = min(128, N - d0);

    if (t < 128) cnt[t] = 0;
    __syncthreads();
    for (int i = s + t; i < e2; i += 256)
        atomicAdd(&cnt[pairs[i] >> 20], 1);
    __syncthreads();
    if (t == 0) {
        int run = 0;
        for (int k = 0; k < 128; ++k) { pref[k] = run; run += cnt[k]; }
    }
    __syncthreads();
    if (t < dc) {
        rowptr[d0 + t] = s + pref[t];
        dinv[d0 + t] = rsqrtf(1.0f + (float)cnt[t]);
    }
    __syncthreads();
    if (t < 128) cnt[t] = 0;
    __syncthreads();
    for (int i = s + t; i < e2; i += 256) {
        const unsigned p = pairs[i];
        const int dl = (int)(p >> 20);
        const int pos = atomicAdd(&cnt[dl], 1);
        csr_src[s + pref[dl] + pos] = (int)(p & 0xFFFFFu);
    }
}

// Precompute W into MFMA B-fragment order, split hi/lo bf16.
// w==0 (layer 1, natural-layout A=x): k = kt*32 + (lane>>4)*8 + e.
// w>=1 (permuted-storage A):          k = e*16 + kt*4 + (lane>>4).
__global__ __launch_bounds__(256) void k_wfrag(const float* __restrict__ W1,
                                               const float* __restrict__ W2,
                                               const float* __restrict__ W3,
                                               short* __restrict__ wf) {
    const int w = blockIdx.x >> 3;
    const int slot = (blockIdx.x & 7) * 256 + threadIdx.x;  // 0..2047
    const int nt = slot >> 8;
    const int kt = (slot >> 6) & 3;
    const int lane = slot & 63;
    const float* W = (w == 0) ? W1 : (w == 1) ? W2 : W3;
    short* whi = wf + (size_t)w * 32768;
    short* wlo = whi + 16384;
    const int obase = ((nt * 4 + kt) * 64 + lane) * 8;
    const int c = nt * 16 + (lane & 15);
    s16x8 hi8, lo8;
#pragma unroll
    for (int e = 0; e < 8; ++e) {
        const int k = (w == 0) ? (kt * 32 + (lane >> 4) * 8 + e)
                               : (e * 16 + kt * 4 + (lane >> 4));
        const float v = W[(size_t)k * HD + c];
        const unsigned short h = rne_bf16(v);
        hi8[e] = (short)h;
        lo8[e] = (short)rne_bf16(v - bf16_to_f32(h));
    }
    *(s16x8*)&whi[obase] = hi8;
    *(s16x8*)&wlo[obase] = lo8;
}

// Permute the three bias vectors into storage order: bp[s] = b[(s%8)*16 + s/8].
__global__ void k_bprep(const float* __restrict__ b1, const float* __restrict__ b2,
                        const float* __restrict__ b3, float* __restrict__ bp) {
    const int t = threadIdx.x;  // 128
    const float* b = (blockIdx.x == 0) ? b1 : (blockIdx.x == 1) ? b2 : b3;
    bp[blockIdx.x * HD + t] = b[(t & 7) * 16 + (t >> 3)];
}

static __device__ __forceinline__ void split8(const float* xs, s16x8& hi, s16x8& lo) {
#pragma unroll
    for (int e = 0; e < 8; ++e) {
        const unsigned short h = rne_bf16(xs[e]);
        hi[e] = (short)h;
        lo[e] = (short)rne_bf16(xs[e] - bf16_to_f32(h));
    }
}

// M = bf16( dinv ⊙ (A @ W) ) in PERMUTED storage, via bf16 MFMA.
// whi (32KB) staged once per block into LDS (occupancy up to 5 blocks/CU);
// wlo read from global (L2-hot, ~100MB/dispatch well under L2 BW).
// Block = 4 waves covers 128 rows; each wave owns 32 rows as TWO independent
// 16-row accumulator chains for ILP.
// AF32=1: A f32 natural layout -> split, 3 products.  AF32=0: A bf16
// permuted storage -> direct load, 2 products.
template <int AF32>
__global__ __launch_bounds__(256) void k_gemm(const void* __restrict__ Av,
                                              const short* __restrict__ whi,
                                              const short* __restrict__ wlo,
                                              const float* __restrict__ dinv,
                                              unsigned short* __restrict__ M, int n) {
    __shared__ short lds[16384];  // 32 KB: whi only
    {
        const float4* s0 = (const float4*)whi;  // 2048 float4
        float4* d0 = (float4*)lds;
#pragma unroll
        for (int i = 0; i < 8; ++i)
            d0[i * 256 + threadIdx.x] = s0[i * 256 + threadIdx.x];
    }
    __syncthreads();
    const short* lwhi = lds;

    const int lane = threadIdx.x & 63;
    const int wid = threadIdx.x >> 6;
    const int rbase = blockIdx.x * 128 + wid * 32;
    const int arow0 = min(rbase + (lane & 15), n - 1);
    const int arow1 = min(rbase + 16 + (lane & 15), n - 1);
    const int kbase = (lane >> 4) * 8;

    f32x4 acc[2][8];
#pragma unroll
    for (int g = 0; g < 2; ++g)
#pragma unroll
        for (int nt = 0; nt < 8; ++nt) acc[g][nt] = (f32x4){0.f, 0.f, 0.f, 0.f};

#pragma unroll
    for (int kt = 0; kt < 4; ++kt) {
        s16x8 a0hi, a0lo, a1hi, a1lo;
        if (AF32) {
            const float* X = (const float*)Av;
            const float4 p0 = *(const float4*)&X[(size_t)arow0 * HD + kt * 32 + kbase];
            const float4 p1 = *(const float4*)&X[(size_t)arow0 * HD + kt * 32 + kbase + 4];
            const float4 q0 = *(const float4*)&X[(size_t)arow1 * HD + kt * 32 + kbase];
            const float4 q1 = *(const float4*)&X[(size_t)arow1 * HD + kt * 32 + kbase + 4];
            const float xs0[8] = {p0.x, p0.y, p0.z, p0.w, p1.x, p1.y, p1.z, p1.w};
            const float xs1[8] = {q0.x, q0.y, q0.z, q0.w, q1.x, q1.y, q1.z, q1.w};
            split8(xs0, a0hi, a0lo);
            split8(xs1, a1hi, a1lo);
        } else {
            const short* X = (const short*)Av;
            a0hi = *(const s16x8*)&X[(size_t)arow0 * HD + kt * 32 + kbase];
            a1hi = *(const s16x8*)&X[(size_t)arow1 * HD + kt * 32 + kbase];
        }
#pragma unroll
        for (int nt = 0; nt < 8; ++nt) {
            const int fo = ((nt * 4 + kt) * 64 + lane) * 8;
            const s16x8 bhi = *(const s16x8*)&lwhi[fo];
            const s16x8 blo = *(const s16x8*)&wlo[fo];
            acc[0][nt] = __builtin_amdgcn_mfma_f32_16x16x32_bf16(a0hi, bhi, acc[0][nt], 0, 0, 0);
            acc[1][nt] = __builtin_amdgcn_mfma_f32_16x16x32_bf16(a1hi, bhi, acc[1][nt], 0, 0, 0);
            acc[0][nt] = __builtin_amdgcn_mfma_f32_16x16x32_bf16(a0hi, blo, acc[0][nt], 0, 0, 0);
            acc[1][nt] = __builtin_amdgcn_mfma_f32_16x16x32_bf16(a1hi, blo, acc[1][nt], 0, 0, 0);
            if (AF32) {
                acc[0][nt] = __builtin_amdgcn_mfma_f32_16x16x32_bf16(a0lo, bhi, acc[0][nt], 0, 0, 0);
                acc[1][nt] = __builtin_amdgcn_mfma_f32_16x16x32_bf16(a1lo, bhi, acc[1][nt], 0, 0, 0);
            }
        }
    }

    // C/D: row = (lane>>4)*4 + r, logical col = nt*16+(lane&15)
    //  -> storage s = (lane&15)*8 + nt  (contiguous over nt)
    const int colb = lane & 15;
    const int rq = (lane >> 4) * 4;
#pragma unroll
    for (int g = 0; g < 2; ++g) {
#pragma unroll
        for (int r = 0; r < 4; ++r) {
            const int row = rbase + g * 16 + rq + r;
            if (row < n) {
                const float d = dinv[row];
                u16x8 o;
#pragma unroll
                for (int nt = 0; nt < 8; ++nt) o[nt] = rne_bf16(acc[g][nt][r] * d);
                *(u16x8*)&M[(size_t)row * HD + colb * 8] = o;
            }
        }
    }
}

// OUT[i] = epi( dinv[i]*(M[i] + sum_{e in CSR[i]} M[src_e]) + b ).
// 4 nodes per wave: each 16-lane group owns one node, reading full 256B rows
// as u16x8 (16B/lane, coalescing sweet spot). 4-edge unroll -> 16 rows in
// flight per wave. Purely positional over permuted storage; b pre-permuted.
// LAST=0: relu, bf16 output.  LAST=1: no relu, f32 output (feeds pooling).
template <int LAST>
__global__ __launch_bounds__(256) void k_gather(const int* __restrict__ rowptr,
                                                const int* __restrict__ csr_src,
                                                const unsigned short* __restrict__ M,
                                                const float* __restrict__ dinv,
                                                const float* __restrict__ b,
                                                void* __restrict__ OUTv, int n) {
    const int lane = threadIdx.x & 63;
    const int wid = threadIdx.x >> 6;
    const int grp = lane >> 4;
    const int node = blockIdx.x * 16 + wid * 4 + grp;
    if (node >= n) return;
    const int j = (lane & 15) * 8;  // bf16 element offset (16B per lane)

    // self loop
    const u16x8 sv = *(const u16x8*)&M[(size_t)node * HD + j];
    f32x8 acc;
#pragma unroll
    for (int i = 0; i < 8; ++i) acc[i] = bf16_to_f32(sv[i]);

    const int s = rowptr[node];
    const int e = rowptr[node + 1];
    int k = s;
    for (; k + 4 <= e; k += 4) {
        const int i0 = csr_src[k], i1 = csr_src[k + 1];
        const int i2 = csr_src[k + 2], i3 = csr_src[k + 3];
        const u16x8 v0 = *(const u16x8*)&M[(size_t)i0 * HD + j];
        const u16x8 v1 = *(const u16x8*)&M[(size_t)i1 * HD + j];
        const u16x8 v2 = *(const u16x8*)&M[(size_t)i2 * HD + j];
        const u16x8 v3 = *(const u16x8*)&M[(size_t)i3 * HD + j];
#pragma unroll
        for (int i = 0; i < 8; ++i)
            acc[i] += (bf16_to_f32(v0[i]) + bf16_to_f32(v1[i])) +
                      (bf16_to_f32(v2[i]) + bf16_to_f32(v3[i]));
    }
    for (; k < e; ++k) {
        const int i0 = csr_src[k];
        const u16x8 v0 = *(const u16x8*)&M[(size_t)i0 * HD + j];
#pragma unroll
        for (int i = 0; i < 8; ++i) acc[i] += bf16_to_f32(v0[i]);
    }

    const float d = dinv[node];
    const float4 bv0 = *(const float4*)&b[j];
    const float4 bv1 = *(const float4*)&b[j + 4];
    const float bb[8] = {bv0.x, bv0.y, bv0.z, bv0.w, bv1.x, bv1.y, bv1.z, bv1.w};
    float o[8];
#pragma unroll
    for (int i = 0; i < 8; ++i) {
        o[i] = fmaf(acc[i], d, bb[i]);
        if (!LAST) o[i] = fmaxf(o[i], 0.f);
    }
    if (!LAST) {
        unsigned short* OUT = (unsigned short*)OUTv;
        u16x8 ov;
#pragma unroll
        for (int i = 0; i < 8; ++i) ov[i] = rne_bf16(o[i]);
        *(u16x8*)&OUT[(size_t)node * HD + j] = ov;
    } else {
        float* OUT = (float*)OUTv;
        *(float4*)&OUT[(size_t)node * HD + j] = make_float4(o[0], o[1], o[2], o[3]);
        *(float4*)&OUT[(size_t)node * HD + j + 4] = make_float4(o[4], o[5], o[6], o[7]);
    }
}

// Stage 1 pooling: QSEG blocks per graph (positional over permuted storage).
__global__ __launch_bounds__(128) void k_pool_part(const float* __restrict__ X,
                                                   const int* __restrict__ batch,
                                                   float* __restrict__ psum, int n) {
    const int g = blockIdx.x / QSEG;
    const int q = blockIdx.x % QSEG;
    const int t = threadIdx.x;
    int lo = 0, hi = n;
    while (lo < hi) { int m = (lo + hi) >> 1; if (batch[m] < g) lo = m + 1; else hi = m; }
    const int start = lo;
    hi = n;
    while (lo < hi) { int m = (lo + hi) >> 1; if (batch[m] < g + 1) lo = m + 1; else hi = m; }
    const int end = lo;
    float acc = 0.f;
    for (int i = start + q; i < end; i += QSEG) acc += X[(size_t)i * HD + t];
    psum[(size_t)blockIdx.x * HD + t] = acc;
}

// Stage 2 + final linear fused. pl is in permuted storage; map to logical
// column c(k) = (k%8)*16 + k/8 when indexing Wl.
__global__ __launch_bounds__(128) void k_pool_final(const float* __restrict__ psum,
                                                    const int* __restrict__ batch,
                                                    const float* __restrict__ Wl,
                                                    const float* __restrict__ bl,
                                                    float* __restrict__ out, int n, int C) {
    __shared__ float pl[HD];
    const int g = blockIdx.x;
    const int t = threadIdx.x;
    int lo = 0, hi = n;
    while (lo < hi) { int m = (lo + hi) >> 1; if (batch[m] < g) lo = m + 1; else hi = m; }
    const int start = lo;
    hi = n;
    while (lo < hi) { int m = (lo + hi) >> 1; if (batch[m] < g + 1) lo = m + 1; else hi = m; }
    const int cnt = lo - start;
    float acc = 0.f;
#pragma unroll
    for (int q = 0; q < QSEG; ++q)
        acc += psum[((size_t)g * QSEG + q) * HD + t];
    pl[t] = acc / (float)max(cnt, 1);
    __syncthreads();
    if (t < C) {
        float s = 0.f;
        for (int k = 0; k < HD; ++k) {
            const int c = (k & 7) * 16 + (k >> 3);
            s = fmaf(pl[k], Wl[(size_t)c * C + t], s);
        }
        out[(size_t)g * C + t] = s + bl[t];
    }
}

extern "C" void kernel_launch(void* const* d_in, const int* in_sizes, int n_in,
                              void* d_out, int out_size, void* d_ws, size_t ws_size,
                              hipStream_t stream) {
    const float* x   = (const float*)d_in[0];
    const int* ei    = (const int*)d_in[1];
    const int* batch = (const int*)d_in[2];
    const float* W1 = (const float*)d_in[3];
    const float* b1 = (const float*)d_in[4];
    const float* W2 = (const float*)d_in[5];
    const float* b2 = (const float*)d_in[6];
    const float* W3 = (const float*)d_in[7];
    const float* b3 = (const float*)d_in[8];
    const float* Wl = (const float*)d_in[9];
    const float* bl = (const float*)d_in[10];
    float* out = (float*)d_out;

    const int N = in_sizes[0] / HD;
    const int E = in_sizes[1] / 2;
    const int C = 10;
    const int G = out_size / C;
    const int NB = (N + 127) >> BSH;  // 128-dst buckets

    const int* rowi = ei;      // sources
    const int* coli = ei + E;  // targets

    // workspace layout
    float* Yf         = (float*)d_ws;                            // N*HD f32 (layer-3 out)
    unsigned short* M = (unsigned short*)(Yf + (size_t)N * HD);  // N*HD bf16 messages
    unsigned short* Yb = M + (size_t)N * HD;                     // N*HD bf16 activations
    float* dinv     = (float*)(Yb + (size_t)N * HD);             // N
    short* wf       = (short*)(dinv + N);            // 3*2*16384 shorts
    float* bp       = (float*)(wf + 3 * 32768);      // 3*128 permuted biases
    int* rowptr     = (int*)(bp + 3 * HD);           // N+1
    int* bcnt       = rowptr + (N + 1);              // NB
    int* bbase      = bcnt + NB;                     // NB+1
    int* cursor     = bbase + (NB + 1);              // NB
    int* csr_src    = cursor + NB;                   // E
    unsigned* pairs = (unsigned*)M;  // E u32 (3.2MB) — M unused until layer 1
    float* psum     = (float*)M;     // pooling scratch — M dead after layer-3 gather

    const int T = 256;

    // ---- preprocessing: bucketed CSR build + dinv + W fragments + biases ----
    k_zero_int<<<(NB + T - 1) / T, T, 0, stream>>>(bcnt, NB);
    k_bhist<<<(E + EB * 2 - 1) / (EB * 2), T, 0, stream>>>(coli, bcnt, E, NB);
    k_bscan<<<1, 64, 0, stream>>>(bcnt, bbase, cursor, rowptr, NB, E, N);
    k_bin<<<(E + EB - 1) / EB, T, 0, stream>>>(rowi, coli, cursor, pairs, E, NB);
    k_sortbuild<<<NB, T, 0, stream>>>(pairs, bbase, rowptr, dinv, csr_src, N);
    k_wfrag<<<24, 256, 0, stream>>>(W1, W2, W3, wf);
    k_bprep<<<3, 128, 0, stream>>>(b1, b2, b3, bp);

    const short* whi1 = wf;                const short* wlo1 = wf + 16384;
    const short* whi2 = wf + 32768;        const short* wlo2 = wf + 49152;
    const short* whi3 = wf + 65536;        const short* wlo3 = wf + 81920;

    const int gGemm   = (N + 127) / 128;
    const int gGather = (N + 15) / 16;

    // Layer 1: x(f32,natural) --gemm--> M(perm) --gather--> Yb (bf16, relu)
    k_gemm<1><<<gGemm, T, 0, stream>>>(x, whi1, wlo1, dinv, M, N);
    k_gather<0><<<gGather, T, 0, stream>>>(rowptr, csr_src, M, dinv, bp, Yb, N);

    // Layer 2: Yb(perm) --gemm--> M(perm) --gather--> Yb (bf16, relu)
    k_gemm<0><<<gGemm, T, 0, stream>>>(Yb, whi2, wlo2, dinv, M, N);
    k_gather<0><<<gGather, T, 0, stream>>>(rowptr, csr_src, M, dinv, bp + HD, Yb, N);

    // Layer 3: Yb(perm) --gemm--> M(perm) --gather--> Yf (f32, no relu)
    k_gemm<0><<<gGemm, T, 0, stream>>>(Yb, whi3, wlo3, dinv, M, N);
    k_gather<1><<<gGather, T, 0, stream>>>(rowptr, csr_src, M, dinv, bp + 2 * HD, Yf, N);

    // Two-stage pool + fused final linear (psum aliases M, now dead)
    k_pool_part<<<G * QSEG, 128, 0, stream>>>(Yf, batch, psum, N);
    k_pool_final<<<G, 128, 0, stream>>>(psum, batch, Wl, bl, out, N, C);
}

// Round 15
// 265.640 us; speedup vs baseline: 2.1141x; 1.1446x over previous
//
#include <hip/hip_runtime.h>
#include <cstddef>

// N=100000, E=800000, H=128, C=10, G=512
#define HD 128
#define QSEG 8      // partial-pool blocks per graph
#define BSH 7       // bucket shift: 128 dsts per bucket
#define NBP 1024    // padded bucket-array size (>= NB)
#define EB 4096     // edges per k_bin block

// Permuted storage layout for all hidden N x 128 arrays (M, Yb, Yf):
//   storage index s holds logical column c(s) = (s%8)*16 + s/8
// MFMA C/D fragment -> 8 contiguous shorts per (lane, r): coalesced 16B
// stores. Layer>=2 K relabeling is baked into the W fragments.
// Packed edge encoding (k_bin/k_sortbuild): u32 = (dst&127)<<20 | src,
// valid for N < 2^20.

typedef float f32x4 __attribute__((ext_vector_type(4)));
typedef float f32x8 __attribute__((ext_vector_type(8)));
typedef short s16x8 __attribute__((ext_vector_type(8)));
typedef unsigned short u16x4 __attribute__((ext_vector_type(4)));
typedef unsigned short u16x8 __attribute__((ext_vector_type(8)));

static __device__ __forceinline__ int atomAddI(int* p, int v) {
    return __hip_atomic_fetch_add(p, v, __ATOMIC_RELAXED, __HIP_MEMORY_SCOPE_AGENT);
}

// round-to-nearest-even f32 -> bf16 bits
static __device__ __forceinline__ unsigned short rne_bf16(float f) {
    unsigned u = __float_as_uint(f);
    unsigned r = u + 0x7FFFu + ((u >> 16) & 1u);
    return (unsigned short)(r >> 16);
}
static __device__ __forceinline__ float bf16_to_f32(unsigned short h) {
    return __uint_as_float((unsigned)h << 16);
}

__global__ void k_zero_int(int* p, int n) {
    int i = blockIdx.x * blockDim.x + threadIdx.x;
    if (i < n) p[i] = 0;
}

// Coarse histogram of dst buckets (dst>>BSH) via per-block LDS staging.
__global__ __launch_bounds__(256) void k_bhist(const int* __restrict__ coli,
                                               int* __restrict__ bcnt, int E, int NB) {
    __shared__ int lc[NBP];
    for (int b = threadIdx.x; b < NBP; b += 256) lc[b] = 0;
    __syncthreads();
    const int base = blockIdx.x * (EB * 2);
    const int end = min(base + EB * 2, E);
    for (int i = base + threadIdx.x; i < end; i += 256)
        atomicAdd(&lc[coli[i] >> BSH], 1);
    __syncthreads();
    for (int b = threadIdx.x; b < NB; b += 256)
        if (lc[b]) atomAddI(&bcnt[b], lc[b]);
}

// One-block parallel exclusive scan of bucket counts -> bbase + cursor.
// 256 threads x 4 buckets each (NBP=1024 >= NB). Replaces the serial scan
// that cost 44us of single-thread dependent-load latency.
__global__ __launch_bounds__(256) void k_bscan(const int* __restrict__ bcnt,
                                               int* __restrict__ bbase,
                                               int* __restrict__ cursor,
                                               int* __restrict__ rowptr,
                                               int NB, int E, int N) {
    __shared__ int sd[256];
    const int t = threadIdx.x;
    int loc[4];
    int tsum = 0;
#pragma unroll
    for (int i = 0; i < 4; ++i) {
        const int b = t * 4 + i;
        loc[i] = (b < NB) ? bcnt[b] : 0;
        tsum += loc[i];
    }
    sd[t] = tsum;
    __syncthreads();
    for (int off = 1; off < 256; off <<= 1) {
        int u = (t >= off) ? sd[t - off] : 0;
        __syncthreads();
        sd[t] += u;
        __syncthreads();
    }
    int pos = sd[t] - tsum;  // exclusive prefix of this thread's chunk
#pragma unroll
    for (int i = 0; i < 4; ++i) {
        const int b = t * 4 + i;
        if (b < NB) { bbase[b] = pos; cursor[b] = pos; }
        pos += loc[i];
    }
    if (t == 255) {
        bbase[NB] = sd[255];   // == E
        rowptr[N] = sd[255];
    }
}

// Bin edges into bucket-grouped packed u32 ((dst&127)<<20 | src).
__global__ __launch_bounds__(256) void k_bin(const int* __restrict__ rowi,
                                             const int* __restrict__ coli,
                                             int* __restrict__ cursor,
                                             unsigned* __restrict__ pairs, int E, int NB) {
    __shared__ int lcnt[NBP];
    __shared__ int gbs[NBP];
    const int t = threadIdx.x;
    const int base = blockIdx.x * EB;
    for (int b = t; b < NBP; b += 256) lcnt[b] = 0;
    __syncthreads();

    unsigned ed[16];
    int eb[16];
#pragma unroll
    for (int u = 0; u < 16; ++u) {
        const int idx = base + u * 256 + t;
        if (idx < E) {
            const unsigned src = (unsigned)rowi[idx];
            const unsigned dst = (unsigned)coli[idx];
            ed[u] = ((dst & 127u) << 20) | src;
            eb[u] = (int)(dst >> BSH);
            atomicAdd(&lcnt[eb[u]], 1);
        } else {
            eb[u] = -1;
        }
    }
    __syncthreads();
    for (int b = t; b < NB; b += 256) {
        const int c = lcnt[b];
        gbs[b] = c > 0 ? atomAddI(&cursor[b], c) : 0;
    }
    __syncthreads();
    for (int b = t; b < NBP; b += 256) lcnt[b] = 0;
    __syncthreads();
#pragma unroll
    for (int u = 0; u < 16; ++u) {
        if (eb[u] >= 0) {
            const int p = gbs[eb[u]] + atomicAdd(&lcnt[eb[u]], 1);
            pairs[p] = ed[u];
        }
    }
}

// One block per bucket: exact CSR for its 128 dsts.
__global__ __launch_bounds__(256) void k_sortbuild(const unsigned* __restrict__ pairs,
                                                   const int* __restrict__ bbase,
                                                   int* __restrict__ rowptr,
                                                   float* __restrict__ dinv,
                                                   int* __restrict__ csr_src, int N) {
    __shared__ int cnt[128];
    __shared__ int pref[128];
    const int j = blockIdx.x;
    const int t = threadIdx.x;
    const int s = bbase[j];
    const int e2 = bbase[j + 1];
    const int d0 = j << BSH;
    const int dc = min(128, N - d0);

    if (t < 128) cnt[t] = 0;
    __syncthreads();
    for (int i = s + t; i < e2; i += 256)
        atomicAdd(&cnt[pairs[i] >> 20], 1);
    __syncthreads();
    if (t == 0) {
        int run = 0;
        for (int k = 0; k < 128; ++k) { pref[k] = run; run += cnt[k]; }
    }
    __syncthreads();
    if (t < dc) {
        rowptr[d0 + t] = s + pref[t];
        dinv[d0 + t] = rsqrtf(1.0f + (float)cnt[t]);
    }
    __syncthreads();
    if (t < 128) cnt[t] = 0;
    __syncthreads();
    for (int i = s + t; i < e2; i += 256) {
        const unsigned p = pairs[i];
        const int dl = (int)(p >> 20);
        const int pos = atomicAdd(&cnt[dl], 1);
        csr_src[s + pref[dl] + pos] = (int)(p & 0xFFFFFu);
    }
}

// Precompute W into MFMA B-fragment order, split hi/lo bf16.
// w==0 (layer 1, natural-layout A=x): k = kt*32 + (lane>>4)*8 + e.
// w>=1 (permuted-storage A):          k = e*16 + kt*4 + (lane>>4).
__global__ __launch_bounds__(256) void k_wfrag(const float* __restrict__ W1,
                                               const float* __restrict__ W2,
                                               const float* __restrict__ W3,
                                               short* __restrict__ wf) {
    const int w = blockIdx.x >> 3;
    const int slot = (blockIdx.x & 7) * 256 + threadIdx.x;  // 0..2047
    const int nt = slot >> 8;
    const int kt = (slot >> 6) & 3;
    const int lane = slot & 63;
    const float* W = (w == 0) ? W1 : (w == 1) ? W2 : W3;
    short* whi = wf + (size_t)w * 32768;
    short* wlo = whi + 16384;
    const int obase = ((nt * 4 + kt) * 64 + lane) * 8;
    const int c = nt * 16 + (lane & 15);
    s16x8 hi8, lo8;
#pragma unroll
    for (int e = 0; e < 8; ++e) {
        const int k = (w == 0) ? (kt * 32 + (lane >> 4) * 8 + e)
                               : (e * 16 + kt * 4 + (lane >> 4));
        const float v = W[(size_t)k * HD + c];
        const unsigned short h = rne_bf16(v);
        hi8[e] = (short)h;
        lo8[e] = (short)rne_bf16(v - bf16_to_f32(h));
    }
    *(s16x8*)&whi[obase] = hi8;
    *(s16x8*)&wlo[obase] = lo8;
}

// Permute the three bias vectors into storage order: bp[s] = b[(s%8)*16 + s/8].
__global__ void k_bprep(const float* __restrict__ b1, const float* __restrict__ b2,
                        const float* __restrict__ b3, float* __restrict__ bp) {
    const int t = threadIdx.x;  // 128
    const float* b = (blockIdx.x == 0) ? b1 : (blockIdx.x == 1) ? b2 : b3;
    bp[blockIdx.x * HD + t] = b[(t & 7) * 16 + (t >> 3)];
}

static __device__ __forceinline__ void split8(const float* xs, s16x8& hi, s16x8& lo) {
#pragma unroll
    for (int e = 0; e < 8; ++e) {
        const unsigned short h = rne_bf16(xs[e]);
        hi[e] = (short)h;
        lo[e] = (short)rne_bf16(xs[e] - bf16_to_f32(h));
    }
}

// M = bf16( dinv ⊙ (A @ W) ) in PERMUTED storage, via bf16 MFMA.
// whi (32KB) staged once per block into LDS (occupancy up to 5 blocks/CU);
// wlo read from global (L2-hot). Block = 4 waves covers 128 rows; each wave
// owns 32 rows as TWO independent 16-row accumulator chains for ILP.
// AF32=1: A f32 natural layout -> split, 3 products.  AF32=0: A bf16
// permuted storage -> direct load, 2 products.
template <int AF32>
__global__ __launch_bounds__(256) void k_gemm(const void* __restrict__ Av,
                                              const short* __restrict__ whi,
                                              const short* __restrict__ wlo,
                                              const float* __restrict__ dinv,
                                              unsigned short* __restrict__ M, int n) {
    __shared__ short lds[16384];  // 32 KB: whi only
    {
        const float4* s0 = (const float4*)whi;  // 2048 float4
        float4* d0 = (float4*)lds;
#pragma unroll
        for (int i = 0; i < 8; ++i)
            d0[i * 256 + threadIdx.x] = s0[i * 256 + threadIdx.x];
    }
    __syncthreads();
    const short* lwhi = lds;

    const int lane = threadIdx.x & 63;
    const int wid = threadIdx.x >> 6;
    const int rbase = blockIdx.x * 128 + wid * 32;
    const int arow0 = min(rbase + (lane & 15), n - 1);
    const int arow1 = min(rbase + 16 + (lane & 15), n - 1);
    const int kbase = (lane >> 4) * 8;

    f32x4 acc[2][8];
#pragma unroll
    for (int g = 0; g < 2; ++g)
#pragma unroll
        for (int nt = 0; nt < 8; ++nt) acc[g][nt] = (f32x4){0.f, 0.f, 0.f, 0.f};

#pragma unroll
    for (int kt = 0; kt < 4; ++kt) {
        s16x8 a0hi, a0lo, a1hi, a1lo;
        if (AF32) {
            const float* X = (const float*)Av;
            const float4 p0 = *(const float4*)&X[(size_t)arow0 * HD + kt * 32 + kbase];
            const float4 p1 = *(const float4*)&X[(size_t)arow0 * HD + kt * 32 + kbase + 4];
            const float4 q0 = *(const float4*)&X[(size_t)arow1 * HD + kt * 32 + kbase];
            const float4 q1 = *(const float4*)&X[(size_t)arow1 * HD + kt * 32 + kbase + 4];
            const float xs0[8] = {p0.x, p0.y, p0.z, p0.w, p1.x, p1.y, p1.z, p1.w};
            const float xs1[8] = {q0.x, q0.y, q0.z, q0.w, q1.x, q1.y, q1.z, q1.w};
            split8(xs0, a0hi, a0lo);
            split8(xs1, a1hi, a1lo);
        } else {
            const short* X = (const short*)Av;
            a0hi = *(const s16x8*)&X[(size_t)arow0 * HD + kt * 32 + kbase];
            a1hi = *(const s16x8*)&X[(size_t)arow1 * HD + kt * 32 + kbase];
        }
#pragma unroll
        for (int nt = 0; nt < 8; ++nt) {
            const int fo = ((nt * 4 + kt) * 64 + lane) * 8;
            const s16x8 bhi = *(const s16x8*)&lwhi[fo];
            const s16x8 blo = *(const s16x8*)&wlo[fo];
            acc[0][nt] = __builtin_amdgcn_mfma_f32_16x16x32_bf16(a0hi, bhi, acc[0][nt], 0, 0, 0);
            acc[1][nt] = __builtin_amdgcn_mfma_f32_16x16x32_bf16(a1hi, bhi, acc[1][nt], 0, 0, 0);
            acc[0][nt] = __builtin_amdgcn_mfma_f32_16x16x32_bf16(a0hi, blo, acc[0][nt], 0, 0, 0);
            acc[1][nt] = __builtin_amdgcn_mfma_f32_16x16x32_bf16(a1hi, blo, acc[1][nt], 0, 0, 0);
            if (AF32) {
                acc[0][nt] = __builtin_amdgcn_mfma_f32_16x16x32_bf16(a0lo, bhi, acc[0][nt], 0, 0, 0);
                acc[1][nt] = __builtin_amdgcn_mfma_f32_16x16x32_bf16(a1lo, bhi, acc[1][nt], 0, 0, 0);
            }
        }
    }

    // C/D: row = (lane>>4)*4 + r, logical col = nt*16+(lane&15)
    //  -> storage s = (lane&15)*8 + nt  (contiguous over nt)
    const int colb = lane & 15;
    const int rq = (lane >> 4) * 4;
#pragma unroll
    for (int g = 0; g < 2; ++g) {
#pragma unroll
        for (int r = 0; r < 4; ++r) {
            const int row = rbase + g * 16 + rq + r;
            if (row < n) {
                const float d = dinv[row];
                u16x8 o;
#pragma unroll
                for (int nt = 0; nt < 8; ++nt) o[nt] = rne_bf16(acc[g][nt][r] * d);
                *(u16x8*)&M[(size_t)row * HD + colb * 8] = o;
            }
        }
    }
}

// OUT[i] = epi( dinv[i]*(M[i] + sum_{e in CSR[i]} M[src_e]) + b ).
// 4 nodes per wave: each 16-lane group owns one node, reading full 256B rows
// as u16x8 (16B/lane). 4-edge unroll -> 16 rows in flight per wave.
// LAST=0: relu, bf16 output.  LAST=1: no relu, f32 output (feeds pooling).
template <int LAST>
__global__ __launch_bounds__(256) void k_gather(const int* __restrict__ rowptr,
                                                const int* __restrict__ csr_src,
                                                const unsigned short* __restrict__ M,
                                                const float* __restrict__ dinv,
                                                const float* __restrict__ b,
                                                void* __restrict__ OUTv, int n) {
    const int lane = threadIdx.x & 63;
    const int wid = threadIdx.x >> 6;
    const int grp = lane >> 4;
    const int node = blockIdx.x * 16 + wid * 4 + grp;
    if (node >= n) return;
    const int j = (lane & 15) * 8;  // bf16 element offset (16B per lane)

    // self loop
    const u16x8 sv = *(const u16x8*)&M[(size_t)node * HD + j];
    f32x8 acc;
#pragma unroll
    for (int i = 0; i < 8; ++i) acc[i] = bf16_to_f32(sv[i]);

    const int s = rowptr[node];
    const int e = rowptr[node + 1];
    int k = s;
    for (; k + 4 <= e; k += 4) {
        const int i0 = csr_src[k], i1 = csr_src[k + 1];
        const int i2 = csr_src[k + 2], i3 = csr_src[k + 3];
        const u16x8 v0 = *(const u16x8*)&M[(size_t)i0 * HD + j];
        const u16x8 v1 = *(const u16x8*)&M[(size_t)i1 * HD + j];
        const u16x8 v2 = *(const u16x8*)&M[(size_t)i2 * HD + j];
        const u16x8 v3 = *(const u16x8*)&M[(size_t)i3 * HD + j];
#pragma unroll
        for (int i = 0; i < 8; ++i)
            acc[i] += (bf16_to_f32(v0[i]) + bf16_to_f32(v1[i])) +
                      (bf16_to_f32(v2[i]) + bf16_to_f32(v3[i]));
    }
    for (; k < e; ++k) {
        const int i0 = csr_src[k];
        const u16x8 v0 = *(const u16x8*)&M[(size_t)i0 * HD + j];
#pragma unroll
        for (int i = 0; i < 8; ++i) acc[i] += bf16_to_f32(v0[i]);
    }

    const float d = dinv[node];
    const float4 bv0 = *(const float4*)&b[j];
    const float4 bv1 = *(const float4*)&b[j + 4];
    const float bb[8] = {bv0.x, bv0.y, bv0.z, bv0.w, bv1.x, bv1.y, bv1.z, bv1.w};
    float o[8];
#pragma unroll
    for (int i = 0; i < 8; ++i) {
        o[i] = fmaf(acc[i], d, bb[i]);
        if (!LAST) o[i] = fmaxf(o[i], 0.f);
    }
    if (!LAST) {
        unsigned short* OUT = (unsigned short*)OUTv;
        u16x8 ov;
#pragma unroll
        for (int i = 0; i < 8; ++i) ov[i] = rne_bf16(o[i]);
        *(u16x8*)&OUT[(size_t)node * HD + j] = ov;
    } else {
        float* OUT = (float*)OUTv;
        *(float4*)&OUT[(size_t)node * HD + j] = make_float4(o[0], o[1], o[2], o[3]);
        *(float4*)&OUT[(size_t)node * HD + j + 4] = make_float4(o[4], o[5], o[6], o[7]);
    }
}

// Stage 1 pooling: QSEG blocks per graph (positional over permuted storage).
__global__ __launch_bounds__(128) void k_pool_part(const float* __restrict__ X,
                                                   const int* __restrict__ batch,
                                                   float* __restrict__ psum, int n) {
    const int g = blockIdx.x / QSEG;
    const int q = blockIdx.x % QSEG;
    const int t = threadIdx.x;
    int lo = 0, hi = n;
    while (lo < hi) { int m = (lo + hi) >> 1; if (batch[m] < g) lo = m + 1; else hi = m; }
    const int start = lo;
    hi = n;
    while (lo < hi) { int m = (lo + hi) >> 1; if (batch[m] < g + 1) lo = m + 1; else hi = m; }
    const int end = lo;
    float acc = 0.f;
    for (int i = start + q; i < end; i += QSEG) acc += X[(size_t)i * HD + t];
    psum[(size_t)blockIdx.x * HD + t] = acc;
}

// Stage 2 + final linear fused. pl is in permuted storage; map to logical
// column c(k) = (k%8)*16 + k/8 when indexing Wl.
__global__ __launch_bounds__(128) void k_pool_final(const float* __restrict__ psum,
                                                    const int* __restrict__ batch,
                                                    const float* __restrict__ Wl,
                                                    const float* __restrict__ bl,
                                                    float* __restrict__ out, int n, int C) {
    __shared__ float pl[HD];
    const int g = blockIdx.x;
    const int t = threadIdx.x;
    int lo = 0, hi = n;
    while (lo < hi) { int m = (lo + hi) >> 1; if (batch[m] < g) lo = m + 1; else hi = m; }
    const int start = lo;
    hi = n;
    while (lo < hi) { int m = (lo + hi) >> 1; if (batch[m] < g + 1) lo = m + 1; else hi = m; }
    const int cnt = lo - start;
    float acc = 0.f;
#pragma unroll
    for (int q = 0; q < QSEG; ++q)
        acc += psum[((size_t)g * QSEG + q) * HD + t];
    pl[t] = acc / (float)max(cnt, 1);
    __syncthreads();
    if (t < C) {
        float s = 0.f;
        for (int k = 0; k < HD; ++k) {
            const int c = (k & 7) * 16 + (k >> 3);
            s = fmaf(pl[k], Wl[(size_t)c * C + t], s);
        }
        out[(size_t)g * C + t] = s + bl[t];
    }
}

extern "C" void kernel_launch(void* const* d_in, const int* in_sizes, int n_in,
                              void* d_out, int out_size, void* d_ws, size_t ws_size,
                              hipStream_t stream) {
    const float* x   = (const float*)d_in[0];
    const int* ei    = (const int*)d_in[1];
    const int* batch = (const int*)d_in[2];
    const float* W1 = (const float*)d_in[3];
    const float* b1 = (const float*)d_in[4];
    const float* W2 = (const float*)d_in[5];
    const float* b2 = (const float*)d_in[6];
    const float* W3 = (const float*)d_in[7];
    const float* b3 = (const float*)d_in[8];
    const float* Wl = (const float*)d_in[9];
    const float* bl = (const float*)d_in[10];
    float* out = (float*)d_out;

    const int N = in_sizes[0] / HD;
    const int E = in_sizes[1] / 2;
    const int C = 10;
    const int G = out_size / C;
    const int NB = (N + 127) >> BSH;  // 128-dst buckets

    const int* rowi = ei;      // sources
    const int* coli = ei + E;  // targets

    // workspace layout
    float* Yf         = (float*)d_ws;                            // N*HD f32 (layer-3 out)
    unsigned short* M = (unsigned short*)(Yf + (size_t)N * HD);  // N*HD bf16 messages
    unsigned short* Yb = M + (size_t)N * HD;                     // N*HD bf16 activations
    float* dinv     = (float*)(Yb + (size_t)N * HD);             // N
    short* wf       = (short*)(dinv + N);            // 3*2*16384 shorts
    float* bp       = (float*)(wf + 3 * 32768);      // 3*128 permuted biases
    int* rowptr     = (int*)(bp + 3 * HD);           // N+1
    int* bcnt       = rowptr + (N + 1);              // NB
    int* bbase      = bcnt + NB;                     // NB+1
    int* cursor     = bbase + (NB + 1);              // NB
    int* csr_src    = cursor + NB;                   // E
    unsigned* pairs = (unsigned*)M;  // E u32 (3.2MB) — M unused until layer 1
    float* psum     = (float*)M;     // pooling scratch — M dead after layer-3 gather

    const int T = 256;

    // ---- preprocessing: bucketed CSR build + dinv + W fragments + biases ----
    k_zero_int<<<(NB + T - 1) / T, T, 0, stream>>>(bcnt, NB);
    k_bhist<<<(E + EB * 2 - 1) / (EB * 2), T, 0, stream>>>(coli, bcnt, E, NB);
    k_bscan<<<1, T, 0, stream>>>(bcnt, bbase, cursor, rowptr, NB, E, N);
    k_bin<<<(E + EB - 1) / EB, T, 0, stream>>>(rowi, coli, cursor, pairs, E, NB);
    k_sortbuild<<<NB, T, 0, stream>>>(pairs, bbase, rowptr, dinv, csr_src, N);
    k_wfrag<<<24, 256, 0, stream>>>(W1, W2, W3, wf);
    k_bprep<<<3, 128, 0, stream>>>(b1, b2, b3, bp);

    const short* whi1 = wf;                const short* wlo1 = wf + 16384;
    const short* whi2 = wf + 32768;        const short* wlo2 = wf + 49152;
    const short* whi3 = wf + 65536;        const short* wlo3 = wf + 81920;

    const int gGemm   = (N + 127) / 128;
    const int gGather = (N + 15) / 16;

    // Layer 1: x(f32,natural) --gemm--> M(perm) --gather--> Yb (bf16, relu)
    k_gemm<1><<<gGemm, T, 0, stream>>>(x, whi1, wlo1, dinv, M, N);
    k_gather<0><<<gGather, T, 0, stream>>>(rowptr, csr_src, M, dinv, bp, Yb, N);

    // Layer 2: Yb(perm) --gemm--> M(perm) --gather--> Yb (bf16, relu)
    k_gemm<0><<<gGemm, T, 0, stream>>>(Yb, whi2, wlo2, dinv, M, N);
    k_gather<0><<<gGather, T, 0, stream>>>(rowptr, csr_src, M, dinv, bp + HD, Yb, N);

    // Layer 3: Yb(perm) --gemm--> M(perm) --gather--> Yf (f32, no relu)
    k_gemm<0><<<gGemm, T, 0, stream>>>(Yb, whi3, wlo3, dinv, M, N);
    k_gather<1><<<gGather, T, 0, stream>>>(rowptr, csr_src, M, dinv, bp + 2 * HD, Yf, N);

    // Two-stage pool + fused final linear (psum aliases M, now dead)
    k_pool_part<<<G * QSEG, 128, 0, stream>>>(Yf, batch, psum, N);
    k_pool_final<<<G, 128, 0, stream>>>(psum, batch, Wl, bl, out, N, C);
}

// Round 16
// 260.873 us; speedup vs baseline: 2.1527x; 1.0183x over previous
//
#include <hip/hip_runtime.h>
#include <cstddef>

// N=100000, E=800000, H=128, C=10, G=512
#define HD 128
#define QSEG 8      // partial-pool blocks per graph
#define BSH 7       // bucket shift: 128 dsts per bucket
#define NBP 1024    // padded bucket-array size (>= NB)
#define EB 4096     // edges per k_bin block

// Permuted storage layout for all hidden N x 128 arrays (M, Yb, Yf):
//   storage index s holds logical column c(s) = (s%8)*16 + s/8
// MFMA C/D fragment -> 8 contiguous f16 per (lane, r): coalesced 16B stores.
// Layer>=2 K relabeling is baked into the W fragments.
// All hidden values (messages M, activations Yb) are FP16: 11-bit mantissa
// makes single f16xf16 MFMA more accurate than the old split-bf16 scheme
// while halving MFMA count and removing the wlo table entirely.
// Packed edge encoding: u32 = (dst&127)<<20 | src, valid for N < 2^20.

typedef float f32x4 __attribute__((ext_vector_type(4)));
typedef float f32x8 __attribute__((ext_vector_type(8)));
typedef _Float16 f16x8 __attribute__((ext_vector_type(8)));
typedef unsigned short u16x8 __attribute__((ext_vector_type(8)));

static __device__ __forceinline__ int atomAddI(int* p, int v) {
    return __hip_atomic_fetch_add(p, v, __ATOMIC_RELAXED, __HIP_MEMORY_SCOPE_AGENT);
}

static __device__ __forceinline__ unsigned short f32_to_f16u(float f) {
    _Float16 h = (_Float16)f;  // v_cvt_f16_f32, RNE
    return __builtin_bit_cast(unsigned short, h);
}
static __device__ __forceinline__ float f16u_to_f32(unsigned short u) {
    return (float)__builtin_bit_cast(_Float16, u);
}

__global__ void k_zero_int(int* p, int n) {
    int i = blockIdx.x * blockDim.x + threadIdx.x;
    if (i < n) p[i] = 0;
}

// Coarse histogram of dst buckets (dst>>BSH) via per-block LDS staging.
__global__ __launch_bounds__(256) void k_bhist(const int* __restrict__ coli,
                                               int* __restrict__ bcnt, int E, int NB) {
    __shared__ int lc[NBP];
    for (int b = threadIdx.x; b < NBP; b += 256) lc[b] = 0;
    __syncthreads();
    const int base = blockIdx.x * (EB * 2);
    const int end = min(base + EB * 2, E);
    for (int i = base + threadIdx.x; i < end; i += 256)
        atomicAdd(&lc[coli[i] >> BSH], 1);
    __syncthreads();
    for (int b = threadIdx.x; b < NB; b += 256)
        if (lc[b]) atomAddI(&bcnt[b], lc[b]);
}

// One-block parallel exclusive scan of bucket counts -> bbase + cursor.
__global__ __launch_bounds__(256) void k_bscan(const int* __restrict__ bcnt,
                                               int* __restrict__ bbase,
                                               int* __restrict__ cursor,
                                               int* __restrict__ rowptr,
                                               int NB, int E, int N) {
    __shared__ int sd[256];
    const int t = threadIdx.x;
    int loc[4];
    int tsum = 0;
#pragma unroll
    for (int i = 0; i < 4; ++i) {
        const int b = t * 4 + i;
        loc[i] = (b < NB) ? bcnt[b] : 0;
        tsum += loc[i];
    }
    sd[t] = tsum;
    __syncthreads();
    for (int off = 1; off < 256; off <<= 1) {
        int u = (t >= off) ? sd[t - off] : 0;
        __syncthreads();
        sd[t] += u;
        __syncthreads();
    }
    int pos = sd[t] - tsum;
#pragma unroll
    for (int i = 0; i < 4; ++i) {
        const int b = t * 4 + i;
        if (b < NB) { bbase[b] = pos; cursor[b] = pos; }
        pos += loc[i];
    }
    if (t == 255) {
        bbase[NB] = sd[255];   // == E
        rowptr[N] = sd[255];
    }
}

// Bin edges into bucket-grouped packed u32 ((dst&127)<<20 | src).
__global__ __launch_bounds__(256) void k_bin(const int* __restrict__ rowi,
                                             const int* __restrict__ coli,
                                             int* __restrict__ cursor,
                                             unsigned* __restrict__ pairs, int E, int NB) {
    __shared__ int lcnt[NBP];
    __shared__ int gbs[NBP];
    const int t = threadIdx.x;
    const int base = blockIdx.x * EB;
    for (int b = t; b < NBP; b += 256) lcnt[b] = 0;
    __syncthreads();

    unsigned ed[16];
    int eb[16];
#pragma unroll
    for (int u = 0; u < 16; ++u) {
        const int idx = base + u * 256 + t;
        if (idx < E) {
            const unsigned src = (unsigned)rowi[idx];
            const unsigned dst = (unsigned)coli[idx];
            ed[u] = ((dst & 127u) << 20) | src;
            eb[u] = (int)(dst >> BSH);
            atomicAdd(&lcnt[eb[u]], 1);
        } else {
            eb[u] = -1;
        }
    }
    __syncthreads();
    for (int b = t; b < NB; b += 256) {
        const int c = lcnt[b];
        gbs[b] = c > 0 ? atomAddI(&cursor[b], c) : 0;
    }
    __syncthreads();
    for (int b = t; b < NBP; b += 256) lcnt[b] = 0;
    __syncthreads();
#pragma unroll
    for (int u = 0; u < 16; ++u) {
        if (eb[u] >= 0) {
            const int p = gbs[eb[u]] + atomicAdd(&lcnt[eb[u]], 1);
            pairs[p] = ed[u];
        }
    }
}

// One block per bucket: exact CSR for its 128 dsts.
__global__ __launch_bounds__(256) void k_sortbuild(const unsigned* __restrict__ pairs,
                                                   const int* __restrict__ bbase,
                                                   int* __restrict__ rowptr,
                                                   float* __restrict__ dinv,
                                                   int* __restrict__ csr_src, int N) {
    __shared__ int cnt[128];
    __shared__ int pref[128];
    const int j = blockIdx.x;
    const int t = threadIdx.x;
    const int s = bbase[j];
    const int e2 = bbase[j + 1];
    const int d0 = j << BSH;
    const int dc = min(128, N - d0);

    if (t < 128) cnt[t] = 0;
    __syncthreads();
    for (int i = s + t; i < e2; i += 256)
        atomicAdd(&cnt[pairs[i] >> 20], 1);
    __syncthreads();
    if (t == 0) {
        int run = 0;
        for (int k = 0; k < 128; ++k) { pref[k] = run; run += cnt[k]; }
    }
    __syncthreads();
    if (t < dc) {
        rowptr[d0 + t] = s + pref[t];
        dinv[d0 + t] = rsqrtf(1.0f + (float)cnt[t]);
    }
    __syncthreads();
    if (t < 128) cnt[t] = 0;
    __syncthreads();
    for (int i = s + t; i < e2; i += 256) {
        const unsigned p = pairs[i];
        const int dl = (int)(p >> 20);
        const int pos = atomicAdd(&cnt[dl], 1);
        csr_src[s + pref[dl] + pos] = (int)(p & 0xFFFFFu);
    }
}

// Precompute W into f16 MFMA B-fragment order (single table per layer).
// w==0 (layer 1, natural-layout A=x): k = kt*32 + (lane>>4)*8 + e.
// w>=1 (permuted-storage A):          k = e*16 + kt*4 + (lane>>4).
__global__ __launch_bounds__(256) void k_wfrag(const float* __restrict__ W1,
                                               const float* __restrict__ W2,
                                               const float* __restrict__ W3,
                                               unsigned short* __restrict__ wf) {
    const int w = blockIdx.x >> 3;
    const int slot = (blockIdx.x & 7) * 256 + threadIdx.x;  // 0..2047
    const int nt = slot >> 8;
    const int kt = (slot >> 6) & 3;
    const int lane = slot & 63;
    const float* W = (w == 0) ? W1 : (w == 1) ? W2 : W3;
    unsigned short* wt = wf + (size_t)w * 16384;
    const int obase = ((nt * 4 + kt) * 64 + lane) * 8;
    const int c = nt * 16 + (lane & 15);
    u16x8 h8;
#pragma unroll
    for (int e = 0; e < 8; ++e) {
        const int k = (w == 0) ? (kt * 32 + (lane >> 4) * 8 + e)
                               : (e * 16 + kt * 4 + (lane >> 4));
        h8[e] = f32_to_f16u(W[(size_t)k * HD + c]);
    }
    *(u16x8*)&wt[obase] = h8;
}

// Permute the three bias vectors into storage order: bp[s] = b[(s%8)*16 + s/8].
__global__ void k_bprep(const float* __restrict__ b1, const float* __restrict__ b2,
                        const float* __restrict__ b3, float* __restrict__ bp) {
    const int t = threadIdx.x;  // 128
    const float* b = (blockIdx.x == 0) ? b1 : (blockIdx.x == 1) ? b2 : b3;
    bp[blockIdx.x * HD + t] = b[(t & 7) * 16 + (t >> 3)];
}

// M = f16( dinv ⊙ (A @ W) ) in PERMUTED storage, via single f16 MFMA.
// Full f16 W table (32KB) staged once per block into LDS; no global W reads
// in the loop. Block = 4 waves covers 128 rows; each wave owns 32 rows as
// TWO independent 16-row accumulator chains for ILP.
// AF32=1: A f32 natural layout -> cvt f16.  AF32=0: A f16 permuted storage.
template <int AF32>
__global__ __launch_bounds__(256) void k_gemm(const void* __restrict__ Av,
                                              const unsigned short* __restrict__ wfr,
                                              const float* __restrict__ dinv,
                                              unsigned short* __restrict__ M, int n) {
    __shared__ unsigned short lds[16384];  // 32 KB f16 fragment table
    {
        const float4* s0 = (const float4*)wfr;  // 2048 float4
        float4* d0 = (float4*)lds;
#pragma unroll
        for (int i = 0; i < 8; ++i)
            d0[i * 256 + threadIdx.x] = s0[i * 256 + threadIdx.x];
    }
    __syncthreads();

    const int lane = threadIdx.x & 63;
    const int wid = threadIdx.x >> 6;
    const int rbase = blockIdx.x * 128 + wid * 32;
    const int arow0 = min(rbase + (lane & 15), n - 1);
    const int arow1 = min(rbase + 16 + (lane & 15), n - 1);
    const int kbase = (lane >> 4) * 8;

    f32x4 acc[2][8];
#pragma unroll
    for (int g = 0; g < 2; ++g)
#pragma unroll
        for (int nt = 0; nt < 8; ++nt) acc[g][nt] = (f32x4){0.f, 0.f, 0.f, 0.f};

#pragma unroll
    for (int kt = 0; kt < 4; ++kt) {
        f16x8 a0, a1;
        if (AF32) {
            const float* X = (const float*)Av;
            const float4 p0 = *(const float4*)&X[(size_t)arow0 * HD + kt * 32 + kbase];
            const float4 p1 = *(const float4*)&X[(size_t)arow0 * HD + kt * 32 + kbase + 4];
            const float4 q0 = *(const float4*)&X[(size_t)arow1 * HD + kt * 32 + kbase];
            const float4 q1 = *(const float4*)&X[(size_t)arow1 * HD + kt * 32 + kbase + 4];
            a0[0] = (_Float16)p0.x; a0[1] = (_Float16)p0.y;
            a0[2] = (_Float16)p0.z; a0[3] = (_Float16)p0.w;
            a0[4] = (_Float16)p1.x; a0[5] = (_Float16)p1.y;
            a0[6] = (_Float16)p1.z; a0[7] = (_Float16)p1.w;
            a1[0] = (_Float16)q0.x; a1[1] = (_Float16)q0.y;
            a1[2] = (_Float16)q0.z; a1[3] = (_Float16)q0.w;
            a1[4] = (_Float16)q1.x; a1[5] = (_Float16)q1.y;
            a1[6] = (_Float16)q1.z; a1[7] = (_Float16)q1.w;
        } else {
            const unsigned short* X = (const unsigned short*)Av;
            a0 = *(const f16x8*)&X[(size_t)arow0 * HD + kt * 32 + kbase];
            a1 = *(const f16x8*)&X[(size_t)arow1 * HD + kt * 32 + kbase];
        }
#pragma unroll
        for (int nt = 0; nt < 8; ++nt) {
            const int fo = ((nt * 4 + kt) * 64 + lane) * 8;
            const f16x8 bf = *(const f16x8*)&lds[fo];
            acc[0][nt] = __builtin_amdgcn_mfma_f32_16x16x32_f16(a0, bf, acc[0][nt], 0, 0, 0);
            acc[1][nt] = __builtin_amdgcn_mfma_f32_16x16x32_f16(a1, bf, acc[1][nt], 0, 0, 0);
        }
    }

    // C/D: row = (lane>>4)*4 + r, logical col = nt*16+(lane&15)
    //  -> storage s = (lane&15)*8 + nt  (contiguous over nt)
    const int colb = lane & 15;
    const int rq = (lane >> 4) * 4;
#pragma unroll
    for (int g = 0; g < 2; ++g) {
#pragma unroll
        for (int r = 0; r < 4; ++r) {
            const int row = rbase + g * 16 + rq + r;
            if (row < n) {
                const float d = dinv[row];
                u16x8 o;
#pragma unroll
                for (int nt = 0; nt < 8; ++nt) o[nt] = f32_to_f16u(acc[g][nt][r] * d);
                *(u16x8*)&M[(size_t)row * HD + colb * 8] = o;
            }
        }
    }
}

// OUT[i] = epi( dinv[i]*(M[i] + sum_{e in CSR[i]} M[src_e]) + b ),  M f16.
// 4 nodes per wave: each 16-lane group owns one node, reading full 256B rows
// as u16x8 (16B/lane). 8-edge unroll -> 32 rows in flight per wave.
// LAST=0: relu, f16 output.  LAST=1: no relu, f32 output (feeds pooling).
template <int LAST>
__global__ __launch_bounds__(256) void k_gather(const int* __restrict__ rowptr,
                                                const int* __restrict__ csr_src,
                                                const unsigned short* __restrict__ M,
                                                const float* __restrict__ dinv,
                                                const float* __restrict__ b,
                                                void* __restrict__ OUTv, int n) {
    const int lane = threadIdx.x & 63;
    const int wid = threadIdx.x >> 6;
    const int grp = lane >> 4;
    const int node = blockIdx.x * 16 + wid * 4 + grp;
    if (node >= n) return;
    const int j = (lane & 15) * 8;  // f16 element offset (16B per lane)

    // self loop
    const u16x8 sv = *(const u16x8*)&M[(size_t)node * HD + j];
    f32x8 acc;
#pragma unroll
    for (int i = 0; i < 8; ++i) acc[i] = f16u_to_f32(sv[i]);

    const int s = rowptr[node];
    const int e = rowptr[node + 1];
    int k = s;
    for (; k + 8 <= e; k += 8) {
        int idx[8];
#pragma unroll
        for (int u = 0; u < 8; ++u) idx[u] = csr_src[k + u];
        u16x8 v[8];
#pragma unroll
        for (int u = 0; u < 8; ++u)
            v[u] = *(const u16x8*)&M[(size_t)idx[u] * HD + j];
#pragma unroll
        for (int i = 0; i < 8; ++i) {
            float s0 = (f16u_to_f32(v[0][i]) + f16u_to_f32(v[1][i])) +
                       (f16u_to_f32(v[2][i]) + f16u_to_f32(v[3][i]));
            float s1 = (f16u_to_f32(v[4][i]) + f16u_to_f32(v[5][i])) +
                       (f16u_to_f32(v[6][i]) + f16u_to_f32(v[7][i]));
            acc[i] += s0 + s1;
        }
    }
    for (; k < e; ++k) {
        const int i0 = csr_src[k];
        const u16x8 v0 = *(const u16x8*)&M[(size_t)i0 * HD + j];
#pragma unroll
        for (int i = 0; i < 8; ++i) acc[i] += f16u_to_f32(v0[i]);
    }

    const float d = dinv[node];
    const float4 bv0 = *(const float4*)&b[j];
    const float4 bv1 = *(const float4*)&b[j + 4];
    const float bb[8] = {bv0.x, bv0.y, bv0.z, bv0.w, bv1.x, bv1.y, bv1.z, bv1.w};
    float o[8];
#pragma unroll
    for (int i = 0; i < 8; ++i) {
        o[i] = fmaf(acc[i], d, bb[i]);
        if (!LAST) o[i] = fmaxf(o[i], 0.f);
    }
    if (!LAST) {
        unsigned short* OUT = (unsigned short*)OUTv;
        u16x8 ov;
#pragma unroll
        for (int i = 0; i < 8; ++i) ov[i] = f32_to_f16u(o[i]);
        *(u16x8*)&OUT[(size_t)node * HD + j] = ov;
    } else {
        float* OUT = (float*)OUTv;
        *(float4*)&OUT[(size_t)node * HD + j] = make_float4(o[0], o[1], o[2], o[3]);
        *(float4*)&OUT[(size_t)node * HD + j + 4] = make_float4(o[4], o[5], o[6], o[7]);
    }
}

// Stage 1 pooling: QSEG blocks per graph (positional over permuted storage).
__global__ __launch_bounds__(128) void k_pool_part(const float* __restrict__ X,
                                                   const int* __restrict__ batch,
                                                   float* __restrict__ psum, int n) {
    const int g = blockIdx.x / QSEG;
    const int q = blockIdx.x % QSEG;
    const int t = threadIdx.x;
    int lo = 0, hi = n;
    while (lo < hi) { int m = (lo + hi) >> 1; if (batch[m] < g) lo = m + 1; else hi = m; }
    const int start = lo;
    hi = n;
    while (lo < hi) { int m = (lo + hi) >> 1; if (batch[m] < g + 1) lo = m + 1; else hi = m; }
    const int end = lo;
    float acc = 0.f;
    for (int i = start + q; i < end; i += QSEG) acc += X[(size_t)i * HD + t];
    psum[(size_t)blockIdx.x * HD + t] = acc;
}

// Stage 2 + final linear fused. pl is in permuted storage; map to logical
// column c(k) = (k%8)*16 + k/8 when indexing Wl.
__global__ __launch_bounds__(128) void k_pool_final(const float* __restrict__ psum,
                                                    const int* __restrict__ batch,
                                                    const float* __restrict__ Wl,
                                                    const float* __restrict__ bl,
                                                    float* __restrict__ out, int n, int C) {
    __shared__ float pl[HD];
    const int g = blockIdx.x;
    const int t = threadIdx.x;
    int lo = 0, hi = n;
    while (lo < hi) { int m = (lo + hi) >> 1; if (batch[m] < g) lo = m + 1; else hi = m; }
    const int start = lo;
    hi = n;
    while (lo < hi) { int m = (lo + hi) >> 1; if (batch[m] < g + 1) lo = m + 1; else hi = m; }
    const int cnt = lo - start;
    float acc = 0.f;
#pragma unroll
    for (int q = 0; q < QSEG; ++q)
        acc += psum[((size_t)g * QSEG + q) * HD + t];
    pl[t] = acc / (float)max(cnt, 1);
    __syncthreads();
    if (t < C) {
        float s = 0.f;
        for (int k = 0; k < HD; ++k) {
            const int c = (k & 7) * 16 + (k >> 3);
            s = fmaf(pl[k], Wl[(size_t)c * C + t], s);
        }
        out[(size_t)g * C + t] = s + bl[t];
    }
}

extern "C" void kernel_launch(void* const* d_in, const int* in_sizes, int n_in,
                              void* d_out, int out_size, void* d_ws, size_t ws_size,
                              hipStream_t stream) {
    const float* x   = (const float*)d_in[0];
    const int* ei    = (const int*)d_in[1];
    const int* batch = (const int*)d_in[2];
    const float* W1 = (const float*)d_in[3];
    const float* b1 = (const float*)d_in[4];
    const float* W2 = (const float*)d_in[5];
    const float* b2 = (const float*)d_in[6];
    const float* W3 = (const float*)d_in[7];
    const float* b3 = (const float*)d_in[8];
    const float* Wl = (const float*)d_in[9];
    const float* bl = (const float*)d_in[10];
    float* out = (float*)d_out;

    const int N = in_sizes[0] / HD;
    const int E = in_sizes[1] / 2;
    const int C = 10;
    const int G = out_size / C;
    const int NB = (N + 127) >> BSH;  // 128-dst buckets

    const int* rowi = ei;      // sources
    const int* coli = ei + E;  // targets

    // workspace layout
    float* Yf         = (float*)d_ws;                            // N*HD f32 (layer-3 out)
    unsigned short* M = (unsigned short*)(Yf + (size_t)N * HD);  // N*HD f16 messages
    unsigned short* Yb = M + (size_t)N * HD;                     // N*HD f16 activations
    float* dinv     = (float*)(Yb + (size_t)N * HD);             // N
    unsigned short* wf = (unsigned short*)(dinv + N);  // 3*16384 f16 W tables
    float* bp       = (float*)(wf + 3 * 16384);      // 3*128 permuted biases
    int* rowptr     = (int*)(bp + 3 * HD);           // N+1
    int* bcnt       = rowptr + (N + 1);              // NB
    int* bbase      = bcnt + NB;                     // NB+1
    int* cursor     = bbase + (NB + 1);              // NB
    int* csr_src    = cursor + NB;                   // E
    unsigned* pairs = (unsigned*)M;  // E u32 (3.2MB) — M unused until layer 1
    float* psum     = (float*)M;     // pooling scratch — M dead after layer-3 gather

    const int T = 256;

    // ---- preprocessing: bucketed CSR build + dinv + W fragments + biases ----
    k_zero_int<<<(NB + T - 1) / T, T, 0, stream>>>(bcnt, NB);
    k_bhist<<<(E + EB * 2 - 1) / (EB * 2), T, 0, stream>>>(coli, bcnt, E, NB);
    k_bscan<<<1, T, 0, stream>>>(bcnt, bbase, cursor, rowptr, NB, E, N);
    k_bin<<<(E + EB - 1) / EB, T, 0, stream>>>(rowi, coli, cursor, pairs, E, NB);
    k_sortbuild<<<NB, T, 0, stream>>>(pairs, bbase, rowptr, dinv, csr_src, N);
    k_wfrag<<<24, 256, 0, stream>>>(W1, W2, W3, wf);
    k_bprep<<<3, 128, 0, stream>>>(b1, b2, b3, bp);

    const unsigned short* wf1 = wf;
    const unsigned short* wf2 = wf + 16384;
    const unsigned short* wf3 = wf + 32768;

    const int gGemm   = (N + 127) / 128;
    const int gGather = (N + 15) / 16;

    // Layer 1: x(f32,natural) --gemm--> M(f16,perm) --gather--> Yb (f16, relu)
    k_gemm<1><<<gGemm, T, 0, stream>>>(x, wf1, dinv, M, N);
    k_gather<0><<<gGather, T, 0, stream>>>(rowptr, csr_src, M, dinv, bp, Yb, N);

    // Layer 2: Yb(f16,perm) --gemm--> M --gather--> Yb (f16, relu)
    k_gemm<0><<<gGemm, T, 0, stream>>>(Yb, wf2, dinv, M, N);
    k_gather<0><<<gGather, T, 0, stream>>>(rowptr, csr_src, M, dinv, bp + HD, Yb, N);

    // Layer 3: Yb(f16,perm) --gemm--> M --gather--> Yf (f32, no relu)
    k_gemm<0><<<gGemm, T, 0, stream>>>(Yb, wf3, dinv, M, N);
    k_gather<1><<<gGather, T, 0, stream>>>(rowptr, csr_src, M, dinv, bp + 2 * HD, Yf, N);

    // Two-stage pool + fused final linear (psum aliases M, now dead)
    k_pool_part<<<G * QSEG, 128, 0, stream>>>(Yf, batch, psum, N);
    k_pool_final<<<G, 128, 0, stream>>>(psum, batch, Wl, bl, out, N, C);
}

// Round 17
// 238.711 us; speedup vs baseline: 2.3526x; 1.0928x over previous
//
#include <hip/hip_runtime.h>
#include <cstddef>

// N=100000, E=800000, H=128, C=10, G=512
#define HD 128
#define QSEG 8      // partial-pool blocks per graph
#define BSH 7       // bucket shift: 128 dsts per bucket
#define NBP 1024    // padded bucket-array size (>= NB)
#define EB 4096     // edges per k_bin block

// Permuted storage layout for all hidden N x 128 arrays (M, Yb, Yf):
//   storage index s holds logical column c(s) = (s%8)*16 + s/8
// MFMA C/D fragment -> 8 contiguous f16 per (lane, r): coalesced 16B stores.
// Layer>=2 K relabeling is baked into the W fragments.
// All hidden values (messages M, activations Yb) are FP16 (11-bit mantissa:
// better accuracy than bf16 AND single f16xf16 MFMA, no split tables).
// Packed edge encoding: u32 = (dst&127)<<20 | src, valid for N < 2^20.

typedef float f32x4 __attribute__((ext_vector_type(4)));
typedef float f32x8 __attribute__((ext_vector_type(8)));
typedef _Float16 f16x8 __attribute__((ext_vector_type(8)));
typedef unsigned short u16x8 __attribute__((ext_vector_type(8)));

static __device__ __forceinline__ int atomAddI(int* p, int v) {
    return __hip_atomic_fetch_add(p, v, __ATOMIC_RELAXED, __HIP_MEMORY_SCOPE_AGENT);
}

static __device__ __forceinline__ unsigned short f32_to_f16u(float f) {
    _Float16 h = (_Float16)f;  // v_cvt_f16_f32, RNE
    return __builtin_bit_cast(unsigned short, h);
}
static __device__ __forceinline__ float f16u_to_f32(unsigned short u) {
    return (float)__builtin_bit_cast(_Float16, u);
}

__global__ void k_zero_int(int* p, int n) {
    int i = blockIdx.x * blockDim.x + threadIdx.x;
    if (i < n) p[i] = 0;
}

// Coarse histogram of dst buckets (dst>>BSH) via per-block LDS staging.
__global__ __launch_bounds__(256) void k_bhist(const int* __restrict__ coli,
                                               int* __restrict__ bcnt, int E, int NB) {
    __shared__ int lc[NBP];
    for (int b = threadIdx.x; b < NBP; b += 256) lc[b] = 0;
    __syncthreads();
    const int base = blockIdx.x * (EB * 2);
    const int end = min(base + EB * 2, E);
    for (int i = base + threadIdx.x; i < end; i += 256)
        atomicAdd(&lc[coli[i] >> BSH], 1);
    __syncthreads();
    for (int b = threadIdx.x; b < NB; b += 256)
        if (lc[b]) atomAddI(&bcnt[b], lc[b]);
}

// One-block parallel exclusive scan of bucket counts -> bbase + cursor.
__global__ __launch_bounds__(256) void k_bscan(const int* __restrict__ bcnt,
                                               int* __restrict__ bbase,
                                               int* __restrict__ cursor,
                                               int* __restrict__ rowptr,
                                               int NB, int E, int N) {
    __shared__ int sd[256];
    const int t = threadIdx.x;
    int loc[4];
    int tsum = 0;
#pragma unroll
    for (int i = 0; i < 4; ++i) {
        const int b = t * 4 + i;
        loc[i] = (b < NB) ? bcnt[b] : 0;
        tsum += loc[i];
    }
    sd[t] = tsum;
    __syncthreads();
    for (int off = 1; off < 256; off <<= 1) {
        int u = (t >= off) ? sd[t - off] : 0;
        __syncthreads();
        sd[t] += u;
        __syncthreads();
    }
    int pos = sd[t] - tsum;
#pragma unroll
    for (int i = 0; i < 4; ++i) {
        const int b = t * 4 + i;
        if (b < NB) { bbase[b] = pos; cursor[b] = pos; }
        pos += loc[i];
    }
    if (t == 255) {
        bbase[NB] = sd[255];   // == E
        rowptr[N] = sd[255];
    }
}

// Bin edges into bucket-grouped packed u32 ((dst&127)<<20 | src).
__global__ __launch_bounds__(256) void k_bin(const int* __restrict__ rowi,
                                             const int* __restrict__ coli,
                                             int* __restrict__ cursor,
                                             unsigned* __restrict__ pairs, int E, int NB) {
    __shared__ int lcnt[NBP];
    __shared__ int gbs[NBP];
    const int t = threadIdx.x;
    const int base = blockIdx.x * EB;
    for (int b = t; b < NBP; b += 256) lcnt[b] = 0;
    __syncthreads();

    unsigned ed[16];
    int eb[16];
#pragma unroll
    for (int u = 0; u < 16; ++u) {
        const int idx = base + u * 256 + t;
        if (idx < E) {
            const unsigned src = (unsigned)rowi[idx];
            const unsigned dst = (unsigned)coli[idx];
            ed[u] = ((dst & 127u) << 20) | src;
            eb[u] = (int)(dst >> BSH);
            atomicAdd(&lcnt[eb[u]], 1);
        } else {
            eb[u] = -1;
        }
    }
    __syncthreads();
    for (int b = t; b < NB; b += 256) {
        const int c = lcnt[b];
        gbs[b] = c > 0 ? atomAddI(&cursor[b], c) : 0;
    }
    __syncthreads();
    for (int b = t; b < NBP; b += 256) lcnt[b] = 0;
    __syncthreads();
#pragma unroll
    for (int u = 0; u < 16; ++u) {
        if (eb[u] >= 0) {
            const int p = gbs[eb[u]] + atomicAdd(&lcnt[eb[u]], 1);
            pairs[p] = ed[u];
        }
    }
}

// One block per bucket: exact CSR for its 128 dsts.
__global__ __launch_bounds__(256) void k_sortbuild(const unsigned* __restrict__ pairs,
                                                   const int* __restrict__ bbase,
                                                   int* __restrict__ rowptr,
                                                   float* __restrict__ dinv,
                                                   int* __restrict__ csr_src, int N) {
    __shared__ int cnt[128];
    __shared__ int pref[128];
    const int j = blockIdx.x;
    const int t = threadIdx.x;
    const int s = bbase[j];
    const int e2 = bbase[j + 1];
    const int d0 = j << BSH;
    const int dc = min(128, N - d0);

    if (t < 128) cnt[t] = 0;
    __syncthreads();
    for (int i = s + t; i < e2; i += 256)
        atomicAdd(&cnt[pairs[i] >> 20], 1);
    __syncthreads();
    if (t == 0) {
        int run = 0;
        for (int k = 0; k < 128; ++k) { pref[k] = run; run += cnt[k]; }
    }
    __syncthreads();
    if (t < dc) {
        rowptr[d0 + t] = s + pref[t];
        dinv[d0 + t] = rsqrtf(1.0f + (float)cnt[t]);
    }
    __syncthreads();
    if (t < 128) cnt[t] = 0;
    __syncthreads();
    for (int i = s + t; i < e2; i += 256) {
        const unsigned p = pairs[i];
        const int dl = (int)(p >> 20);
        const int pos = atomicAdd(&cnt[dl], 1);
        csr_src[s + pref[dl] + pos] = (int)(p & 0xFFFFFu);
    }
}

// Precompute W into f16 MFMA B-fragment order (single table per layer).
// w==0 (layer 1, natural-layout A=x): k = kt*32 + (lane>>4)*8 + e.
// w>=1 (permuted-storage A):          k = e*16 + kt*4 + (lane>>4).
__global__ __launch_bounds__(256) void k_wfrag(const float* __restrict__ W1,
                                               const float* __restrict__ W2,
                                               const float* __restrict__ W3,
                                               unsigned short* __restrict__ wf) {
    const int w = blockIdx.x >> 3;
    const int slot = (blockIdx.x & 7) * 256 + threadIdx.x;  // 0..2047
    const int nt = slot >> 8;
    const int kt = (slot >> 6) & 3;
    const int lane = slot & 63;
    const float* W = (w == 0) ? W1 : (w == 1) ? W2 : W3;
    unsigned short* wt = wf + (size_t)w * 16384;
    const int obase = ((nt * 4 + kt) * 64 + lane) * 8;
    const int c = nt * 16 + (lane & 15);
    u16x8 h8;
#pragma unroll
    for (int e = 0; e < 8; ++e) {
        const int k = (w == 0) ? (kt * 32 + (lane >> 4) * 8 + e)
                               : (e * 16 + kt * 4 + (lane >> 4));
        h8[e] = f32_to_f16u(W[(size_t)k * HD + c]);
    }
    *(u16x8*)&wt[obase] = h8;
}

// Permute the three bias vectors into storage order: bp[s] = b[(s%8)*16 + s/8].
__global__ void k_bprep(const float* __restrict__ b1, const float* __restrict__ b2,
                        const float* __restrict__ b3, float* __restrict__ bp) {
    const int t = threadIdx.x;  // 128
    const float* b = (blockIdx.x == 0) ? b1 : (blockIdx.x == 1) ? b2 : b3;
    bp[blockIdx.x * HD + t] = b[(t & 7) * 16 + (t >> 3)];
}

// M = f16( dinv ⊙ (A @ W) ) in PERMUTED storage, via single f16 MFMA.
// Full f16 W table (32KB) staged once per block into LDS; no global W reads
// in the loop. Block = 4 waves covers 128 rows; each wave owns 32 rows as
// TWO independent 16-row accumulator chains for ILP.
// AF32=1: A f32 natural layout -> cvt f16.  AF32=0: A f16 permuted storage.
template <int AF32>
__global__ __launch_bounds__(256) void k_gemm(const void* __restrict__ Av,
                                              const unsigned short* __restrict__ wfr,
                                              const float* __restrict__ dinv,
                                              unsigned short* __restrict__ M, int n) {
    __shared__ unsigned short lds[16384];  // 32 KB f16 fragment table
    {
        const float4* s0 = (const float4*)wfr;  // 2048 float4
        float4* d0 = (float4*)lds;
#pragma unroll
        for (int i = 0; i < 8; ++i)
            d0[i * 256 + threadIdx.x] = s0[i * 256 + threadIdx.x];
    }
    __syncthreads();

    const int lane = threadIdx.x & 63;
    const int wid = threadIdx.x >> 6;
    const int rbase = blockIdx.x * 128 + wid * 32;
    const int arow0 = min(rbase + (lane & 15), n - 1);
    const int arow1 = min(rbase + 16 + (lane & 15), n - 1);
    const int kbase = (lane >> 4) * 8;

    f32x4 acc[2][8];
#pragma unroll
    for (int g = 0; g < 2; ++g)
#pragma unroll
        for (int nt = 0; nt < 8; ++nt) acc[g][nt] = (f32x4){0.f, 0.f, 0.f, 0.f};

#pragma unroll
    for (int kt = 0; kt < 4; ++kt) {
        f16x8 a0, a1;
        if (AF32) {
            const float* X = (const float*)Av;
            const float4 p0 = *(const float4*)&X[(size_t)arow0 * HD + kt * 32 + kbase];
            const float4 p1 = *(const float4*)&X[(size_t)arow0 * HD + kt * 32 + kbase + 4];
            const float4 q0 = *(const float4*)&X[(size_t)arow1 * HD + kt * 32 + kbase];
            const float4 q1 = *(const float4*)&X[(size_t)arow1 * HD + kt * 32 + kbase + 4];
            a0[0] = (_Float16)p0.x; a0[1] = (_Float16)p0.y;
            a0[2] = (_Float16)p0.z; a0[3] = (_Float16)p0.w;
            a0[4] = (_Float16)p1.x; a0[5] = (_Float16)p1.y;
            a0[6] = (_Float16)p1.z; a0[7] = (_Float16)p1.w;
            a1[0] = (_Float16)q0.x; a1[1] = (_Float16)q0.y;
            a1[2] = (_Float16)q0.z; a1[3] = (_Float16)q0.w;
            a1[4] = (_Float16)q1.x; a1[5] = (_Float16)q1.y;
            a1[6] = (_Float16)q1.z; a1[7] = (_Float16)q1.w;
        } else {
            const unsigned short* X = (const unsigned short*)Av;
            a0 = *(const f16x8*)&X[(size_t)arow0 * HD + kt * 32 + kbase];
            a1 = *(const f16x8*)&X[(size_t)arow1 * HD + kt * 32 + kbase];
        }
#pragma unroll
        for (int nt = 0; nt < 8; ++nt) {
            const int fo = ((nt * 4 + kt) * 64 + lane) * 8;
            const f16x8 bf = *(const f16x8*)&lds[fo];
            acc[0][nt] = __builtin_amdgcn_mfma_f32_16x16x32_f16(a0, bf, acc[0][nt], 0, 0, 0);
            acc[1][nt] = __builtin_amdgcn_mfma_f32_16x16x32_f16(a1, bf, acc[1][nt], 0, 0, 0);
        }
    }

    // C/D: row = (lane>>4)*4 + r, logical col = nt*16+(lane&15)
    //  -> storage s = (lane&15)*8 + nt  (contiguous over nt)
    const int colb = lane & 15;
    const int rq = (lane >> 4) * 4;
#pragma unroll
    for (int g = 0; g < 2; ++g) {
#pragma unroll
        for (int r = 0; r < 4; ++r) {
            const int row = rbase + g * 16 + rq + r;
            if (row < n) {
                const float d = dinv[row];
                u16x8 o;
#pragma unroll
                for (int nt = 0; nt < 8; ++nt) o[nt] = f32_to_f16u(acc[g][nt][r] * d);
                *(u16x8*)&M[(size_t)row * HD + colb * 8] = o;
            }
        }
    }
}

// OUT[i] = epi( dinv[i]*(M[i] + sum_{e in CSR[i]} M[src_e]) + b ),  M f16.
// 4 nodes per wave: each 16-lane group owns one node, reading full 256B rows
// as u16x8 (16B/lane). 4-edge unroll (VGPR ~28 -> ~61% occupancy; the 8-edge
// variant cost 16 VGPR and dropped occupancy to 41%, regressing 6.7us).
// LAST=0: relu, f16 output.  LAST=1: no relu, f32 output (feeds pooling).
template <int LAST>
__global__ __launch_bounds__(256) void k_gather(const int* __restrict__ rowptr,
                                                const int* __restrict__ csr_src,
                                                const unsigned short* __restrict__ M,
                                                const float* __restrict__ dinv,
                                                const float* __restrict__ b,
                                                void* __restrict__ OUTv, int n) {
    const int lane = threadIdx.x & 63;
    const int wid = threadIdx.x >> 6;
    const int grp = lane >> 4;
    const int node = blockIdx.x * 16 + wid * 4 + grp;
    if (node >= n) return;
    const int j = (lane & 15) * 8;  // f16 element offset (16B per lane)

    // self loop
    const u16x8 sv = *(const u16x8*)&M[(size_t)node * HD + j];
    f32x8 acc;
#pragma unroll
    for (int i = 0; i < 8; ++i) acc[i] = f16u_to_f32(sv[i]);

    const int s = rowptr[node];
    const int e = rowptr[node + 1];
    int k = s;
    for (; k + 4 <= e; k += 4) {
        const int i0 = csr_src[k], i1 = csr_src[k + 1];
        const int i2 = csr_src[k + 2], i3 = csr_src[k + 3];
        const u16x8 v0 = *(const u16x8*)&M[(size_t)i0 * HD + j];
        const u16x8 v1 = *(const u16x8*)&M[(size_t)i1 * HD + j];
        const u16x8 v2 = *(const u16x8*)&M[(size_t)i2 * HD + j];
        const u16x8 v3 = *(const u16x8*)&M[(size_t)i3 * HD + j];
#pragma unroll
        for (int i = 0; i < 8; ++i)
            acc[i] += (f16u_to_f32(v0[i]) + f16u_to_f32(v1[i])) +
                      (f16u_to_f32(v2[i]) + f16u_to_f32(v3[i]));
    }
    for (; k < e; ++k) {
        const int i0 = csr_src[k];
        const u16x8 v0 = *(const u16x8*)&M[(size_t)i0 * HD + j];
#pragma unroll
        for (int i = 0; i < 8; ++i) acc[i] += f16u_to_f32(v0[i]);
    }

    const float d = dinv[node];
    const float4 bv0 = *(const float4*)&b[j];
    const float4 bv1 = *(const float4*)&b[j + 4];
    const float bb[8] = {bv0.x, bv0.y, bv0.z, bv0.w, bv1.x, bv1.y, bv1.z, bv1.w};
    float o[8];
#pragma unroll
    for (int i = 0; i < 8; ++i) {
        o[i] = fmaf(acc[i], d, bb[i]);
        if (!LAST) o[i] = fmaxf(o[i], 0.f);
    }
    if (!LAST) {
        unsigned short* OUT = (unsigned short*)OUTv;
        u16x8 ov;
#pragma unroll
        for (int i = 0; i < 8; ++i) ov[i] = f32_to_f16u(o[i]);
        *(u16x8*)&OUT[(size_t)node * HD + j] = ov;
    } else {
        float* OUT = (float*)OUTv;
        *(float4*)&OUT[(size_t)node * HD + j] = make_float4(o[0], o[1], o[2], o[3]);
        *(float4*)&OUT[(size_t)node * HD + j + 4] = make_float4(o[4], o[5], o[6], o[7]);
    }
}

// Stage 1 pooling: QSEG blocks per graph (positional over permuted storage).
__global__ __launch_bounds__(128) void k_pool_part(const float* __restrict__ X,
                                                   const int* __restrict__ batch,
                                                   float* __restrict__ psum, int n) {
    const int g = blockIdx.x / QSEG;
    const int q = blockIdx.x % QSEG;
    const int t = threadIdx.x;
    int lo = 0, hi = n;
    while (lo < hi) { int m = (lo + hi) >> 1; if (batch[m] < g) lo = m + 1; else hi = m; }
    const int start = lo;
    hi = n;
    while (lo < hi) { int m = (lo + hi) >> 1; if (batch[m] < g + 1) lo = m + 1; else hi = m; }
    const int end = lo;
    float acc = 0.f;
    for (int i = start + q; i < end; i += QSEG) acc += X[(size_t)i * HD + t];
    psum[(size_t)blockIdx.x * HD + t] = acc;
}

// Stage 2 + final linear fused. pl is in permuted storage; map to logical
// column c(k) = (k%8)*16 + k/8 when indexing Wl.
__global__ __launch_bounds__(128) void k_pool_final(const float* __restrict__ psum,
                                                    const int* __restrict__ batch,
                                                    const float* __restrict__ Wl,
                                                    const float* __restrict__ bl,
                                                    float* __restrict__ out, int n, int C) {
    __shared__ float pl[HD];
    const int g = blockIdx.x;
    const int t = threadIdx.x;
    int lo = 0, hi = n;
    while (lo < hi) { int m = (lo + hi) >> 1; if (batch[m] < g) lo = m + 1; else hi = m; }
    const int start = lo;
    hi = n;
    while (lo < hi) { int m = (lo + hi) >> 1; if (batch[m] < g + 1) lo = m + 1; else hi = m; }
    const int cnt = lo - start;
    float acc = 0.f;
#pragma unroll
    for (int q = 0; q < QSEG; ++q)
        acc += psum[((size_t)g * QSEG + q) * HD + t];
    pl[t] = acc / (float)max(cnt, 1);
    __syncthreads();
    if (t < C) {
        float s = 0.f;
        for (int k = 0; k < HD; ++k) {
            const int c = (k & 7) * 16 + (k >> 3);
            s = fmaf(pl[k], Wl[(size_t)c * C + t], s);
        }
        out[(size_t)g * C + t] = s + bl[t];
    }
}

extern "C" void kernel_launch(void* const* d_in, const int* in_sizes, int n_in,
                              void* d_out, int out_size, void* d_ws, size_t ws_size,
                              hipStream_t stream) {
    const float* x   = (const float*)d_in[0];
    const int* ei    = (const int*)d_in[1];
    const int* batch = (const int*)d_in[2];
    const float* W1 = (const float*)d_in[3];
    const float* b1 = (const float*)d_in[4];
    const float* W2 = (const float*)d_in[5];
    const float* b2 = (const float*)d_in[6];
    const float* W3 = (const float*)d_in[7];
    const float* b3 = (const float*)d_in[8];
    const float* Wl = (const float*)d_in[9];
    const float* bl = (const float*)d_in[10];
    float* out = (float*)d_out;

    const int N = in_sizes[0] / HD;
    const int E = in_sizes[1] / 2;
    const int C = 10;
    const int G = out_size / C;
    const int NB = (N + 127) >> BSH;  // 128-dst buckets

    const int* rowi = ei;      // sources
    const int* coli = ei + E;  // targets

    // workspace layout
    float* Yf         = (float*)d_ws;                            // N*HD f32 (layer-3 out)
    unsigned short* M = (unsigned short*)(Yf + (size_t)N * HD);  // N*HD f16 messages
    unsigned short* Yb = M + (size_t)N * HD;                     // N*HD f16 activations
    float* dinv     = (float*)(Yb + (size_t)N * HD);             // N
    unsigned short* wf = (unsigned short*)(dinv + N);  // 3*16384 f16 W tables
    float* bp       = (float*)(wf + 3 * 16384);      // 3*128 permuted biases
    int* rowptr     = (int*)(bp + 3 * HD);           // N+1
    int* bcnt       = rowptr + (N + 1);              // NB
    int* bbase      = bcnt + NB;                     // NB+1
    int* cursor     = bbase + (NB + 1);              // NB
    int* csr_src    = cursor + NB;                   // E
    unsigned* pairs = (unsigned*)M;  // E u32 (3.2MB) — M unused until layer 1
    float* psum     = (float*)M;     // pooling scratch — M dead after layer-3 gather

    const int T = 256;

    // ---- preprocessing: bucketed CSR build + dinv + W fragments + biases ----
    k_zero_int<<<(NB + T - 1) / T, T, 0, stream>>>(bcnt, NB);
    k_bhist<<<(E + EB * 2 - 1) / (EB * 2), T, 0, stream>>>(coli, bcnt, E, NB);
    k_bscan<<<1, T, 0, stream>>>(bcnt, bbase, cursor, rowptr, NB, E, N);
    k_bin<<<(E + EB - 1) / EB, T, 0, stream>>>(rowi, coli, cursor, pairs, E, NB);
    k_sortbuild<<<NB, T, 0, stream>>>(pairs, bbase, rowptr, dinv, csr_src, N);
    k_wfrag<<<24, 256, 0, stream>>>(W1, W2, W3, wf);
    k_bprep<<<3, 128, 0, stream>>>(b1, b2, b3, bp);

    const unsigned short* wf1 = wf;
    const unsigned short* wf2 = wf + 16384;
    const unsigned short* wf3 = wf + 32768;

    const int gGemm   = (N + 127) / 128;
    const int gGather = (N + 15) / 16;

    // Layer 1: x(f32,natural) --gemm--> M(f16,perm) --gather--> Yb (f16, relu)
    k_gemm<1><<<gGemm, T, 0, stream>>>(x, wf1, dinv, M, N);
    k_gather<0><<<gGather, T, 0, stream>>>(rowptr, csr_src, M, dinv, bp, Yb, N);

    // Layer 2: Yb(f16,perm) --gemm--> M --gather--> Yb (f16, relu)
    k_gemm<0><<<gGemm, T, 0, stream>>>(Yb, wf2, dinv, M, N);
    k_gather<0><<<gGather, T, 0, stream>>>(rowptr, csr_src, M, dinv, bp + HD, Yb, N);

    // Layer 3: Yb(f16,perm) --gemm--> M --gather--> Yf (f32, no relu)
    k_gemm<0><<<gGemm, T, 0, stream>>>(Yb, wf3, dinv, M, N);
    k_gather<1><<<gGather, T, 0, stream>>>(rowptr, csr_src, M, dinv, bp + 2 * HD, Yf, N);

    // Two-stage pool + fused final linear (psum aliases M, now dead)
    k_pool_part<<<G * QSEG, 128, 0, stream>>>(Yf, batch, psum, N);
    k_pool_final<<<G, 128, 0, stream>>>(psum, batch, Wl, bl, out, N, C);
}

// Round 18
// 218.238 us; speedup vs baseline: 2.5733x; 1.0938x over previous
//
#include <hip/hip_runtime.h>
#include <cstddef>

// N=100000, E=800000, H=128, C=10, G=512
#define HD 128
#define QSEG 8      // partial-pool blocks per graph
#define BSH 7       // bucket shift: 128 dsts per bucket
#define NBP 1024    // padded bucket-array size (>= NB)
#define EB 4096     // edges per k_binP block
#define ECAP 1536   // padded slots per bucket (Poisson(1024)+16 sigma)

// Permuted storage layout for all hidden N x 128 arrays (M, Yb, Yf):
//   storage index s holds logical column c(s) = (s%8)*16 + s/8
// MFMA C/D fragment -> 8 contiguous f16 per (lane, r): coalesced 16B stores.
// Layer>=2 K relabeling is baked into the W fragments.
// All hidden values (M, Yb, Yf) are FP16.
// CSR is built in ONE pass into fixed-capacity bucket regions (ECAP each);
// rowptr/rowend are absolute indices into the padded csr_src.
// Packed edge encoding: u32 = (dst&127)<<20 | src, valid for N < 2^20.

typedef float f32x4 __attribute__((ext_vector_type(4)));
typedef float f32x8 __attribute__((ext_vector_type(8)));
typedef _Float16 f16x8 __attribute__((ext_vector_type(8)));
typedef unsigned short u16x8 __attribute__((ext_vector_type(8)));

static __device__ __forceinline__ int atomAddI(int* p, int v) {
    return __hip_atomic_fetch_add(p, v, __ATOMIC_RELAXED, __HIP_MEMORY_SCOPE_AGENT);
}

static __device__ __forceinline__ unsigned short f32_to_f16u(float f) {
    _Float16 h = (_Float16)f;  // v_cvt_f16_f32, RNE
    return __builtin_bit_cast(unsigned short, h);
}
static __device__ __forceinline__ float f16u_to_f32(unsigned short u) {
    return (float)__builtin_bit_cast(_Float16, u);
}

// cursor[b] = b * ECAP  (start of bucket b's padded region)
__global__ void k_initcur(int* cursor, int NB) {
    int i = blockIdx.x * blockDim.x + threadIdx.x;
    if (i < NB) cursor[i] = i * ECAP;
}

// Single-pass binning: edges -> bucket-grouped packed u32 in padded regions.
// Per-block LDS histogram, ONE reservation atomic per (block,bucket), then
// 4B writes into the reserved contiguous runs. No pre-scan needed.
__global__ __launch_bounds__(256) void k_binP(const int* __restrict__ rowi,
                                              const int* __restrict__ coli,
                                              int* __restrict__ cursor,
                                              unsigned* __restrict__ pairs, int E, int NB) {
    __shared__ int lcnt[NBP];
    __shared__ int gbs[NBP];
    const int t = threadIdx.x;
    const int base = blockIdx.x * EB;
    for (int b = t; b < NBP; b += 256) lcnt[b] = 0;
    __syncthreads();

    unsigned ed[16];
    int eb[16];
#pragma unroll
    for (int u = 0; u < 16; ++u) {
        const int idx = base + u * 256 + t;
        if (idx < E) {
            const unsigned src = (unsigned)rowi[idx];
            const unsigned dst = (unsigned)coli[idx];
            ed[u] = ((dst & 127u) << 20) | src;
            eb[u] = (int)(dst >> BSH);
            atomicAdd(&lcnt[eb[u]], 1);
        } else {
            eb[u] = -1;
        }
    }
    __syncthreads();
    for (int b = t; b < NB; b += 256) {
        const int c = lcnt[b];
        gbs[b] = c > 0 ? atomAddI(&cursor[b], c) : 0;
    }
    __syncthreads();
    for (int b = t; b < NBP; b += 256) lcnt[b] = 0;
    __syncthreads();
#pragma unroll
    for (int u = 0; u < 16; ++u) {
        if (eb[u] >= 0) {
            const int p = gbs[eb[u]] + atomicAdd(&lcnt[eb[u]], 1);
            pairs[p] = ed[u];
        }
    }
}

// One block per bucket: exact CSR (within the padded region) for 128 dsts.
// Writes absolute rowptr/rowend + dinv coalesced, then compacts srcs.
__global__ __launch_bounds__(256) void k_sortbuildP(const unsigned* __restrict__ pairs,
                                                    const int* __restrict__ cursor,
                                                    int* __restrict__ rowptr,
                                                    int* __restrict__ rowend,
                                                    float* __restrict__ dinv,
                                                    int* __restrict__ csr_src, int N) {
    __shared__ int cnt[128];
    __shared__ int pref[128];
    const int j = blockIdx.x;
    const int t = threadIdx.x;
    const int s = j * ECAP;
    const int e2 = cursor[j];          // end of this bucket's filled region
    const int d0 = j << BSH;
    const int dc = min(128, N - d0);

    if (t < 128) cnt[t] = 0;
    __syncthreads();
    for (int i = s + t; i < e2; i += 256)
        atomicAdd(&cnt[pairs[i] >> 20], 1);
    __syncthreads();
    if (t == 0) {
        int run = 0;
        for (int k = 0; k < 128; ++k) { pref[k] = run; run += cnt[k]; }
    }
    __syncthreads();
    if (t < dc) {
        rowptr[d0 + t] = s + pref[t];
        rowend[d0 + t] = s + pref[t] + cnt[t];
        dinv[d0 + t] = rsqrtf(1.0f + (float)cnt[t]);
    }
    __syncthreads();
    if (t < 128) cnt[t] = 0;
    __syncthreads();
    for (int i = s + t; i < e2; i += 256) {
        const unsigned p = pairs[i];
        const int dl = (int)(p >> 20);
        const int pos = atomicAdd(&cnt[dl], 1);
        csr_src[s + pref[dl] + pos] = (int)(p & 0xFFFFFu);
    }
}

// Precompute W into f16 MFMA B-fragment order (single table per layer).
// w==0 (layer 1, natural-layout A=x): k = kt*32 + (lane>>4)*8 + e.
// w>=1 (permuted-storage A):          k = e*16 + kt*4 + (lane>>4).
__global__ __launch_bounds__(256) void k_wfrag(const float* __restrict__ W1,
                                               const float* __restrict__ W2,
                                               const float* __restrict__ W3,
                                               unsigned short* __restrict__ wf) {
    const int w = blockIdx.x >> 3;
    const int slot = (blockIdx.x & 7) * 256 + threadIdx.x;  // 0..2047
    const int nt = slot >> 8;
    const int kt = (slot >> 6) & 3;
    const int lane = slot & 63;
    const float* W = (w == 0) ? W1 : (w == 1) ? W2 : W3;
    unsigned short* wt = wf + (size_t)w * 16384;
    const int obase = ((nt * 4 + kt) * 64 + lane) * 8;
    const int c = nt * 16 + (lane & 15);
    u16x8 h8;
#pragma unroll
    for (int e = 0; e < 8; ++e) {
        const int k = (w == 0) ? (kt * 32 + (lane >> 4) * 8 + e)
                               : (e * 16 + kt * 4 + (lane >> 4));
        h8[e] = f32_to_f16u(W[(size_t)k * HD + c]);
    }
    *(u16x8*)&wt[obase] = h8;
}

// Permute the three bias vectors into storage order: bp[s] = b[(s%8)*16 + s/8].
__global__ void k_bprep(const float* __restrict__ b1, const float* __restrict__ b2,
                        const float* __restrict__ b3, float* __restrict__ bp) {
    const int t = threadIdx.x;  // 128
    const float* b = (blockIdx.x == 0) ? b1 : (blockIdx.x == 1) ? b2 : b3;
    bp[blockIdx.x * HD + t] = b[(t & 7) * 16 + (t >> 3)];
}

// M = f16( dinv ⊙ (A @ W) ) in PERMUTED storage, via single f16 MFMA.
// Full f16 W table (32KB) staged once per block into LDS. Block = 4 waves
// covers 128 rows; each wave owns 32 rows as TWO independent chains.
// AF32=1: A f32 natural layout -> cvt f16.  AF32=0: A f16 permuted storage.
template <int AF32>
__global__ __launch_bounds__(256) void k_gemm(const void* __restrict__ Av,
                                              const unsigned short* __restrict__ wfr,
                                              const float* __restrict__ dinv,
                                              unsigned short* __restrict__ M, int n) {
    __shared__ unsigned short lds[16384];  // 32 KB f16 fragment table
    {
        const float4* s0 = (const float4*)wfr;  // 2048 float4
        float4* d0 = (float4*)lds;
#pragma unroll
        for (int i = 0; i < 8; ++i)
            d0[i * 256 + threadIdx.x] = s0[i * 256 + threadIdx.x];
    }
    __syncthreads();

    const int lane = threadIdx.x & 63;
    const int wid = threadIdx.x >> 6;
    const int rbase = blockIdx.x * 128 + wid * 32;
    const int arow0 = min(rbase + (lane & 15), n - 1);
    const int arow1 = min(rbase + 16 + (lane & 15), n - 1);
    const int kbase = (lane >> 4) * 8;

    f32x4 acc[2][8];
#pragma unroll
    for (int g = 0; g < 2; ++g)
#pragma unroll
        for (int nt = 0; nt < 8; ++nt) acc[g][nt] = (f32x4){0.f, 0.f, 0.f, 0.f};

#pragma unroll
    for (int kt = 0; kt < 4; ++kt) {
        f16x8 a0, a1;
        if (AF32) {
            const float* X = (const float*)Av;
            const float4 p0 = *(const float4*)&X[(size_t)arow0 * HD + kt * 32 + kbase];
            const float4 p1 = *(const float4*)&X[(size_t)arow0 * HD + kt * 32 + kbase + 4];
            const float4 q0 = *(const float4*)&X[(size_t)arow1 * HD + kt * 32 + kbase];
            const float4 q1 = *(const float4*)&X[(size_t)arow1 * HD + kt * 32 + kbase + 4];
            a0[0] = (_Float16)p0.x; a0[1] = (_Float16)p0.y;
            a0[2] = (_Float16)p0.z; a0[3] = (_Float16)p0.w;
            a0[4] = (_Float16)p1.x; a0[5] = (_Float16)p1.y;
            a0[6] = (_Float16)p1.z; a0[7] = (_Float16)p1.w;
            a1[0] = (_Float16)q0.x; a1[1] = (_Float16)q0.y;
            a1[2] = (_Float16)q0.z; a1[3] = (_Float16)q0.w;
            a1[4] = (_Float16)q1.x; a1[5] = (_Float16)q1.y;
            a1[6] = (_Float16)q1.z; a1[7] = (_Float16)q1.w;
        } else {
            const unsigned short* X = (const unsigned short*)Av;
            a0 = *(const f16x8*)&X[(size_t)arow0 * HD + kt * 32 + kbase];
            a1 = *(const f16x8*)&X[(size_t)arow1 * HD + kt * 32 + kbase];
        }
#pragma unroll
        for (int nt = 0; nt < 8; ++nt) {
            const int fo = ((nt * 4 + kt) * 64 + lane) * 8;
            const f16x8 bf = *(const f16x8*)&lds[fo];
            acc[0][nt] = __builtin_amdgcn_mfma_f32_16x16x32_f16(a0, bf, acc[0][nt], 0, 0, 0);
            acc[1][nt] = __builtin_amdgcn_mfma_f32_16x16x32_f16(a1, bf, acc[1][nt], 0, 0, 0);
        }
    }

    // C/D: row = (lane>>4)*4 + r, logical col = nt*16+(lane&15)
    //  -> storage s = (lane&15)*8 + nt  (contiguous over nt)
    const int colb = lane & 15;
    const int rq = (lane >> 4) * 4;
#pragma unroll
    for (int g = 0; g < 2; ++g) {
#pragma unroll
        for (int r = 0; r < 4; ++r) {
            const int row = rbase + g * 16 + rq + r;
            if (row < n) {
                const float d = dinv[row];
                u16x8 o;
#pragma unroll
                for (int nt = 0; nt < 8; ++nt) o[nt] = f32_to_f16u(acc[g][nt][r] * d);
                *(u16x8*)&M[(size_t)row * HD + colb * 8] = o;
            }
        }
    }
}

// OUT[i] = epi( dinv[i]*(M[i] + sum_{e in CSR[i]} M[src_e]) + b ),  M f16.
// 4 nodes per wave: each 16-lane group owns one node, reading full 256B rows
// as u16x8 (16B/lane). 4-edge unroll (VGPR ~28, ~61% occupancy — the 8-edge
// variant regressed: occupancy 41%). rowptr/rowend give [start,end) in the
// padded csr_src. RELU=1: relu. Output always f16 permuted storage.
template <int RELU>
__global__ __launch_bounds__(256) void k_gather(const int* __restrict__ rowptr,
                                                const int* __restrict__ rowend,
                                                const int* __restrict__ csr_src,
                                                const unsigned short* __restrict__ M,
                                                const float* __restrict__ dinv,
                                                const float* __restrict__ b,
                                                unsigned short* __restrict__ OUT, int n) {
    const int lane = threadIdx.x & 63;
    const int wid = threadIdx.x >> 6;
    const int grp = lane >> 4;
    const int node = blockIdx.x * 16 + wid * 4 + grp;
    if (node >= n) return;
    const int j = (lane & 15) * 8;  // f16 element offset (16B per lane)

    // self loop
    const u16x8 sv = *(const u16x8*)&M[(size_t)node * HD + j];
    f32x8 acc;
#pragma unroll
    for (int i = 0; i < 8; ++i) acc[i] = f16u_to_f32(sv[i]);

    const int s = rowptr[node];
    const int e = rowend[node];
    int k = s;
    for (; k + 4 <= e; k += 4) {
        const int i0 = csr_src[k], i1 = csr_src[k + 1];
        const int i2 = csr_src[k + 2], i3 = csr_src[k + 3];
        const u16x8 v0 = *(const u16x8*)&M[(size_t)i0 * HD + j];
        const u16x8 v1 = *(const u16x8*)&M[(size_t)i1 * HD + j];
        const u16x8 v2 = *(const u16x8*)&M[(size_t)i2 * HD + j];
        const u16x8 v3 = *(const u16x8*)&M[(size_t)i3 * HD + j];
#pragma unroll
        for (int i = 0; i < 8; ++i)
            acc[i] += (f16u_to_f32(v0[i]) + f16u_to_f32(v1[i])) +
                      (f16u_to_f32(v2[i]) + f16u_to_f32(v3[i]));
    }
    for (; k < e; ++k) {
        const int i0 = csr_src[k];
        const u16x8 v0 = *(const u16x8*)&M[(size_t)i0 * HD + j];
#pragma unroll
        for (int i = 0; i < 8; ++i) acc[i] += f16u_to_f32(v0[i]);
    }

    const float d = dinv[node];
    const float4 bv0 = *(const float4*)&b[j];
    const float4 bv1 = *(const float4*)&b[j + 4];
    const float bb[8] = {bv0.x, bv0.y, bv0.z, bv0.w, bv1.x, bv1.y, bv1.z, bv1.w};
    u16x8 ov;
#pragma unroll
    for (int i = 0; i < 8; ++i) {
        float o = fmaf(acc[i], d, bb[i]);
        if (RELU) o = fmaxf(o, 0.f);
        ov[i] = f32_to_f16u(o);
    }
    *(u16x8*)&OUT[(size_t)node * HD + j] = ov;
}

// Stage 1 pooling over f16 input: QSEG blocks per graph.
__global__ __launch_bounds__(128) void k_pool_part(const unsigned short* __restrict__ X,
                                                   const int* __restrict__ batch,
                                                   float* __restrict__ psum, int n) {
    const int g = blockIdx.x / QSEG;
    const int q = blockIdx.x % QSEG;
    const int t = threadIdx.x;
    int lo = 0, hi = n;
    while (lo < hi) { int m = (lo + hi) >> 1; if (batch[m] < g) lo = m + 1; else hi = m; }
    const int start = lo;
    hi = n;
    while (lo < hi) { int m = (lo + hi) >> 1; if (batch[m] < g + 1) lo = m + 1; else hi = m; }
    const int end = lo;
    float acc = 0.f;
    for (int i = start + q; i < end; i += QSEG)
        acc += f16u_to_f32(X[(size_t)i * HD + t]);
    psum[(size_t)blockIdx.x * HD + t] = acc;
}

// Stage 2 + final linear fused. pl is in permuted storage; map to logical
// column c(k) = (k%8)*16 + k/8 when indexing Wl.
__global__ __launch_bounds__(128) void k_pool_final(const float* __restrict__ psum,
                                                    const int* __restrict__ batch,
                                                    const float* __restrict__ Wl,
                                                    const float* __restrict__ bl,
                                                    float* __restrict__ out, int n, int C) {
    __shared__ float pl[HD];
    const int g = blockIdx.x;
    const int t = threadIdx.x;
    int lo = 0, hi = n;
    while (lo < hi) { int m = (lo + hi) >> 1; if (batch[m] < g) lo = m + 1; else hi = m; }
    const int start = lo;
    hi = n;
    while (lo < hi) { int m = (lo + hi) >> 1; if (batch[m] < g + 1) lo = m + 1; else hi = m; }
    const int cnt = lo - start;
    float acc = 0.f;
#pragma unroll
    for (int q = 0; q < QSEG; ++q)
        acc += psum[((size_t)g * QSEG + q) * HD + t];
    pl[t] = acc / (float)max(cnt, 1);
    __syncthreads();
    if (t < C) {
        float s = 0.f;
        for (int k = 0; k < HD; ++k) {
            const int c = (k & 7) * 16 + (k >> 3);
            s = fmaf(pl[k], Wl[(size_t)c * C + t], s);
        }
        out[(size_t)g * C + t] = s + bl[t];
    }
}

extern "C" void kernel_launch(void* const* d_in, const int* in_sizes, int n_in,
                              void* d_out, int out_size, void* d_ws, size_t ws_size,
                              hipStream_t stream) {
    const float* x   = (const float*)d_in[0];
    const int* ei    = (const int*)d_in[1];
    const int* batch = (const int*)d_in[2];
    const float* W1 = (const float*)d_in[3];
    const float* b1 = (const float*)d_in[4];
    const float* W2 = (const float*)d_in[5];
    const float* b2 = (const float*)d_in[6];
    const float* W3 = (const float*)d_in[7];
    const float* b3 = (const float*)d_in[8];
    const float* Wl = (const float*)d_in[9];
    const float* bl = (const float*)d_in[10];
    float* out = (float*)d_out;

    const int N = in_sizes[0] / HD;
    const int E = in_sizes[1] / 2;
    const int C = 10;
    const int G = out_size / C;
    const int NB = (N + 127) >> BSH;  // 128-dst buckets

    const int* rowi = ei;      // sources
    const int* coli = ei + E;  // targets

    // workspace layout
    unsigned short* Yf = (unsigned short*)d_ws;          // N*HD f16 (layer-3 out)
    unsigned short* M  = Yf + (size_t)N * HD;            // N*HD f16 messages
    unsigned short* Yb = M + (size_t)N * HD;             // N*HD f16 activations
    float* dinv     = (float*)(Yb + (size_t)N * HD);     // N
    unsigned short* wf = (unsigned short*)(dinv + N);    // 3*16384 f16 W tables
    float* bp       = (float*)(wf + 3 * 16384);          // 3*128 permuted biases
    int* rowptr     = (int*)(bp + 3 * HD);               // N
    int* rowend     = rowptr + N;                        // N
    int* cursor     = rowend + N;                        // NB
    int* csr_src    = cursor + NB;                       // NB*ECAP (padded)
    unsigned* pairs = (unsigned*)M;  // NB*ECAP u32 (4.8MB) — M unused until layer 1
    float* psum     = (float*)M;     // pooling scratch — M dead after layer-3 gather

    const int T = 256;

    // ---- preprocessing: single-pass padded CSR + dinv + W fragments ----
    k_initcur<<<(NB + T - 1) / T, T, 0, stream>>>(cursor, NB);
    k_binP<<<(E + EB - 1) / EB, T, 0, stream>>>(rowi, coli, cursor, pairs, E, NB);
    k_sortbuildP<<<NB, T, 0, stream>>>(pairs, cursor, rowptr, rowend, dinv, csr_src, N);
    k_wfrag<<<24, 256, 0, stream>>>(W1, W2, W3, wf);
    k_bprep<<<3, 128, 0, stream>>>(b1, b2, b3, bp);

    const unsigned short* wf1 = wf;
    const unsigned short* wf2 = wf + 16384;
    const unsigned short* wf3 = wf + 32768;

    const int gGemm   = (N + 127) / 128;
    const int gGather = (N + 15) / 16;

    // Layer 1: x(f32,natural) --gemm--> M(f16,perm) --gather--> Yb (f16, relu)
    k_gemm<1><<<gGemm, T, 0, stream>>>(x, wf1, dinv, M, N);
    k_gather<1><<<gGather, T, 0, stream>>>(rowptr, rowend, csr_src, M, dinv, bp, Yb, N);

    // Layer 2: Yb(f16,perm) --gemm--> M --gather--> Yb (f16, relu)
    k_gemm<0><<<gGemm, T, 0, stream>>>(Yb, wf2, dinv, M, N);
    k_gather<1><<<gGather, T, 0, stream>>>(rowptr, rowend, csr_src, M, dinv, bp + HD, Yb, N);

    // Layer 3: Yb(f16,perm) --gemm--> M --gather--> Yf (f16, no relu)
    k_gemm<0><<<gGemm, T, 0, stream>>>(Yb, wf3, dinv, M, N);
    k_gather<0><<<gGather, T, 0, stream>>>(rowptr, rowend, csr_src, M, dinv, bp + 2 * HD, Yf, N);

    // Two-stage pool + fused final linear (psum aliases M, now dead)
    k_pool_part<<<G * QSEG, 128, 0, stream>>>(Yf, batch, psum, N);
    k_pool_final<<<G, 128, 0, stream>>>(psum, batch, Wl, bl, out, N, C);
}